// Round 1
// 1698.153 us; speedup vs baseline: 1.8413x; 1.8413x over previous
//
#include <hip/hip_runtime.h>

#define NN 263
#define TT 24

typedef __fp16 h2 __attribute__((ext_vector_type(2)));
typedef _Float16 f16x4 __attribute__((ext_vector_type(4)));
typedef _Float16 f16x8 __attribute__((ext_vector_type(8)));
typedef float f32x4 __attribute__((ext_vector_type(4)));

static __device__ __forceinline__ float wred_sum(float v) {
  #pragma unroll
  for (int off = 32; off >= 1; off >>= 1) v += __shfl_xor(v, off, 64);
  return v;
}
static __device__ __forceinline__ float wred_max(float v) {
  #pragma unroll
  for (int off = 32; off >= 1; off >>= 1) v = fmaxf(v, __shfl_xor(v, off, 64));
  return v;
}
// broadcast a packed h2 from lane `l` to all lanes (VALU readlane, no DS traffic)
static __device__ __forceinline__ h2 rl_h2(h2 v, int l) {
  union { h2 h; int i; } u; u.h = v;
  u.i = __builtin_amdgcn_readlane(u.i, l);
  return u.h;
}
static __device__ __forceinline__ float rl_f(float v, int l) {
  union { float f; int i; } u; u.f = v;
  u.i = __builtin_amdgcn_readlane(u.i, l);
  return u.f;
}

// ---------------------------------------------------------------------------
// f16-MFMA NT GEMM: C[m,n] = sum_k A[m,k]*W[n,k] (+bias[n])
// A: M x K row-major fp32, W: N x K row-major fp32, C: M x ldc fp32.
// 128x128 tile, BK=32. 4 waves (2x2), each wave owns a 64x64 sub-tile as
// 4x4 fragments of v_mfma_f32_16x16x32_f16 (fp32 accumulate).
// Staging: reg-staged fp32->fp16 cvt into LDS, 40-half (80B) row stride so
// every ds_read_b128 is 16B-aligned with <=2-way bank aliasing (free).
// Next K-tile is prefetched into registers between the two barriers.
// Requires: N % 128 == 0, K % 32 == 0 (true for all call sites); M guarded.
// ---------------------------------------------------------------------------
__global__ __launch_bounds__(256) void gemm_nt_mfma(
    const float* __restrict__ A, const float* __restrict__ W,
    const float* __restrict__ bias, float* __restrict__ C,
    int M, int N, int K, int ldc)
{
  __shared__ _Float16 As[128][40];
  __shared__ _Float16 Bs[128][40];
  const int tid  = threadIdx.x;
  const int lane = tid & 63;
  const int wave = tid >> 6;
  const int wr = wave >> 1, wc = wave & 1;   // 2x2 wave grid
  const int bm = blockIdx.x * 128;
  const int bn = blockIdx.y * 128;

  // staging: idx = tid + 256*l -> row = idx>>3 (0..127), kq = (idx&7)*4
  const int srow = tid >> 3;
  const int skq  = (tid & 7) * 4;
  const float* aptr[4];
  const float* bptr[4];
  #pragma unroll
  for (int l = 0; l < 4; ++l) {
    int gm = bm + srow + 32 * l; if (gm > M - 1) gm = M - 1;
    aptr[l] = A + (size_t)gm * K + skq;
    int gn = bn + srow + 32 * l;             // N is a multiple of 128
    bptr[l] = W + (size_t)gn * K + skq;
  }

  f32x4 acc[4][4];
  #pragma unroll
  for (int i = 0; i < 4; ++i)
    #pragma unroll
    for (int j = 0; j < 4; ++j) {
      acc[i][j].x = 0.f; acc[i][j].y = 0.f; acc[i][j].z = 0.f; acc[i][j].w = 0.f;
    }

  // MFMA fragment addressing (m89/m91-verified layout):
  // A/B: row|col = lane&15, k = (lane>>4)*8 + j ; C/D: col = lane&15,
  // row = (lane>>4)*4 + reg.
  const int fr = lane & 15;
  const int fk = (lane >> 4) * 8;

  float4 av[4], bv[4];
  #pragma unroll
  for (int l = 0; l < 4; ++l) {
    av[l] = *(const float4*)(aptr[l]);
    bv[l] = *(const float4*)(bptr[l]);
  }

  for (int k0 = 0; k0 < K; k0 += 32) {
    // write staged regs (tile @k0) to LDS as fp16
    #pragma unroll
    for (int l = 0; l < 4; ++l) {
      f16x4 a4, b4;
      a4.x = (_Float16)av[l].x; a4.y = (_Float16)av[l].y;
      a4.z = (_Float16)av[l].z; a4.w = (_Float16)av[l].w;
      b4.x = (_Float16)bv[l].x; b4.y = (_Float16)bv[l].y;
      b4.z = (_Float16)bv[l].z; b4.w = (_Float16)bv[l].w;
      *(f16x4*)&As[srow + 32 * l][skq] = a4;
      *(f16x4*)&Bs[srow + 32 * l][skq] = b4;
    }
    __syncthreads();

    // prefetch next K-tile into registers; latency hides under ds_read+MFMA
    if (k0 + 32 < K) {
      #pragma unroll
      for (int l = 0; l < 4; ++l) {
        av[l] = *(const float4*)(aptr[l] + k0 + 32);
        bv[l] = *(const float4*)(bptr[l] + k0 + 32);
      }
    }

    f16x8 af[4], bf[4];
    #pragma unroll
    for (int mi = 0; mi < 4; ++mi)
      af[mi] = *(const f16x8*)&As[wr * 64 + mi * 16 + fr][fk];
    #pragma unroll
    for (int ni = 0; ni < 4; ++ni)
      bf[ni] = *(const f16x8*)&Bs[wc * 64 + ni * 16 + fr][fk];
    #pragma unroll
    for (int mi = 0; mi < 4; ++mi)
      #pragma unroll
      for (int ni = 0; ni < 4; ++ni)
        acc[mi][ni] = __builtin_amdgcn_mfma_f32_16x16x32_f16(
            af[mi], bf[ni], acc[mi][ni], 0, 0, 0);
    __syncthreads();
  }

  // epilogue: C[row][col], col = bn + wc*64 + ni*16 + fr,
  // row = bm + wr*64 + mi*16 + (lane>>4)*4 + r
  #pragma unroll
  for (int mi = 0; mi < 4; ++mi) {
    int rb = bm + wr * 64 + mi * 16 + (lane >> 4) * 4;
    #pragma unroll
    for (int r = 0; r < 4; ++r) {
      int gm = rb + r;
      if (gm < M) {
        float* crow = C + (size_t)gm * ldc + bn + wc * 64 + fr;
        #pragma unroll
        for (int ni = 0; ni < 4; ++ni) {
          float v = acc[mi][ni][r];
          if (bias) v += bias[bn + wc * 64 + ni * 16 + fr];
          crow[ni * 16] = v;
        }
      }
    }
  }
}

// ---------------------------------------------------------------------------
__global__ void lam_kernel(const float* __restrict__ lq1, const float* __restrict__ lk1,
                           const float* __restrict__ lq2, const float* __restrict__ lk2,
                           float* __restrict__ out) {
  int lane = threadIdx.x;
  float v1 = lane < 32 ? lq1[lane] * lk1[lane] : 0.f;
  float v2 = lane < 32 ? lq2[lane] * lk2[lane] : 0.f;
  v1 = wred_sum(v1);
  v2 = wred_sum(v2);
  if (lane == 0) out[0] = expf(v1) - expf(v2) + 0.2f;
}

// ---------------------------------------------------------------------------
// Differential self-attention half, v2.
// Per block (bt,h,i): K-half cached in registers as f16x2 (lane l owns rows
// m = l+64j); V resident in LDS as f16 pairs over (m, m+64) matching the
// lane-strided P layout; QK and PV via v_dot2_f32_f16 (fp32 accumulate);
// P broadcast via v_readlane (VALU) — DS pipe only carries the 135
// conflict-free ds_read_b32 of V per row.
// ---------------------------------------------------------------------------
__global__ __launch_bounds__(256) void diff_attn(
    const float* __restrict__ qkv, float* __restrict__ aout)
{
  __shared__ h2 vp[135 * 64];   // vp[mp*64+d] = (v[m_lo][d], v[m_hi][d])
  const int h = blockIdx.x & 3;
  const int bt = blockIdx.x >> 2;
  const int i = blockIdx.y;
  const int tid = threadIdx.x;
  const int lane = tid & 63;
  const int wave = tid >> 6;
  const float* base  = qkv + (size_t)bt * NN * 768;
  const float* kbase = base + 256 + h * 64 + i * 32;
  const float* vbase = base + 512 + h * 64;

  // stage V: pairs (m, m+64) within each 128-row group; tail rows pair with 0
  for (int idx = tid; idx < 135 * 64; idx += 256) {
    int mp = idx >> 6, d = idx & 63;
    int m_lo = mp < 64 ? mp : (mp < 128 ? mp + 64 : mp + 128);
    float lo = vbase[(size_t)m_lo * 768 + d];
    float hi = (mp < 128) ? vbase[(size_t)(m_lo + 64) * 768 + d] : 0.f;
    vp[idx] = __builtin_amdgcn_cvt_pkrtz(lo, hi);
  }

  // register K-cache: lane l holds k rows m = l + 64j (j=0..4, clamped)
  h2 kc[5][16];
  #pragma unroll
  for (int j = 0; j < 5; ++j) {
    int m = lane + 64 * j; if (m > NN - 1) m = NN - 1;
    const float* kr = kbase + (size_t)m * 768;
    #pragma unroll
    for (int t = 0; t < 8; ++t) {
      float4 kv = *(const float4*)(kr + 4 * t);
      kc[j][2 * t]     = __builtin_amdgcn_cvt_pkrtz(kv.x, kv.y);
      kc[j][2 * t + 1] = __builtin_amdgcn_cvt_pkrtz(kv.z, kv.w);
    }
  }
  __syncthreads();

  float* ab = aout + (size_t)i * (50496ull * 256ull);
  const float sc = 0.17677669529663687f;  // 1/sqrt(32)

  for (int n = wave; n < NN; n += 4) {
    // q row -> f16x2 pairs broadcast to all lanes
    float qv = (lane < 32) ? base[(size_t)n * 768 + h * 64 + i * 32 + lane] : 0.f;
    h2 qp[16];
    #pragma unroll
    for (int kk = 0; kk < 16; ++kk)
      qp[kk] = __builtin_amdgcn_cvt_pkrtz(rl_f(qv, 2 * kk), rl_f(qv, 2 * kk + 1));
    // scores: 5 m-rows per lane, all from registers
    float s[5] = {0.f, 0.f, 0.f, 0.f, 0.f};
    #pragma unroll
    for (int kk = 0; kk < 16; ++kk)
      #pragma unroll
      for (int j = 0; j < 5; ++j)
        s[j] = __builtin_amdgcn_fdot2(qp[kk], kc[j][kk], s[j], false);
    float mx = -1e30f;
    #pragma unroll
    for (int j = 0; j < 5; ++j) {
      s[j] *= sc;
      if (lane + 64 * j >= NN) s[j] = -1e30f;
      mx = fmaxf(mx, s[j]);
    }
    mx = wred_max(mx);
    float sum = 0.f;
    #pragma unroll
    for (int j = 0; j < 5; ++j) { s[j] = __expf(s[j] - mx); sum += s[j]; }
    sum = wred_sum(sum);
    float inv = 1.f / sum;
    // pack P pairs matching vp pairing: (l, l+64), (l+128, l+192), (l+256, 0)
    h2 p01 = __builtin_amdgcn_cvt_pkrtz(s[0] * inv, s[1] * inv);
    h2 p23 = __builtin_amdgcn_cvt_pkrtz(s[2] * inv, s[3] * inv);
    h2 p4  = __builtin_amdgcn_cvt_pkrtz(s[4] * inv, 0.f);
    // PV: lane = d; readlane-broadcast P, ds_read V, dot2 accumulate
    float o0 = 0.f, o1 = 0.f, o2 = 0.f, o3 = 0.f;
    #pragma unroll
    for (int mp = 0; mp < 64; mp += 4) {
      o0 = __builtin_amdgcn_fdot2(rl_h2(p01, mp + 0), vp[(mp + 0) * 64 + lane], o0, false);
      o1 = __builtin_amdgcn_fdot2(rl_h2(p01, mp + 1), vp[(mp + 1) * 64 + lane], o1, false);
      o2 = __builtin_amdgcn_fdot2(rl_h2(p01, mp + 2), vp[(mp + 2) * 64 + lane], o2, false);
      o3 = __builtin_amdgcn_fdot2(rl_h2(p01, mp + 3), vp[(mp + 3) * 64 + lane], o3, false);
    }
    #pragma unroll
    for (int mp = 0; mp < 64; mp += 4) {
      o0 = __builtin_amdgcn_fdot2(rl_h2(p23, mp + 0), vp[(64 + mp + 0) * 64 + lane], o0, false);
      o1 = __builtin_amdgcn_fdot2(rl_h2(p23, mp + 1), vp[(64 + mp + 1) * 64 + lane], o1, false);
      o2 = __builtin_amdgcn_fdot2(rl_h2(p23, mp + 2), vp[(64 + mp + 2) * 64 + lane], o2, false);
      o3 = __builtin_amdgcn_fdot2(rl_h2(p23, mp + 3), vp[(64 + mp + 3) * 64 + lane], o3, false);
    }
    #pragma unroll
    for (int mp = 0; mp < 7; ++mp)
      o0 = __builtin_amdgcn_fdot2(rl_h2(p4, mp), vp[(128 + mp) * 64 + lane], o0, false);
    ab[((size_t)(bt * NN + n) * 4 + h) * 64 + lane] = (o0 + o1) + (o2 + o3);
  }
}

// ---------------------------------------------------------------------------
__global__ __launch_bounds__(256) void diff_ln(
    const float* __restrict__ a1, const float* __restrict__ a2,
    const float* __restrict__ lamp,
    const float* __restrict__ g, const float* __restrict__ b,
    float* __restrict__ st)
{
  const int btn = blockIdx.x;
  const int lane = threadIdx.x & 63;
  const int h = threadIdx.x >> 6;
  const float lam = lamp[0];
  size_t off = ((size_t)btn * 4 + h) * 64 + lane;
  float y = a1[off] - lam * a2[off];
  float mean = wred_sum(y) * (1.f / 64.f);
  float t = y - mean;
  float var = wred_sum(t * t) * (1.f / 64.f);
  float r = rsqrtf(var + 1e-5f);
  st[(size_t)btn * 640 + h * 64 + lane] = (t * r * g[lane] + b[lane]) * 0.8f;
}

// ---------------------------------------------------------------------------
__global__ __launch_bounds__(256) void temporal_attn(
    const float* __restrict__ qkvt, float* __restrict__ st)
{
  __shared__ float kt[2 * 24 * 65];
  __shared__ float vt[2 * 24 * 65];
  const int b = blockIdx.x / NN;
  const int n = blockIdx.x % NN;
  const int tid = threadIdx.x;
  const int lane = tid & 63;
  const int wave = tid >> 6;
  for (int idx = tid; idx < 2 * 24 * 64; idx += 256) {
    int t = idx >> 7, hd = idx & 127, h = hd >> 6, d = hd & 63;
    size_t row = ((size_t)(b * TT + t) * NN + n) * 640;
    kt[(h * 24 + t) * 65 + d] = qkvt[row + 128 + h * 64 + d];
    vt[(h * 24 + t) * 65 + d] = qkvt[row + 256 + h * 64 + d];
  }
  __syncthreads();
  for (int r = wave; r < 48; r += 4) {
    int t = r >> 1, h = r & 1;
    size_t row = ((size_t)(b * TT + t) * NN + n) * 640;
    float qv = qkvt[row + h * 64 + lane];
    int ss = lane < 24 ? lane : 23;
    float sc_ = 0.f;
    #pragma unroll
    for (int d = 0; d < 64; ++d) {
      float qd = __shfl(qv, d, 64);
      sc_ = fmaf(qd, kt[(h * 24 + ss) * 65 + d], sc_);
    }
    sc_ *= 0.125f;
    bool valid = lane < 24;
    float mx = wred_max(valid ? sc_ : -1e30f);
    float p = valid ? __expf(sc_ - mx) : 0.f;
    float inv = 1.f / wred_sum(p);
    float o = 0.f;
    #pragma unroll
    for (int s = 0; s < 24; ++s) {
      float ps = __shfl(p, s, 64);
      o = fmaf(ps, vt[(h * 24 + s) * 65 + lane], o);
    }
    st[row + 384 + h * 64 + lane] = o * inv;
  }
}

// ---------------------------------------------------------------------------
__global__ __launch_bounds__(256) void tglobal_attn(
    const float* __restrict__ qkvt, const float* __restrict__ q_agg,
    const float* __restrict__ tmp_map, float* __restrict__ st)
{
  __shared__ float kg[2 * 24 * 65];
  __shared__ float vg[2 * 24 * 65];
  __shared__ float tgx[12 * 128];
  const int b = blockIdx.x / NN;
  const int n = blockIdx.x % NN;
  const int tid = threadIdx.x;
  const int lane = tid & 63;
  const int wave = tid >> 6;
  for (int idx = tid; idx < 2 * 24 * 64; idx += 256) {
    int t = idx >> 7, hd = idx & 127, h = hd >> 6, d = hd & 63;
    size_t row = ((size_t)(b * TT + t) * NN + n) * 640;
    kg[(h * 24 + t) * 65 + d] = qkvt[row + 384 + h * 64 + d];
    vg[(h * 24 + t) * 65 + d] = qkvt[row + 512 + h * 64 + d];
  }
  __syncthreads();
  for (int r = wave; r < 24; r += 4) {
    int s = r >> 1, h = r & 1;
    float qv = q_agg[((size_t)n * 12 + s) * 128 + h * 64 + lane];
    int tc = lane < 24 ? lane : 23;
    float sc_ = 0.f;
    #pragma unroll
    for (int d = 0; d < 64; ++d) {
      float qd = __shfl(qv, d, 64);
      sc_ = fmaf(qd, kg[(h * 24 + tc) * 65 + d], sc_);
    }
    sc_ *= 0.125f;
    bool valid = lane < 24;
    float mx = wred_max(valid ? sc_ : -1e30f);
    float p = valid ? __expf(sc_ - mx) : 0.f;
    float inv = 1.f / wred_sum(p);
    float o = 0.f;
    #pragma unroll
    for (int t = 0; t < 24; ++t) {
      float pt = __shfl(p, t, 64);
      o = fmaf(pt, vg[(h * 24 + t) * 65 + lane], o);
    }
    tgx[s * 128 + h * 64 + lane] = o * inv;
  }
  __syncthreads();
  for (int idx = tid; idx < 24 * 128; idx += 256) {
    int t = idx >> 7, c = idx & 127;
    const float* tm = tmp_map + ((size_t)(b * NN + n) * TT + t) * 12;
    float acc = 0.f;
    #pragma unroll
    for (int s = 0; s < 12; ++s) acc = fmaf(tm[s], tgx[s * 128 + c], acc);
    st[((size_t)(b * TT + t) * NN + n) * 640 + 512 + c] = acc;
  }
}

// ---------------------------------------------------------------------------
__global__ __launch_bounds__(256) void agg_attn(
    const float* __restrict__ qkva, float* __restrict__ sx, int Ni)
{
  __shared__ float kT[64 * 64];
  __shared__ float vl[64 * 64];
  const int h = blockIdx.x & 1;
  const int bt = blockIdx.x >> 1;
  const int tid = threadIdx.x;
  const int lane = tid & 63;
  const int wave = tid >> 6;
  for (int idx = tid; idx < Ni * 64; idx += 256) {
    int m = idx >> 6, d = idx & 63;
    size_t row = (size_t)(bt * Ni + m) * 384;
    kT[d * Ni + m] = qkva[row + 128 + h * 64 + d];
    vl[m * 64 + d] = qkva[row + 256 + h * 64 + d];
  }
  __syncthreads();
  int mc = lane < Ni ? lane : Ni - 1;
  bool valid = lane < Ni;
  for (int n = wave; n < Ni; n += 4) {
    float qv = qkva[(size_t)(bt * Ni + n) * 384 + h * 64 + lane];
    float sc_ = 0.f;
    #pragma unroll
    for (int d = 0; d < 64; ++d) {
      float qd = __shfl(qv, d, 64);
      sc_ = fmaf(qd, kT[d * Ni + mc], sc_);
    }
    sc_ *= 0.125f;
    float mx = wred_max(valid ? sc_ : -1e30f);
    float p = valid ? __expf(sc_ - mx) : 0.f;
    float inv = 1.f / wred_sum(p);
    float o = 0.f;
    for (int m = 0; m < Ni; ++m) {
      float pm = __shfl(p, m, 64);
      o = fmaf(pm, vl[m * 64 + lane], o);
    }
    sx[(size_t)(bt * Ni + n) * 128 + h * 64 + lane] = o * inv;
  }
}

// ---------------------------------------------------------------------------
__global__ __launch_bounds__(256) void mmap_kernel(
    const float* __restrict__ sx0, const float* __restrict__ sx1,
    const float* __restrict__ M0, const float* __restrict__ M1,
    float* __restrict__ sg)
{
  __shared__ float s0[32 * 128];
  __shared__ float s1[64 * 128];
  const int bt = blockIdx.x;
  const int chunk = blockIdx.y;
  const int tid = threadIdx.x;
  for (int idx = tid; idx < 32 * 128; idx += 256) s0[idx] = sx0[(size_t)bt * 32 * 128 + idx];
  for (int idx = tid; idx < 64 * 128; idx += 256) s1[idx] = sx1[(size_t)bt * 64 * 128 + idx];
  __syncthreads();
  for (int idx = tid; idx < 88 * 128; idx += 256) {
    int n = chunk * 88 + (idx >> 7);
    if (n < NN) {
      int c = idx & 127;
      float acc = 0.f;
      #pragma unroll
      for (int m = 0; m < 32; ++m) acc = fmaf(M0[m * NN + n], s0[m * 128 + c], acc);
      #pragma unroll
      for (int m = 0; m < 64; ++m) acc = fmaf(M1[m * NN + n], s1[m * 128 + c], acc);
      sg[((size_t)bt * NN + n) * 128 + c] = acc;
    }
  }
}

// ---------------------------------------------------------------------------
extern "C" void kernel_launch(void* const* d_in, const int* in_sizes, int n_in,
                              void* d_out, int out_size, void* d_ws, size_t ws_size,
                              hipStream_t stream)
{
  const float* x       = (const float*)d_in[0];
  const float* agg_x0  = (const float*)d_in[1];
  const float* agg_x1  = (const float*)d_in[2];
  const float* tmp_map = (const float*)d_in[3];
  const float* Wq_s = (const float*)d_in[4];
  const float* Wk_s = (const float*)d_in[5];
  const float* Wv_s = (const float*)d_in[6];
  const float* lq1 = (const float*)d_in[7];
  const float* lk1 = (const float*)d_in[8];
  const float* lq2 = (const float*)d_in[9];
  const float* lk2 = (const float*)d_in[10];
  const float* ln_g = (const float*)d_in[11];
  const float* ln_b = (const float*)d_in[12];
  const float* Wq_a0 = (const float*)d_in[13];
  const float* Wk_a0 = (const float*)d_in[14];
  const float* Wv_a0 = (const float*)d_in[15];
  const float* Wq_a1 = (const float*)d_in[16];
  const float* Wk_a1 = (const float*)d_in[17];
  const float* Wv_a1 = (const float*)d_in[18];
  const float* M0   = (const float*)d_in[19];
  const float* M1   = (const float*)d_in[20];
  const float* Wagg = (const float*)d_in[21];
  const float* bagg = (const float*)d_in[22];
  const float* Wq_t = (const float*)d_in[23];
  const float* Wk_t = (const float*)d_in[24];
  const float* Wv_t = (const float*)d_in[25];
  const float* q_agg = (const float*)d_in[26];
  const float* Wk_tg = (const float*)d_in[27];
  const float* Wv_tg = (const float*)d_in[28];
  const float* Wout  = (const float*)d_in[29];
  const float* bout  = (const float*)d_in[30];
  float* ws  = (float*)d_ws;
  float* out = (float*)d_out;

  const size_t o_Wa0  = 720896;
  const size_t o_Wa1  = 917504;
  const size_t o_lam  = 1114112;
  const size_t o_A    = 1114128;
  const size_t o_qkvt = o_A + 38780928;
  const size_t o_B    = o_qkvt + 32317440;

  float* W_all = ws;
  float* W_a0  = ws + o_Wa0;
  float* W_a1  = ws + o_Wa1;
  float* lamp  = ws + o_lam;
  float* qkv_s = ws + o_A;
  float* st    = ws + o_A;
  float* qkvt  = ws + o_qkvt;
  float* a1    = ws + o_B;
  float* qkva0 = ws + o_B;
  float* qkva1 = qkva0 + 2359296;
  float* sx0   = qkva0 + 7077888;
  float* sx1   = qkva0 + 7864320;
  float* sgp   = qkva0 + 9437184;

  auto cp = [&](float* dst, const float* src, size_t nfl) {
    (void)hipMemcpyAsync(dst, src, nfl * sizeof(float), hipMemcpyDeviceToDevice, stream);
  };
  cp(W_all + 0,      Wq_s, 131072);
  cp(W_all + 131072, Wk_s, 131072);
  cp(W_all + 262144, Wv_s, 131072);
  cp(W_all + 393216, Wq_t, 65536);
  cp(W_all + 458752, Wk_t, 65536);
  cp(W_all + 524288, Wv_t, 65536);
  cp(W_all + 589824, Wk_tg, 65536);
  cp(W_all + 655360, Wv_tg, 65536);
  cp(W_a0 + 0,      Wq_a0, 65536);
  cp(W_a0 + 65536,  Wk_a0, 65536);
  cp(W_a0 + 131072, Wv_a0, 65536);
  cp(W_a1 + 0,      Wq_a1, 65536);
  cp(W_a1 + 65536,  Wk_a1, 65536);
  cp(W_a1 + 131072, Wv_a1, 65536);

  hipLaunchKernelGGL(lam_kernel, dim3(1), dim3(64), 0, stream, lq1, lk1, lq2, lk2, lamp);

  const int Mx = 50496;
  hipLaunchKernelGGL(gemm_nt_mfma, dim3(395, 6), dim3(256), 0, stream,
                     x, W_all, (const float*)nullptr, qkv_s, Mx, 768, 512, 768);
  hipLaunchKernelGGL(diff_attn, dim3(768, 2), dim3(256), 0, stream, qkv_s, a1);
  hipLaunchKernelGGL(gemm_nt_mfma, dim3(395, 5), dim3(256), 0, stream,
                     x, W_all + 393216, (const float*)nullptr, qkvt, Mx, 640, 512, 640);
  hipLaunchKernelGGL(diff_ln, dim3(Mx), dim3(256), 0, stream,
                     a1, a1 + 12926976, lamp, ln_g, ln_b, st);
  hipLaunchKernelGGL(temporal_attn, dim3(8 * NN), dim3(256), 0, stream, qkvt, st);
  hipLaunchKernelGGL(tglobal_attn, dim3(8 * NN), dim3(256), 0, stream, qkvt, q_agg, tmp_map, st);
  hipLaunchKernelGGL(gemm_nt_mfma, dim3(48, 3), dim3(256), 0, stream,
                     agg_x0, W_a0, (const float*)nullptr, qkva0, 6144, 384, 512, 384);
  hipLaunchKernelGGL(gemm_nt_mfma, dim3(96, 3), dim3(256), 0, stream,
                     agg_x1, W_a1, (const float*)nullptr, qkva1, 12288, 384, 512, 384);
  hipLaunchKernelGGL(agg_attn, dim3(384), dim3(256), 0, stream, qkva0, sx0, 32);
  hipLaunchKernelGGL(agg_attn, dim3(384), dim3(256), 0, stream, qkva1, sx1, 64);
  hipLaunchKernelGGL(mmap_kernel, dim3(192, 3), dim3(256), 0, stream, sx0, sx1, M0, M1, sgp);
  hipLaunchKernelGGL(gemm_nt_mfma, dim3(395, 1), dim3(256), 0, stream,
                     sgp, Wagg, bagg, st + 256, Mx, 128, 128, 640);
  hipLaunchKernelGGL(gemm_nt_mfma, dim3(395, 4), dim3(256), 0, stream,
                     st, Wout, bout, out, Mx, 512, 640, 512);
}

// Round 3
// 1266.155 us; speedup vs baseline: 2.4695x; 1.3412x over previous
//
#include <hip/hip_runtime.h>

#define NN 263
#define TT 24

typedef __fp16 h2 __attribute__((ext_vector_type(2)));
typedef _Float16 f16x4 __attribute__((ext_vector_type(4)));
typedef _Float16 f16x8 __attribute__((ext_vector_type(8)));
typedef float f32x4 __attribute__((ext_vector_type(4)));

static __device__ __forceinline__ float wred_sum(float v) {
  #pragma unroll
  for (int off = 32; off >= 1; off >>= 1) v += __shfl_xor(v, off, 64);
  return v;
}
static __device__ __forceinline__ float wred_max(float v) {
  #pragma unroll
  for (int off = 32; off >= 1; off >>= 1) v = fmaxf(v, __shfl_xor(v, off, 64));
  return v;
}

// ---------------------------------------------------------------------------
// f16-MFMA NT GEMM: C[m,n] = sum_k A[m,k]*W[n,k] (+bias[n])
// 128x128 tile, BK=32, 4 waves 2x2, each wave 64x64 via 4x4 frags of
// v_mfma_f32_16x16x32_f16 (fp32 accumulate). Verified R0/R1 (passed).
// ---------------------------------------------------------------------------
__global__ __launch_bounds__(256) void gemm_nt_mfma(
    const float* __restrict__ A, const float* __restrict__ W,
    const float* __restrict__ bias, float* __restrict__ C,
    int M, int N, int K, int ldc)
{
  __shared__ _Float16 As[128][40];
  __shared__ _Float16 Bs[128][40];
  const int tid  = threadIdx.x;
  const int lane = tid & 63;
  const int wave = tid >> 6;
  const int wr = wave >> 1, wc = wave & 1;
  const int bm = blockIdx.x * 128;
  const int bn = blockIdx.y * 128;

  const int srow = tid >> 3;
  const int skq  = (tid & 7) * 4;
  const float* aptr[4];
  const float* bptr[4];
  #pragma unroll
  for (int l = 0; l < 4; ++l) {
    int gm = bm + srow + 32 * l; if (gm > M - 1) gm = M - 1;
    aptr[l] = A + (size_t)gm * K + skq;
    int gn = bn + srow + 32 * l;
    bptr[l] = W + (size_t)gn * K + skq;
  }

  f32x4 acc[4][4];
  #pragma unroll
  for (int i = 0; i < 4; ++i)
    #pragma unroll
    for (int j = 0; j < 4; ++j) {
      acc[i][j].x = 0.f; acc[i][j].y = 0.f; acc[i][j].z = 0.f; acc[i][j].w = 0.f;
    }

  const int fr = lane & 15;
  const int fk = (lane >> 4) * 8;

  float4 av[4], bv[4];
  #pragma unroll
  for (int l = 0; l < 4; ++l) {
    av[l] = *(const float4*)(aptr[l]);
    bv[l] = *(const float4*)(bptr[l]);
  }

  for (int k0 = 0; k0 < K; k0 += 32) {
    #pragma unroll
    for (int l = 0; l < 4; ++l) {
      f16x4 a4, b4;
      a4.x = (_Float16)av[l].x; a4.y = (_Float16)av[l].y;
      a4.z = (_Float16)av[l].z; a4.w = (_Float16)av[l].w;
      b4.x = (_Float16)bv[l].x; b4.y = (_Float16)bv[l].y;
      b4.z = (_Float16)bv[l].z; b4.w = (_Float16)bv[l].w;
      *(f16x4*)&As[srow + 32 * l][skq] = a4;
      *(f16x4*)&Bs[srow + 32 * l][skq] = b4;
    }
    __syncthreads();

    if (k0 + 32 < K) {
      #pragma unroll
      for (int l = 0; l < 4; ++l) {
        av[l] = *(const float4*)(aptr[l] + k0 + 32);
        bv[l] = *(const float4*)(bptr[l] + k0 + 32);
      }
    }

    f16x8 af[4], bf[4];
    #pragma unroll
    for (int mi = 0; mi < 4; ++mi)
      af[mi] = *(const f16x8*)&As[wr * 64 + mi * 16 + fr][fk];
    #pragma unroll
    for (int ni = 0; ni < 4; ++ni)
      bf[ni] = *(const f16x8*)&Bs[wc * 64 + ni * 16 + fr][fk];
    #pragma unroll
    for (int mi = 0; mi < 4; ++mi)
      #pragma unroll
      for (int ni = 0; ni < 4; ++ni)
        acc[mi][ni] = __builtin_amdgcn_mfma_f32_16x16x32_f16(
            af[mi], bf[ni], acc[mi][ni], 0, 0, 0);
    __syncthreads();
  }

  #pragma unroll
  for (int mi = 0; mi < 4; ++mi) {
    int rb = bm + wr * 64 + mi * 16 + (lane >> 4) * 4;
    #pragma unroll
    for (int r = 0; r < 4; ++r) {
      int gm = rb + r;
      if (gm < M) {
        float* crow = C + (size_t)gm * ldc + bn + wc * 64 + fr;
        #pragma unroll
        for (int ni = 0; ni < 4; ++ni) {
          float v = acc[mi][ni][r];
          if (bias) v += bias[bn + wc * 64 + ni * 16 + fr];
          crow[ni * 16] = v;
        }
      }
    }
  }
}

// ---------------------------------------------------------------------------
__global__ void lam_kernel(const float* __restrict__ lq1, const float* __restrict__ lk1,
                           const float* __restrict__ lq2, const float* __restrict__ lk2,
                           float* __restrict__ out) {
  int lane = threadIdx.x;
  float v1 = lane < 32 ? lq1[lane] * lk1[lane] : 0.f;
  float v2 = lane < 32 ? lq2[lane] * lk2[lane] : 0.f;
  v1 = wred_sum(v1);
  v2 = wred_sum(v2);
  if (lane == 0) out[0] = expf(v1) - expf(v2) + 0.2f;
}

// ---------------------------------------------------------------------------
// Differential self-attention, MFMA version (NaN fix: Vt pad zeroed).
// One block per (bt,h), 8 waves. 34 wave-tasks = 17 q-row-chunks x 2 halves.
// Swapped QK^T: S^T = mfma(A=K_rows, B=Q_rows) -> lane's softmax reduce over
// k is 68 in-lane values + shfl_xor(16,32); P lands with row = lane&15 =
// exactly the PV A-fragment row. P staged per-wave in LDS as (k,k+1) f16
// pairs; V staged transposed the same way. All matmul on v_mfma_f32_16x16x32_f16.
// LDS: Ks 43.5KB + Vt 37.9KB + Pb 75.8KB = 157KB -> 1 block/CU, 2 waves/SIMD.
// ---------------------------------------------------------------------------
__global__ __launch_bounds__(512, 2) void diff_attn(
    const float* __restrict__ qkv, float* __restrict__ aout)
{
  __shared__ _Float16 Ks[2][272][40];   // [half][k-row][d(32)+pad8]
  __shared__ h2 Vt[64][148];            // Vt[d][kp] = (V[2kp][d], V[2kp+1][d])
  __shared__ h2 Pb[8][16][148];         // per-wave P: [qrow(16)][kp], pad zeroed

  const int h  = blockIdx.x & 3;
  const int bt = blockIdx.x >> 2;
  const int tid = threadIdx.x;
  const int lane = tid & 63;
  const int wave = tid >> 6;
  const int fr = lane & 15;             // fragment row/col index
  const int kb = (lane >> 4) * 4;       // C-layout row part / kp offset
  const float* base = qkv + (size_t)bt * NN * 768;

  union H4 { f16x4 v; h2 h[2]; };
  union H8 { f16x8 v; h2 h[4]; };

  // ---- stage K (both 32-col halves) as f16, rows padded/clamped to 272 ----
  for (int idx = tid; idx < 272 * 16; idx += 512) {
    int row = idx >> 4, q = idx & 15;
    int sr = row < NN ? row : NN - 1;
    float4 kv = *(const float4*)(base + (size_t)sr * 768 + 256 + h * 64 + q * 4);
    H4 t;
    t.h[0] = __builtin_amdgcn_cvt_pkrtz(kv.x, kv.y);
    t.h[1] = __builtin_amdgcn_cvt_pkrtz(kv.z, kv.w);
    *(f16x4*)&Ks[q >> 3][row][(q & 7) * 4] = t.v;
  }
  // ---- stage V transposed as (k,k+1) h2 pairs ----
  for (int idx = tid; idx < 136 * 16; idx += 512) {
    int mp = idx >> 4, dq = (idx & 15) * 4;
    int m0 = 2 * mp, m1 = 2 * mp + 1;
    if (m0 > NN - 1) m0 = NN - 1;
    if (m1 > NN - 1) m1 = NN - 1;
    float4 a = *(const float4*)(base + (size_t)m0 * 768 + 512 + h * 64 + dq);
    float4 b = *(const float4*)(base + (size_t)m1 * 768 + 512 + h * 64 + dq);
    Vt[dq + 0][mp] = __builtin_amdgcn_cvt_pkrtz(a.x, b.x);
    Vt[dq + 1][mp] = __builtin_amdgcn_cvt_pkrtz(a.y, b.y);
    Vt[dq + 2][mp] = __builtin_amdgcn_cvt_pkrtz(a.z, b.z);
    Vt[dq + 3][mp] = __builtin_amdgcn_cvt_pkrtz(a.w, b.w);
  }
  // ---- zero Vt pad columns kp=136..147 (PV reads up to 143; LDS is NOT
  // zero-initialized -> garbage here gave 0*NaN = NaN in R2) ----
  {
    h2 z; z.x = (__fp16)0.f; z.y = (__fp16)0.f;
    for (int idx = tid; idx < 64 * 12; idx += 512)
      Vt[idx / 12][136 + idx % 12] = z;
  }
  // zero this wave's P pad columns kp=136..147
  {
    h2 z; z.x = (__fp16)0.f; z.y = (__fp16)0.f;
    #pragma unroll
    for (int t = 0; t < 3; ++t) Pb[wave][fr][136 + (kb >> 2) * 3 + t] = z;
  }
  __syncthreads();

  const float scq = 0.17677669529663687f;  // 1/sqrt(32)

  // 34 tasks: task = chunk*2 + half
  for (int task = wave; task < 34; task += 8) {
    const int chunk = task >> 1;
    const int half  = task & 1;

    // Q fragment: B[n=fr][d = kb*2 + j] for this half
    int qsrc = chunk * 16 + fr; if (qsrc > NN - 1) qsrc = NN - 1;
    const float* qr = base + (size_t)qsrc * 768 + h * 64 + half * 32 + kb * 2;
    f16x8 qf;
    {
      float4 a = *(const float4*)(qr);
      float4 b = *(const float4*)(qr + 4);
      H8 t;
      t.h[0] = __builtin_amdgcn_cvt_pkrtz(a.x, a.y);
      t.h[1] = __builtin_amdgcn_cvt_pkrtz(a.z, a.w);
      t.h[2] = __builtin_amdgcn_cvt_pkrtz(b.x, b.y);
      t.h[3] = __builtin_amdgcn_cvt_pkrtz(b.z, b.w);
      qf = t.v;
    }

    // S^T tiles: C[m=k-row][n=q-row], 17 m-tiles, one 16x16x32 MFMA each
    f32x4 s[17];
    #pragma unroll
    for (int mt = 0; mt < 17; ++mt) {
      f16x8 af = *(const f16x8*)&Ks[half][mt * 16 + fr][kb * 2];
      f32x4 z4 = {0.f, 0.f, 0.f, 0.f};
      s[mt] = __builtin_amdgcn_mfma_f32_16x16x32_f16(af, qf, z4, 0, 0, 0);
    }

    // softmax over k for fixed q-row=fr: in-lane 68 values + xor 16,32
    float mx = -1e30f;
    #pragma unroll
    for (int mt = 0; mt < 17; ++mt)
      #pragma unroll
      for (int r = 0; r < 4; ++r) {
        float v = s[mt][r] * scq;
        if (mt * 16 + kb + r >= NN) v = -1e30f;
        s[mt][r] = v;
        mx = fmaxf(mx, v);
      }
    mx = fmaxf(mx, __shfl_xor(mx, 16, 64));
    mx = fmaxf(mx, __shfl_xor(mx, 32, 64));
    float sum = 0.f;
    #pragma unroll
    for (int mt = 0; mt < 17; ++mt)
      #pragma unroll
      for (int r = 0; r < 4; ++r) {
        float p = __expf(s[mt][r] - mx);
        s[mt][r] = p;
        sum += p;
      }
    sum += __shfl_xor(sum, 16, 64);
    sum += __shfl_xor(sum, 32, 64);
    float inv = 1.f / sum;

    // write P as (k,k+1) f16 pairs: kp = 8*mt + kb/2
    #pragma unroll
    for (int mt = 0; mt < 17; ++mt) {
      h2 lo = __builtin_amdgcn_cvt_pkrtz(s[mt][0] * inv, s[mt][1] * inv);
      h2 hi = __builtin_amdgcn_cvt_pkrtz(s[mt][2] * inv, s[mt][3] * inv);
      int kp = 8 * mt + (kb >> 1);
      Pb[wave][fr][kp]     = lo;
      Pb[wave][fr][kp + 1] = hi;
    }

    // PV: C[m=q-row][n=d], 9 K-steps of 32 (k padded to 288 with zero P)
    f32x4 o[4];
    #pragma unroll
    for (int nt = 0; nt < 4; ++nt) {
      o[nt].x = 0.f; o[nt].y = 0.f; o[nt].z = 0.f; o[nt].w = 0.f;
    }
    #pragma unroll
    for (int s9 = 0; s9 < 9; ++s9) {
      f16x8 pa = *(const f16x8*)&Pb[wave][fr][16 * s9 + kb];
      #pragma unroll
      for (int nt = 0; nt < 4; ++nt) {
        f16x8 vb = *(const f16x8*)&Vt[nt * 16 + fr][16 * s9 + kb];
        o[nt] = __builtin_amdgcn_mfma_f32_16x16x32_f16(pa, vb, o[nt], 0, 0, 0);
      }
    }

    // store: row = chunk*16 + kb + r, col d = nt*16 + fr
    float* ab = aout + (size_t)half * (50496ull * 256ull);
    #pragma unroll
    for (int r = 0; r < 4; ++r) {
      int qrow = chunk * 16 + kb + r;
      if (qrow < NN) {
        float* op = ab + ((size_t)(bt * NN + qrow) * 4 + h) * 64;
        #pragma unroll
        for (int nt = 0; nt < 4; ++nt) op[nt * 16 + fr] = o[nt][r];
      }
    }
  }
}

// ---------------------------------------------------------------------------
__global__ __launch_bounds__(256) void diff_ln(
    const float* __restrict__ a1, const float* __restrict__ a2,
    const float* __restrict__ lamp,
    const float* __restrict__ g, const float* __restrict__ b,
    float* __restrict__ st)
{
  const int btn = blockIdx.x;
  const int lane = threadIdx.x & 63;
  const int h = threadIdx.x >> 6;
  const float lam = lamp[0];
  size_t off = ((size_t)btn * 4 + h) * 64 + lane;
  float y = a1[off] - lam * a2[off];
  float mean = wred_sum(y) * (1.f / 64.f);
  float t = y - mean;
  float var = wred_sum(t * t) * (1.f / 64.f);
  float r = rsqrtf(var + 1e-5f);
  st[(size_t)btn * 640 + h * 64 + lane] = (t * r * g[lane] + b[lane]) * 0.8f;
}

// ---------------------------------------------------------------------------
__global__ __launch_bounds__(256) void temporal_attn(
    const float* __restrict__ qkvt, float* __restrict__ st)
{
  __shared__ float kt[2 * 24 * 65];
  __shared__ float vt[2 * 24 * 65];
  const int b = blockIdx.x / NN;
  const int n = blockIdx.x % NN;
  const int tid = threadIdx.x;
  const int lane = tid & 63;
  const int wave = tid >> 6;
  for (int idx = tid; idx < 2 * 24 * 64; idx += 256) {
    int t = idx >> 7, hd = idx & 127, h = hd >> 6, d = hd & 63;
    size_t row = ((size_t)(b * TT + t) * NN + n) * 640;
    kt[(h * 24 + t) * 65 + d] = qkvt[row + 128 + h * 64 + d];
    vt[(h * 24 + t) * 65 + d] = qkvt[row + 256 + h * 64 + d];
  }
  __syncthreads();
  for (int r = wave; r < 48; r += 4) {
    int t = r >> 1, h = r & 1;
    size_t row = ((size_t)(b * TT + t) * NN + n) * 640;
    float qv = qkvt[row + h * 64 + lane];
    int ss = lane < 24 ? lane : 23;
    float sc_ = 0.f;
    #pragma unroll
    for (int d = 0; d < 64; ++d) {
      float qd = __shfl(qv, d, 64);
      sc_ = fmaf(qd, kt[(h * 24 + ss) * 65 + d], sc_);
    }
    sc_ *= 0.125f;
    bool valid = lane < 24;
    float mx = wred_max(valid ? sc_ : -1e30f);
    float p = valid ? __expf(sc_ - mx) : 0.f;
    float inv = 1.f / wred_sum(p);
    float o = 0.f;
    #pragma unroll
    for (int s = 0; s < 24; ++s) {
      float ps = __shfl(p, s, 64);
      o = fmaf(ps, vt[(h * 24 + s) * 65 + lane], o);
    }
    st[row + 384 + h * 64 + lane] = o * inv;
  }
}

// ---------------------------------------------------------------------------
__global__ __launch_bounds__(256) void tglobal_attn(
    const float* __restrict__ qkvt, const float* __restrict__ q_agg,
    const float* __restrict__ tmp_map, float* __restrict__ st)
{
  __shared__ float kg[2 * 24 * 65];
  __shared__ float vg[2 * 24 * 65];
  __shared__ float tgx[12 * 128];
  const int b = blockIdx.x / NN;
  const int n = blockIdx.x % NN;
  const int tid = threadIdx.x;
  const int lane = tid & 63;
  const int wave = tid >> 6;
  for (int idx = tid; idx < 2 * 24 * 64; idx += 256) {
    int t = idx >> 7, hd = idx & 127, h = hd >> 6, d = hd & 63;
    size_t row = ((size_t)(b * TT + t) * NN + n) * 640;
    kg[(h * 24 + t) * 65 + d] = qkvt[row + 384 + h * 64 + d];
    vg[(h * 24 + t) * 65 + d] = qkvt[row + 512 + h * 64 + d];
  }
  __syncthreads();
  for (int r = wave; r < 24; r += 4) {
    int s = r >> 1, h = r & 1;
    float qv = q_agg[((size_t)n * 12 + s) * 128 + h * 64 + lane];
    int tc = lane < 24 ? lane : 23;
    float sc_ = 0.f;
    #pragma unroll
    for (int d = 0; d < 64; ++d) {
      float qd = __shfl(qv, d, 64);
      sc_ = fmaf(qd, kg[(h * 24 + tc) * 65 + d], sc_);
    }
    sc_ *= 0.125f;
    bool valid = lane < 24;
    float mx = wred_max(valid ? sc_ : -1e30f);
    float p = valid ? __expf(sc_ - mx) : 0.f;
    float inv = 1.f / wred_sum(p);
    float o = 0.f;
    #pragma unroll
    for (int t = 0; t < 24; ++t) {
      float pt = __shfl(p, t, 64);
      o = fmaf(pt, vg[(h * 24 + t) * 65 + lane], o);
    }
    tgx[s * 128 + h * 64 + lane] = o * inv;
  }
  __syncthreads();
  for (int idx = tid; idx < 24 * 128; idx += 256) {
    int t = idx >> 7, c = idx & 127;
    const float* tm = tmp_map + ((size_t)(b * NN + n) * TT + t) * 12;
    float acc = 0.f;
    #pragma unroll
    for (int s = 0; s < 12; ++s) acc = fmaf(tm[s], tgx[s * 128 + c], acc);
    st[((size_t)(b * TT + t) * NN + n) * 640 + 512 + c] = acc;
  }
}

// ---------------------------------------------------------------------------
__global__ __launch_bounds__(256) void agg_attn(
    const float* __restrict__ qkva, float* __restrict__ sx, int Ni)
{
  __shared__ float kT[64 * 64];
  __shared__ float vl[64 * 64];
  const int h = blockIdx.x & 1;
  const int bt = blockIdx.x >> 1;
  const int tid = threadIdx.x;
  const int lane = tid & 63;
  const int wave = tid >> 6;
  for (int idx = tid; idx < Ni * 64; idx += 256) {
    int m = idx >> 6, d = idx & 63;
    size_t row = (size_t)(bt * Ni + m) * 384;
    kT[d * Ni + m] = qkva[row + 128 + h * 64 + d];
    vl[m * 64 + d] = qkva[row + 256 + h * 64 + d];
  }
  __syncthreads();
  int mc = lane < Ni ? lane : Ni - 1;
  bool valid = lane < Ni;
  for (int n = wave; n < Ni; n += 4) {
    float qv = qkva[(size_t)(bt * Ni + n) * 384 + h * 64 + lane];
    float sc_ = 0.f;
    #pragma unroll
    for (int d = 0; d < 64; ++d) {
      float qd = __shfl(qv, d, 64);
      sc_ = fmaf(qd, kT[d * Ni + mc], sc_);
    }
    sc_ *= 0.125f;
    float mx = wred_max(valid ? sc_ : -1e30f);
    float p = valid ? __expf(sc_ - mx) : 0.f;
    float inv = 1.f / wred_sum(p);
    float o = 0.f;
    for (int m = 0; m < Ni; ++m) {
      float pm = __shfl(p, m, 64);
      o = fmaf(pm, vl[m * 64 + lane], o);
    }
    sx[(size_t)(bt * Ni + n) * 128 + h * 64 + lane] = o * inv;
  }
}

// ---------------------------------------------------------------------------
__global__ __launch_bounds__(256) void mmap_kernel(
    const float* __restrict__ sx0, const float* __restrict__ sx1,
    const float* __restrict__ M0, const float* __restrict__ M1,
    float* __restrict__ sg)
{
  __shared__ float s0[32 * 128];
  __shared__ float s1[64 * 128];
  const int bt = blockIdx.x;
  const int chunk = blockIdx.y;
  const int tid = threadIdx.x;
  for (int idx = tid; idx < 32 * 128; idx += 256) s0[idx] = sx0[(size_t)bt * 32 * 128 + idx];
  for (int idx = tid; idx < 64 * 128; idx += 256) s1[idx] = sx1[(size_t)bt * 64 * 128 + idx];
  __syncthreads();
  for (int idx = tid; idx < 88 * 128; idx += 256) {
    int n = chunk * 88 + (idx >> 7);
    if (n < NN) {
      int c = idx & 127;
      float acc = 0.f;
      #pragma unroll
      for (int m = 0; m < 32; ++m) acc = fmaf(M0[m * NN + n], s0[m * 128 + c], acc);
      #pragma unroll
      for (int m = 0; m < 64; ++m) acc = fmaf(M1[m * NN + n], s1[m * 128 + c], acc);
      sg[((size_t)bt * NN + n) * 128 + c] = acc;
    }
  }
}

// ---------------------------------------------------------------------------
extern "C" void kernel_launch(void* const* d_in, const int* in_sizes, int n_in,
                              void* d_out, int out_size, void* d_ws, size_t ws_size,
                              hipStream_t stream)
{
  const float* x       = (const float*)d_in[0];
  const float* agg_x0  = (const float*)d_in[1];
  const float* agg_x1  = (const float*)d_in[2];
  const float* tmp_map = (const float*)d_in[3];
  const float* Wq_s = (const float*)d_in[4];
  const float* Wk_s = (const float*)d_in[5];
  const float* Wv_s = (const float*)d_in[6];
  const float* lq1 = (const float*)d_in[7];
  const float* lk1 = (const float*)d_in[8];
  const float* lq2 = (const float*)d_in[9];
  const float* lk2 = (const float*)d_in[10];
  const float* ln_g = (const float*)d_in[11];
  const float* ln_b = (const float*)d_in[12];
  const float* Wq_a0 = (const float*)d_in[13];
  const float* Wk_a0 = (const float*)d_in[14];
  const float* Wv_a0 = (const float*)d_in[15];
  const float* Wq_a1 = (const float*)d_in[16];
  const float* Wk_a1 = (const float*)d_in[17];
  const float* Wv_a1 = (const float*)d_in[18];
  const float* M0   = (const float*)d_in[19];
  const float* M1   = (const float*)d_in[20];
  const float* Wagg = (const float*)d_in[21];
  const float* bagg = (const float*)d_in[22];
  const float* Wq_t = (const float*)d_in[23];
  const float* Wk_t = (const float*)d_in[24];
  const float* Wv_t = (const float*)d_in[25];
  const float* q_agg = (const float*)d_in[26];
  const float* Wk_tg = (const float*)d_in[27];
  const float* Wv_tg = (const float*)d_in[28];
  const float* Wout  = (const float*)d_in[29];
  const float* bout  = (const float*)d_in[30];
  float* ws  = (float*)d_ws;
  float* out = (float*)d_out;

  const size_t o_Wa0  = 720896;
  const size_t o_Wa1  = 917504;
  const size_t o_lam  = 1114112;
  const size_t o_A    = 1114128;
  const size_t o_qkvt = o_A + 38780928;
  const size_t o_B    = o_qkvt + 32317440;

  float* W_all = ws;
  float* W_a0  = ws + o_Wa0;
  float* W_a1  = ws + o_Wa1;
  float* lamp  = ws + o_lam;
  float* qkv_s = ws + o_A;
  float* st    = ws + o_A;
  float* qkvt  = ws + o_qkvt;
  float* a1    = ws + o_B;
  float* qkva0 = ws + o_B;
  float* qkva1 = qkva0 + 2359296;
  float* sx0   = qkva0 + 7077888;
  float* sx1   = qkva0 + 7864320;
  float* sgp   = qkva0 + 9437184;

  auto cp = [&](float* dst, const float* src, size_t nfl) {
    (void)hipMemcpyAsync(dst, src, nfl * sizeof(float), hipMemcpyDeviceToDevice, stream);
  };
  cp(W_all + 0,      Wq_s, 131072);
  cp(W_all + 131072, Wk_s, 131072);
  cp(W_all + 262144, Wv_s, 131072);
  cp(W_all + 393216, Wq_t, 65536);
  cp(W_all + 458752, Wk_t, 65536);
  cp(W_all + 524288, Wv_t, 65536);
  cp(W_all + 589824, Wk_tg, 65536);
  cp(W_all + 655360, Wv_tg, 65536);
  cp(W_a0 + 0,      Wq_a0, 65536);
  cp(W_a0 + 65536,  Wk_a0, 65536);
  cp(W_a0 + 131072, Wv_a0, 65536);
  cp(W_a1 + 0,      Wq_a1, 65536);
  cp(W_a1 + 65536,  Wk_a1, 65536);
  cp(W_a1 + 131072, Wv_a1, 65536);

  hipLaunchKernelGGL(lam_kernel, dim3(1), dim3(64), 0, stream, lq1, lk1, lq2, lk2, lamp);

  const int Mx = 50496;
  hipLaunchKernelGGL(gemm_nt_mfma, dim3(395, 6), dim3(256), 0, stream,
                     x, W_all, (const float*)nullptr, qkv_s, Mx, 768, 512, 768);
  hipLaunchKernelGGL(diff_attn, dim3(768), dim3(512), 0, stream, qkv_s, a1);
  hipLaunchKernelGGL(gemm_nt_mfma, dim3(395, 5), dim3(256), 0, stream,
                     x, W_all + 393216, (const float*)nullptr, qkvt, Mx, 640, 512, 640);
  hipLaunchKernelGGL(diff_ln, dim3(Mx), dim3(256), 0, stream,
                     a1, a1 + 12926976, lamp, ln_g, ln_b, st);
  hipLaunchKernelGGL(temporal_attn, dim3(8 * NN), dim3(256), 0, stream, qkvt, st);
  hipLaunchKernelGGL(tglobal_attn, dim3(8 * NN), dim3(256), 0, stream, qkvt, q_agg, tmp_map, st);
  hipLaunchKernelGGL(gemm_nt_mfma, dim3(48, 3), dim3(256), 0, stream,
                     agg_x0, W_a0, (const float*)nullptr, qkva0, 6144, 384, 512, 384);
  hipLaunchKernelGGL(gemm_nt_mfma, dim3(96, 3), dim3(256), 0, stream,
                     agg_x1, W_a1, (const float*)nullptr, qkva1, 12288, 384, 512, 384);
  hipLaunchKernelGGL(agg_attn, dim3(384), dim3(256), 0, stream, qkva0, sx0, 32);
  hipLaunchKernelGGL(agg_attn, dim3(384), dim3(256), 0, stream, qkva1, sx1, 64);
  hipLaunchKernelGGL(mmap_kernel, dim3(192, 3), dim3(256), 0, stream, sx0, sx1, M0, M1, sgp);
  hipLaunchKernelGGL(gemm_nt_mfma, dim3(395, 1), dim3(256), 0, stream,
                     sgp, Wagg, bagg, st + 256, Mx, 128, 128, 640);
  hipLaunchKernelGGL(gemm_nt_mfma, dim3(395, 4), dim3(256), 0, stream,
                     st, Wout, bout, out, Mx, 512, 640, 512);
}

// Round 4
// 1108.153 us; speedup vs baseline: 2.8216x; 1.1426x over previous
//
#include <hip/hip_runtime.h>

#define NN 263
#define TT 24

typedef __fp16 h2 __attribute__((ext_vector_type(2)));
typedef _Float16 f16x4 __attribute__((ext_vector_type(4)));
typedef _Float16 f16x8 __attribute__((ext_vector_type(8)));
typedef float f32x4 __attribute__((ext_vector_type(4)));

static __device__ __forceinline__ float wred_sum(float v) {
  #pragma unroll
  for (int off = 32; off >= 1; off >>= 1) v += __shfl_xor(v, off, 64);
  return v;
}
static __device__ __forceinline__ float wred_max(float v) {
  #pragma unroll
  for (int off = 32; off >= 1; off >>= 1) v = fmaxf(v, __shfl_xor(v, off, 64));
  return v;
}

// ---------------------------------------------------------------------------
// f16-MFMA NT GEMM: C[m,n] = sum_k A[m,k]*W[n,k] (+bias[n])
// 128x128 tile, BK=32, 4 waves 2x2, each wave 64x64 via 4x4 frags of
// v_mfma_f32_16x16x32_f16 (fp32 accumulate). Verified R0/R1/R3 (passed).
// ---------------------------------------------------------------------------
__global__ __launch_bounds__(256) void gemm_nt_mfma(
    const float* __restrict__ A, const float* __restrict__ W,
    const float* __restrict__ bias, float* __restrict__ C,
    int M, int N, int K, int ldc)
{
  __shared__ _Float16 As[128][40];
  __shared__ _Float16 Bs[128][40];
  const int tid  = threadIdx.x;
  const int lane = tid & 63;
  const int wave = tid >> 6;
  const int wr = wave >> 1, wc = wave & 1;
  const int bm = blockIdx.x * 128;
  const int bn = blockIdx.y * 128;

  const int srow = tid >> 3;
  const int skq  = (tid & 7) * 4;
  const float* aptr[4];
  const float* bptr[4];
  #pragma unroll
  for (int l = 0; l < 4; ++l) {
    int gm = bm + srow + 32 * l; if (gm > M - 1) gm = M - 1;
    aptr[l] = A + (size_t)gm * K + skq;
    int gn = bn + srow + 32 * l;
    bptr[l] = W + (size_t)gn * K + skq;
  }

  f32x4 acc[4][4];
  #pragma unroll
  for (int i = 0; i < 4; ++i)
    #pragma unroll
    for (int j = 0; j < 4; ++j) {
      acc[i][j].x = 0.f; acc[i][j].y = 0.f; acc[i][j].z = 0.f; acc[i][j].w = 0.f;
    }

  const int fr = lane & 15;
  const int fk = (lane >> 4) * 8;

  float4 av[4], bv[4];
  #pragma unroll
  for (int l = 0; l < 4; ++l) {
    av[l] = *(const float4*)(aptr[l]);
    bv[l] = *(const float4*)(bptr[l]);
  }

  for (int k0 = 0; k0 < K; k0 += 32) {
    #pragma unroll
    for (int l = 0; l < 4; ++l) {
      f16x4 a4, b4;
      a4.x = (_Float16)av[l].x; a4.y = (_Float16)av[l].y;
      a4.z = (_Float16)av[l].z; a4.w = (_Float16)av[l].w;
      b4.x = (_Float16)bv[l].x; b4.y = (_Float16)bv[l].y;
      b4.z = (_Float16)bv[l].z; b4.w = (_Float16)bv[l].w;
      *(f16x4*)&As[srow + 32 * l][skq] = a4;
      *(f16x4*)&Bs[srow + 32 * l][skq] = b4;
    }
    __syncthreads();

    if (k0 + 32 < K) {
      #pragma unroll
      for (int l = 0; l < 4; ++l) {
        av[l] = *(const float4*)(aptr[l] + k0 + 32);
        bv[l] = *(const float4*)(bptr[l] + k0 + 32);
      }
    }

    f16x8 af[4], bf[4];
    #pragma unroll
    for (int mi = 0; mi < 4; ++mi)
      af[mi] = *(const f16x8*)&As[wr * 64 + mi * 16 + fr][fk];
    #pragma unroll
    for (int ni = 0; ni < 4; ++ni)
      bf[ni] = *(const f16x8*)&Bs[wc * 64 + ni * 16 + fr][fk];
    #pragma unroll
    for (int mi = 0; mi < 4; ++mi)
      #pragma unroll
      for (int ni = 0; ni < 4; ++ni)
        acc[mi][ni] = __builtin_amdgcn_mfma_f32_16x16x32_f16(
            af[mi], bf[ni], acc[mi][ni], 0, 0, 0);
    __syncthreads();
  }

  #pragma unroll
  for (int mi = 0; mi < 4; ++mi) {
    int rb = bm + wr * 64 + mi * 16 + (lane >> 4) * 4;
    #pragma unroll
    for (int r = 0; r < 4; ++r) {
      int gm = rb + r;
      if (gm < M) {
        float* crow = C + (size_t)gm * ldc + bn + wc * 64 + fr;
        #pragma unroll
        for (int ni = 0; ni < 4; ++ni) {
          float v = acc[mi][ni][r];
          if (bias) v += bias[bn + wc * 64 + ni * 16 + fr];
          crow[ni * 16] = v;
        }
      }
    }
  }
}

// ---------------------------------------------------------------------------
__global__ void lam_kernel(const float* __restrict__ lq1, const float* __restrict__ lk1,
                           const float* __restrict__ lq2, const float* __restrict__ lk2,
                           float* __restrict__ out) {
  int lane = threadIdx.x;
  float v1 = lane < 32 ? lq1[lane] * lk1[lane] : 0.f;
  float v2 = lane < 32 ? lq2[lane] * lk2[lane] : 0.f;
  v1 = wred_sum(v1);
  v2 = wred_sum(v2);
  if (lane == 0) out[0] = expf(v1) - expf(v2) + 0.2f;
}

// ---------------------------------------------------------------------------
// Differential self-attention, MFMA version (verified R3).
// ---------------------------------------------------------------------------
__global__ __launch_bounds__(512, 2) void diff_attn(
    const float* __restrict__ qkv, float* __restrict__ aout)
{
  __shared__ _Float16 Ks[2][272][40];   // [half][k-row][d(32)+pad8]
  __shared__ h2 Vt[64][148];            // Vt[d][kp] = (V[2kp][d], V[2kp+1][d])
  __shared__ h2 Pb[8][16][148];         // per-wave P: [qrow(16)][kp], pad zeroed

  const int h  = blockIdx.x & 3;
  const int bt = blockIdx.x >> 2;
  const int tid = threadIdx.x;
  const int lane = tid & 63;
  const int wave = tid >> 6;
  const int fr = lane & 15;             // fragment row/col index
  const int kb = (lane >> 4) * 4;       // C-layout row part / kp offset
  const float* base = qkv + (size_t)bt * NN * 768;

  union H4 { f16x4 v; h2 h[2]; };
  union H8 { f16x8 v; h2 h[4]; };

  // ---- stage K (both 32-col halves) as f16, rows padded/clamped to 272 ----
  for (int idx = tid; idx < 272 * 16; idx += 512) {
    int row = idx >> 4, q = idx & 15;
    int sr = row < NN ? row : NN - 1;
    float4 kv = *(const float4*)(base + (size_t)sr * 768 + 256 + h * 64 + q * 4);
    H4 t;
    t.h[0] = __builtin_amdgcn_cvt_pkrtz(kv.x, kv.y);
    t.h[1] = __builtin_amdgcn_cvt_pkrtz(kv.z, kv.w);
    *(f16x4*)&Ks[q >> 3][row][(q & 7) * 4] = t.v;
  }
  // ---- stage V transposed as (k,k+1) h2 pairs ----
  for (int idx = tid; idx < 136 * 16; idx += 512) {
    int mp = idx >> 4, dq = (idx & 15) * 4;
    int m0 = 2 * mp, m1 = 2 * mp + 1;
    if (m0 > NN - 1) m0 = NN - 1;
    if (m1 > NN - 1) m1 = NN - 1;
    float4 a = *(const float4*)(base + (size_t)m0 * 768 + 512 + h * 64 + dq);
    float4 b = *(const float4*)(base + (size_t)m1 * 768 + 512 + h * 64 + dq);
    Vt[dq + 0][mp] = __builtin_amdgcn_cvt_pkrtz(a.x, b.x);
    Vt[dq + 1][mp] = __builtin_amdgcn_cvt_pkrtz(a.y, b.y);
    Vt[dq + 2][mp] = __builtin_amdgcn_cvt_pkrtz(a.z, b.z);
    Vt[dq + 3][mp] = __builtin_amdgcn_cvt_pkrtz(a.w, b.w);
  }
  // ---- zero Vt pad columns kp=136..147 (PV reads up to 143) ----
  {
    h2 z; z.x = (__fp16)0.f; z.y = (__fp16)0.f;
    for (int idx = tid; idx < 64 * 12; idx += 512)
      Vt[idx / 12][136 + idx % 12] = z;
  }
  // zero this wave's P pad columns kp=136..147
  {
    h2 z; z.x = (__fp16)0.f; z.y = (__fp16)0.f;
    #pragma unroll
    for (int t = 0; t < 3; ++t) Pb[wave][fr][136 + (kb >> 2) * 3 + t] = z;
  }
  __syncthreads();

  const float scq = 0.17677669529663687f;  // 1/sqrt(32)

  // 34 tasks: task = chunk*2 + half
  for (int task = wave; task < 34; task += 8) {
    const int chunk = task >> 1;
    const int half  = task & 1;

    int qsrc = chunk * 16 + fr; if (qsrc > NN - 1) qsrc = NN - 1;
    const float* qr = base + (size_t)qsrc * 768 + h * 64 + half * 32 + kb * 2;
    f16x8 qf;
    {
      float4 a = *(const float4*)(qr);
      float4 b = *(const float4*)(qr + 4);
      H8 t;
      t.h[0] = __builtin_amdgcn_cvt_pkrtz(a.x, a.y);
      t.h[1] = __builtin_amdgcn_cvt_pkrtz(a.z, a.w);
      t.h[2] = __builtin_amdgcn_cvt_pkrtz(b.x, b.y);
      t.h[3] = __builtin_amdgcn_cvt_pkrtz(b.z, b.w);
      qf = t.v;
    }

    f32x4 s[17];
    #pragma unroll
    for (int mt = 0; mt < 17; ++mt) {
      f16x8 af = *(const f16x8*)&Ks[half][mt * 16 + fr][kb * 2];
      f32x4 z4 = {0.f, 0.f, 0.f, 0.f};
      s[mt] = __builtin_amdgcn_mfma_f32_16x16x32_f16(af, qf, z4, 0, 0, 0);
    }

    float mx = -1e30f;
    #pragma unroll
    for (int mt = 0; mt < 17; ++mt)
      #pragma unroll
      for (int r = 0; r < 4; ++r) {
        float v = s[mt][r] * scq;
        if (mt * 16 + kb + r >= NN) v = -1e30f;
        s[mt][r] = v;
        mx = fmaxf(mx, v);
      }
    mx = fmaxf(mx, __shfl_xor(mx, 16, 64));
    mx = fmaxf(mx, __shfl_xor(mx, 32, 64));
    float sum = 0.f;
    #pragma unroll
    for (int mt = 0; mt < 17; ++mt)
      #pragma unroll
      for (int r = 0; r < 4; ++r) {
        float p = __expf(s[mt][r] - mx);
        s[mt][r] = p;
        sum += p;
      }
    sum += __shfl_xor(sum, 16, 64);
    sum += __shfl_xor(sum, 32, 64);
    float inv = 1.f / sum;

    #pragma unroll
    for (int mt = 0; mt < 17; ++mt) {
      h2 lo = __builtin_amdgcn_cvt_pkrtz(s[mt][0] * inv, s[mt][1] * inv);
      h2 hi = __builtin_amdgcn_cvt_pkrtz(s[mt][2] * inv, s[mt][3] * inv);
      int kp = 8 * mt + (kb >> 1);
      Pb[wave][fr][kp]     = lo;
      Pb[wave][fr][kp + 1] = hi;
    }

    f32x4 o[4];
    #pragma unroll
    for (int nt = 0; nt < 4; ++nt) {
      o[nt].x = 0.f; o[nt].y = 0.f; o[nt].z = 0.f; o[nt].w = 0.f;
    }
    #pragma unroll
    for (int s9 = 0; s9 < 9; ++s9) {
      f16x8 pa = *(const f16x8*)&Pb[wave][fr][16 * s9 + kb];
      #pragma unroll
      for (int nt = 0; nt < 4; ++nt) {
        f16x8 vb = *(const f16x8*)&Vt[nt * 16 + fr][16 * s9 + kb];
        o[nt] = __builtin_amdgcn_mfma_f32_16x16x32_f16(pa, vb, o[nt], 0, 0, 0);
      }
    }

    float* ab = aout + (size_t)half * (50496ull * 256ull);
    #pragma unroll
    for (int r = 0; r < 4; ++r) {
      int qrow = chunk * 16 + kb + r;
      if (qrow < NN) {
        float* op = ab + ((size_t)(bt * NN + qrow) * 4 + h) * 64;
        #pragma unroll
        for (int nt = 0; nt < 4; ++nt) op[nt * 16 + fr] = o[nt][r];
      }
    }
  }
}

// ---------------------------------------------------------------------------
__global__ __launch_bounds__(256) void diff_ln(
    const float* __restrict__ a1, const float* __restrict__ a2,
    const float* __restrict__ lamp,
    const float* __restrict__ g, const float* __restrict__ b,
    float* __restrict__ st)
{
  const int btn = blockIdx.x;
  const int lane = threadIdx.x & 63;
  const int h = threadIdx.x >> 6;
  const float lam = lamp[0];
  size_t off = ((size_t)btn * 4 + h) * 64 + lane;
  float y = a1[off] - lam * a2[off];
  float mean = wred_sum(y) * (1.f / 64.f);
  float t = y - mean;
  float var = wred_sum(t * t) * (1.f / 64.f);
  float r = rsqrtf(var + 1e-5f);
  st[(size_t)btn * 640 + h * 64 + lane] = (t * r * g[lane] + b[lane]) * 0.8f;
}

// ---------------------------------------------------------------------------
// Temporal self-attention v2: block = (b,n). Q/K/V staged in LDS (stride 68
// keeps b128 aligned); three flat all-lane phases (scores / softmax / PV) —
// no shfl broadcasts in the hot loops (they were the 158us latency chain).
// ---------------------------------------------------------------------------
__global__ __launch_bounds__(256) void temporal_attn(
    const float* __restrict__ qkvt, float* __restrict__ st)
{
  __shared__ float qs[48][68];
  __shared__ float kt[48][68];
  __shared__ float vt[48][68];
  __shared__ float Ss[48][28];
  const int b = blockIdx.x / NN;
  const int n = blockIdx.x % NN;
  const int tid = threadIdx.x;
  const int lane = tid & 63;
  const int wave = tid >> 6;

  // stage: row = h*24+t, 16 lanes per row cover d=0..63 as float4
  for (int idx = tid; idx < 48 * 16; idx += 256) {
    int row = idx >> 4, dq = (idx & 15) * 4;
    int h = row / 24, t = row - h * 24;
    const float* g = qkvt + ((size_t)(b * TT + t) * NN + n) * 640 + h * 64 + dq;
    *(float4*)&qs[row][dq] = *(const float4*)(g);
    *(float4*)&kt[row][dq] = *(const float4*)(g + 128);
    *(float4*)&vt[row][dq] = *(const float4*)(g + 256);
  }
  __syncthreads();

  // scores: S[row=(h,t)][s] = q[row] . k[h*24+s] * 0.125
  for (int idx = tid; idx < 48 * 24; idx += 256) {
    int row = idx / 24, s = idx - row * 24;
    int krow = (row >= 24 ? 24 : 0) + s;
    float a0 = 0.f, a1 = 0.f, a2 = 0.f, a3 = 0.f;
    #pragma unroll
    for (int dq = 0; dq < 64; dq += 4) {
      float4 q = *(const float4*)&qs[row][dq];
      float4 k = *(const float4*)&kt[krow][dq];
      a0 = fmaf(q.x, k.x, a0);
      a1 = fmaf(q.y, k.y, a1);
      a2 = fmaf(q.z, k.z, a2);
      a3 = fmaf(q.w, k.w, a3);
    }
    Ss[row][s] = ((a0 + a1) + (a2 + a3)) * 0.125f;
  }
  __syncthreads();

  // softmax over s per row; store normalized probs back
  for (int r = wave; r < 48; r += 4) {
    float v = lane < 24 ? Ss[r][lane] : -1e30f;
    float mx = wred_max(v);
    float p = lane < 24 ? __expf(v - mx) : 0.f;
    float inv = 1.f / wred_sum(p);
    if (lane < 24) Ss[r][lane] = p * inv;
  }
  __syncthreads();

  // PV: out[row=(h,t)][d] = sum_s P[row][s] * v[h*24+s][d]
  for (int idx = tid; idx < 48 * 16; idx += 256) {
    int row = idx >> 4, dq = (idx & 15) * 4;
    int h = row / 24, t = row - h * 24;
    int bs = h * 24;
    float ax = 0.f, ay = 0.f, az = 0.f, aw = 0.f;
    #pragma unroll
    for (int s = 0; s < 24; ++s) {
      float p = Ss[row][s];
      float4 v = *(const float4*)&vt[bs + s][dq];
      ax = fmaf(p, v.x, ax);
      ay = fmaf(p, v.y, ay);
      az = fmaf(p, v.z, az);
      aw = fmaf(p, v.w, aw);
    }
    float4 o = {ax, ay, az, aw};
    *(float4*)(st + ((size_t)(b * TT + t) * NN + n) * 640 + 384 + h * 64 + dq) = o;
  }
}

// ---------------------------------------------------------------------------
// Temporal-global attention v2: same LDS-flat-phase structure.
// qg rows = h*12+s (24); kg/vg rows = h*24+t (48); softmax over t.
// ---------------------------------------------------------------------------
__global__ __launch_bounds__(256) void tglobal_attn(
    const float* __restrict__ qkvt, const float* __restrict__ q_agg,
    const float* __restrict__ tmp_map, float* __restrict__ st)
{
  __shared__ float qg[24][68];
  __shared__ float kg[48][68];
  __shared__ float vg[48][68];
  __shared__ float Sg[24][28];
  __shared__ float tgx[12][128];
  const int b = blockIdx.x / NN;
  const int n = blockIdx.x % NN;
  const int tid = threadIdx.x;
  const int lane = tid & 63;
  const int wave = tid >> 6;

  for (int idx = tid; idx < 48 * 16; idx += 256) {
    int row = idx >> 4, dq = (idx & 15) * 4;
    int h = row / 24, t = row - h * 24;
    const float* g = qkvt + ((size_t)(b * TT + t) * NN + n) * 640 + 384 + h * 64 + dq;
    *(float4*)&kg[row][dq] = *(const float4*)(g);
    *(float4*)&vg[row][dq] = *(const float4*)(g + 128);
  }
  for (int idx = tid; idx < 24 * 16; idx += 256) {
    int row = idx >> 4, dq = (idx & 15) * 4;   // row = h*12+s
    int h = row / 12, s = row - h * 12;
    *(float4*)&qg[row][dq] =
        *(const float4*)(q_agg + ((size_t)n * 12 + s) * 128 + h * 64 + dq);
  }
  __syncthreads();

  // scores: Sg[row=(h,s)][t] = qg[row] . kg[h*24+t] * 0.125
  for (int idx = tid; idx < 24 * 24; idx += 256) {
    int row = idx / 24, t = idx - row * 24;
    int krow = (row >= 12 ? 24 : 0) + t;
    float a0 = 0.f, a1 = 0.f, a2 = 0.f, a3 = 0.f;
    #pragma unroll
    for (int dq = 0; dq < 64; dq += 4) {
      float4 q = *(const float4*)&qg[row][dq];
      float4 k = *(const float4*)&kg[krow][dq];
      a0 = fmaf(q.x, k.x, a0);
      a1 = fmaf(q.y, k.y, a1);
      a2 = fmaf(q.z, k.z, a2);
      a3 = fmaf(q.w, k.w, a3);
    }
    Sg[row][t] = ((a0 + a1) + (a2 + a3)) * 0.125f;
  }
  __syncthreads();

  // softmax over t per row
  for (int r = wave; r < 24; r += 4) {
    float v = lane < 24 ? Sg[r][lane] : -1e30f;
    float mx = wred_max(v);
    float p = lane < 24 ? __expf(v - mx) : 0.f;
    float inv = 1.f / wred_sum(p);
    if (lane < 24) Sg[r][lane] = p * inv;
  }
  __syncthreads();

  // tgx[s][h*64+d] = sum_t Pg[(h,s)][t] * vg[h*24+t][d]
  for (int idx = tid; idx < 24 * 16; idx += 256) {
    int row = idx >> 4, dq = (idx & 15) * 4;   // row = h*12+s
    int h = row / 12, s = row - h * 12;
    int bt_ = h * 24;
    float ax = 0.f, ay = 0.f, az = 0.f, aw = 0.f;
    #pragma unroll
    for (int t = 0; t < 24; ++t) {
      float p = Sg[row][t];
      float4 v = *(const float4*)&vg[bt_ + t][dq];
      ax = fmaf(p, v.x, ax);
      ay = fmaf(p, v.y, ay);
      az = fmaf(p, v.z, az);
      aw = fmaf(p, v.w, aw);
    }
    float4 o = {ax, ay, az, aw};
    *(float4*)&tgx[s][h * 64 + dq] = o;
  }
  __syncthreads();

  // tg[t][c] = sum_s tmp_map[b,n,t,s] * tgx[s][c]
  for (int idx = tid; idx < 24 * 32; idx += 256) {
    int t = idx >> 5, cq = (idx & 31) * 4;
    const float* tm = tmp_map + ((size_t)(b * NN + n) * TT + t) * 12;
    float ax = 0.f, ay = 0.f, az = 0.f, aw = 0.f;
    #pragma unroll
    for (int s = 0; s < 12; ++s) {
      float m = tm[s];
      float4 v = *(const float4*)&tgx[s][cq];
      ax = fmaf(m, v.x, ax);
      ay = fmaf(m, v.y, ay);
      az = fmaf(m, v.z, az);
      aw = fmaf(m, v.w, aw);
    }
    float4 o = {ax, ay, az, aw};
    *(float4*)(st + ((size_t)(b * TT + t) * NN + n) * 640 + 512 + cq) = o;
  }
}

// ---------------------------------------------------------------------------
__global__ __launch_bounds__(256) void agg_attn(
    const float* __restrict__ qkva, float* __restrict__ sx, int Ni)
{
  __shared__ float kT[64 * 64];
  __shared__ float vl[64 * 64];
  const int h = blockIdx.x & 1;
  const int bt = blockIdx.x >> 1;
  const int tid = threadIdx.x;
  const int lane = tid & 63;
  const int wave = tid >> 6;
  for (int idx = tid; idx < Ni * 64; idx += 256) {
    int m = idx >> 6, d = idx & 63;
    size_t row = (size_t)(bt * Ni + m) * 384;
    kT[d * Ni + m] = qkva[row + 128 + h * 64 + d];
    vl[m * 64 + d] = qkva[row + 256 + h * 64 + d];
  }
  __syncthreads();
  int mc = lane < Ni ? lane : Ni - 1;
  bool valid = lane < Ni;
  for (int n = wave; n < Ni; n += 4) {
    float qv = qkva[(size_t)(bt * Ni + n) * 384 + h * 64 + lane];
    float sc_ = 0.f;
    #pragma unroll
    for (int d = 0; d < 64; ++d) {
      float qd = __shfl(qv, d, 64);
      sc_ = fmaf(qd, kT[d * Ni + mc], sc_);
    }
    sc_ *= 0.125f;
    float mx = wred_max(valid ? sc_ : -1e30f);
    float p = valid ? __expf(sc_ - mx) : 0.f;
    float inv = 1.f / wred_sum(p);
    float o = 0.f;
    for (int m = 0; m < Ni; ++m) {
      float pm = __shfl(p, m, 64);
      o = fmaf(pm, vl[m * 64 + lane], o);
    }
    sx[(size_t)(bt * Ni + n) * 128 + h * 64 + lane] = o * inv;
  }
}

// ---------------------------------------------------------------------------
__global__ __launch_bounds__(256) void mmap_kernel(
    const float* __restrict__ sx0, const float* __restrict__ sx1,
    const float* __restrict__ M0, const float* __restrict__ M1,
    float* __restrict__ sg)
{
  __shared__ float s0[32 * 128];
  __shared__ float s1[64 * 128];
  const int bt = blockIdx.x;
  const int chunk = blockIdx.y;
  const int tid = threadIdx.x;
  for (int idx = tid; idx < 32 * 128; idx += 256) s0[idx] = sx0[(size_t)bt * 32 * 128 + idx];
  for (int idx = tid; idx < 64 * 128; idx += 256) s1[idx] = sx1[(size_t)bt * 64 * 128 + idx];
  __syncthreads();
  for (int idx = tid; idx < 88 * 128; idx += 256) {
    int n = chunk * 88 + (idx >> 7);
    if (n < NN) {
      int c = idx & 127;
      float acc = 0.f;
      #pragma unroll
      for (int m = 0; m < 32; ++m) acc = fmaf(M0[m * NN + n], s0[m * 128 + c], acc);
      #pragma unroll
      for (int m = 0; m < 64; ++m) acc = fmaf(M1[m * NN + n], s1[m * 128 + c], acc);
      sg[((size_t)bt * NN + n) * 128 + c] = acc;
    }
  }
}

// ---------------------------------------------------------------------------
extern "C" void kernel_launch(void* const* d_in, const int* in_sizes, int n_in,
                              void* d_out, int out_size, void* d_ws, size_t ws_size,
                              hipStream_t stream)
{
  const float* x       = (const float*)d_in[0];
  const float* agg_x0  = (const float*)d_in[1];
  const float* agg_x1  = (const float*)d_in[2];
  const float* tmp_map = (const float*)d_in[3];
  const float* Wq_s = (const float*)d_in[4];
  const float* Wk_s = (const float*)d_in[5];
  const float* Wv_s = (const float*)d_in[6];
  const float* lq1 = (const float*)d_in[7];
  const float* lk1 = (const float*)d_in[8];
  const float* lq2 = (const float*)d_in[9];
  const float* lk2 = (const float*)d_in[10];
  const float* ln_g = (const float*)d_in[11];
  const float* ln_b = (const float*)d_in[12];
  const float* Wq_a0 = (const float*)d_in[13];
  const float* Wk_a0 = (const float*)d_in[14];
  const float* Wv_a0 = (const float*)d_in[15];
  const float* Wq_a1 = (const float*)d_in[16];
  const float* Wk_a1 = (const float*)d_in[17];
  const float* Wv_a1 = (const float*)d_in[18];
  const float* M0   = (const float*)d_in[19];
  const float* M1   = (const float*)d_in[20];
  const float* Wagg = (const float*)d_in[21];
  const float* bagg = (const float*)d_in[22];
  const float* Wq_t = (const float*)d_in[23];
  const float* Wk_t = (const float*)d_in[24];
  const float* Wv_t = (const float*)d_in[25];
  const float* q_agg = (const float*)d_in[26];
  const float* Wk_tg = (const float*)d_in[27];
  const float* Wv_tg = (const float*)d_in[28];
  const float* Wout  = (const float*)d_in[29];
  const float* bout  = (const float*)d_in[30];
  float* ws  = (float*)d_ws;
  float* out = (float*)d_out;

  const size_t o_Wa0  = 720896;
  const size_t o_Wa1  = 917504;
  const size_t o_lam  = 1114112;
  const size_t o_A    = 1114128;
  const size_t o_qkvt = o_A + 38780928;
  const size_t o_B    = o_qkvt + 32317440;

  float* W_all = ws;
  float* W_a0  = ws + o_Wa0;
  float* W_a1  = ws + o_Wa1;
  float* lamp  = ws + o_lam;
  float* qkv_s = ws + o_A;
  float* st    = ws + o_A;
  float* qkvt  = ws + o_qkvt;
  float* a1    = ws + o_B;
  float* qkva0 = ws + o_B;
  float* qkva1 = qkva0 + 2359296;
  float* sx0   = qkva0 + 7077888;
  float* sx1   = qkva0 + 7864320;
  float* sgp   = qkva0 + 9437184;

  auto cp = [&](float* dst, const float* src, size_t nfl) {
    (void)hipMemcpyAsync(dst, src, nfl * sizeof(float), hipMemcpyDeviceToDevice, stream);
  };
  cp(W_all + 0,      Wq_s, 131072);
  cp(W_all + 131072, Wk_s, 131072);
  cp(W_all + 262144, Wv_s, 131072);
  cp(W_all + 393216, Wq_t, 65536);
  cp(W_all + 458752, Wk_t, 65536);
  cp(W_all + 524288, Wv_t, 65536);
  cp(W_all + 589824, Wk_tg, 65536);
  cp(W_all + 655360, Wv_tg, 65536);
  cp(W_a0 + 0,      Wq_a0, 65536);
  cp(W_a0 + 65536,  Wk_a0, 65536);
  cp(W_a0 + 131072, Wv_a0, 65536);
  cp(W_a1 + 0,      Wq_a1, 65536);
  cp(W_a1 + 65536,  Wk_a1, 65536);
  cp(W_a1 + 131072, Wv_a1, 65536);

  hipLaunchKernelGGL(lam_kernel, dim3(1), dim3(64), 0, stream, lq1, lk1, lq2, lk2, lamp);

  const int Mx = 50496;
  hipLaunchKernelGGL(gemm_nt_mfma, dim3(395, 6), dim3(256), 0, stream,
                     x, W_all, (const float*)nullptr, qkv_s, Mx, 768, 512, 768);
  hipLaunchKernelGGL(diff_attn, dim3(768), dim3(512), 0, stream, qkv_s, a1);
  hipLaunchKernelGGL(gemm_nt_mfma, dim3(395, 5), dim3(256), 0, stream,
                     x, W_all + 393216, (const float*)nullptr, qkvt, Mx, 640, 512, 640);
  hipLaunchKernelGGL(diff_ln, dim3(Mx), dim3(256), 0, stream,
                     a1, a1 + 12926976, lamp, ln_g, ln_b, st);
  hipLaunchKernelGGL(temporal_attn, dim3(8 * NN), dim3(256), 0, stream, qkvt, st);
  hipLaunchKernelGGL(tglobal_attn, dim3(8 * NN), dim3(256), 0, stream, qkvt, q_agg, tmp_map, st);
  hipLaunchKernelGGL(gemm_nt_mfma, dim3(48, 3), dim3(256), 0, stream,
                     agg_x0, W_a0, (const float*)nullptr, qkva0, 6144, 384, 512, 384);
  hipLaunchKernelGGL(gemm_nt_mfma, dim3(96, 3), dim3(256), 0, stream,
                     agg_x1, W_a1, (const float*)nullptr, qkva1, 12288, 384, 512, 384);
  hipLaunchKernelGGL(agg_attn, dim3(384), dim3(256), 0, stream, qkva0, sx0, 32);
  hipLaunchKernelGGL(agg_attn, dim3(384), dim3(256), 0, stream, qkva1, sx1, 64);
  hipLaunchKernelGGL(mmap_kernel, dim3(192, 3), dim3(256), 0, stream, sx0, sx1, M0, M1, sgp);
  hipLaunchKernelGGL(gemm_nt_mfma, dim3(395, 1), dim3(256), 0, stream,
                     sgp, Wagg, bagg, st + 256, Mx, 128, 128, 640);
  hipLaunchKernelGGL(gemm_nt_mfma, dim3(395, 4), dim3(256), 0, stream,
                     st, Wout, bout, out, Mx, 512, 640, 512);
}

// Round 5
// 1082.841 us; speedup vs baseline: 2.8875x; 1.0234x over previous
//
#include <hip/hip_runtime.h>

#define NN 263
#define TT 24

typedef __fp16 h2 __attribute__((ext_vector_type(2)));
typedef _Float16 f16x4 __attribute__((ext_vector_type(4)));
typedef _Float16 f16x8 __attribute__((ext_vector_type(8)));
typedef float f32x4 __attribute__((ext_vector_type(4)));

struct WSegs { const float* p[6]; };   // per-128-col-tile weight base pointers

static __device__ __forceinline__ float wred_sum(float v) {
  #pragma unroll
  for (int off = 32; off >= 1; off >>= 1) v += __shfl_xor(v, off, 64);
  return v;
}
static __device__ __forceinline__ float wred_max(float v) {
  #pragma unroll
  for (int off = 32; off >= 1; off >>= 1) v = fmaxf(v, __shfl_xor(v, off, 64));
  return v;
}

// ---------------------------------------------------------------------------
// f16-MFMA NT GEMM: C[m, bn*128+n] = sum_k A[m,k]*Wseg[bn][n,k] (+bias)
// 128x128 tile, BK=32, 4 waves 2x2, each wave 64x64 via 4x4 frags of
// v_mfma_f32_16x16x32_f16 (fp32 accumulate). Inner loop verified R0-R4.
// R5: 1-D grid, bn-fastest logical order + bijective chunked XCD swizzle
// (m204) so sibling column-tiles of one A-panel run dispatch-adjacent on the
// SAME XCD -> A-panel L2 reuse (fetch was NT x A). W via per-tile segment
// pointers (kills the 15 hipMemcpyAsync weight copies).
// Requires: N = NT*128, K % 32 == 0; M guarded.
// ---------------------------------------------------------------------------
__global__ __launch_bounds__(256) void gemm_nt_mfma(
    const float* __restrict__ A, WSegs ws, const float* __restrict__ bias,
    float* __restrict__ C, int M, int NT, int K, int ldc)
{
  __shared__ _Float16 As[128][40];
  __shared__ _Float16 Bs[128][40];
  const int tid  = threadIdx.x;
  const int lane = tid & 63;
  const int wave = tid >> 6;
  const int wr = wave >> 1, wc = wave & 1;

  // bijective chunked XCD swizzle: XCD x gets logical chunk [start_x, start_x+len_x)
  const int nwg = gridDim.x;
  const int q8 = nwg >> 3, r8 = nwg & 7;
  const int xcd = blockIdx.x & 7, pos = blockIdx.x >> 3;
  const int logical = (xcd < r8 ? xcd * (q8 + 1) : r8 * (q8 + 1) + (xcd - r8) * q8) + pos;
  const int bm = (logical / NT) * 128;
  const int bn = logical - (logical / NT) * NT;
  const float* __restrict__ W = ws.p[bn];

  const int srow = tid >> 3;
  const int skq  = (tid & 7) * 4;
  const float* aptr[4];
  const float* bptr[4];
  #pragma unroll
  for (int l = 0; l < 4; ++l) {
    int gm = bm + srow + 32 * l; if (gm > M - 1) gm = M - 1;
    aptr[l] = A + (size_t)gm * K + skq;
    bptr[l] = W + (size_t)(srow + 32 * l) * K + skq;
  }

  f32x4 acc[4][4];
  #pragma unroll
  for (int i = 0; i < 4; ++i)
    #pragma unroll
    for (int j = 0; j < 4; ++j) {
      acc[i][j].x = 0.f; acc[i][j].y = 0.f; acc[i][j].z = 0.f; acc[i][j].w = 0.f;
    }

  const int fr = lane & 15;
  const int fk = (lane >> 4) * 8;

  float4 av[4], bv[4];
  #pragma unroll
  for (int l = 0; l < 4; ++l) {
    av[l] = *(const float4*)(aptr[l]);
    bv[l] = *(const float4*)(bptr[l]);
  }

  for (int k0 = 0; k0 < K; k0 += 32) {
    #pragma unroll
    for (int l = 0; l < 4; ++l) {
      f16x4 a4, b4;
      a4.x = (_Float16)av[l].x; a4.y = (_Float16)av[l].y;
      a4.z = (_Float16)av[l].z; a4.w = (_Float16)av[l].w;
      b4.x = (_Float16)bv[l].x; b4.y = (_Float16)bv[l].y;
      b4.z = (_Float16)bv[l].z; b4.w = (_Float16)bv[l].w;
      *(f16x4*)&As[srow + 32 * l][skq] = a4;
      *(f16x4*)&Bs[srow + 32 * l][skq] = b4;
    }
    __syncthreads();

    if (k0 + 32 < K) {
      #pragma unroll
      for (int l = 0; l < 4; ++l) {
        av[l] = *(const float4*)(aptr[l] + k0 + 32);
        bv[l] = *(const float4*)(bptr[l] + k0 + 32);
      }
    }

    f16x8 af[4], bf[4];
    #pragma unroll
    for (int mi = 0; mi < 4; ++mi)
      af[mi] = *(const f16x8*)&As[wr * 64 + mi * 16 + fr][fk];
    #pragma unroll
    for (int ni = 0; ni < 4; ++ni)
      bf[ni] = *(const f16x8*)&Bs[wc * 64 + ni * 16 + fr][fk];
    #pragma unroll
    for (int mi = 0; mi < 4; ++mi)
      #pragma unroll
      for (int ni = 0; ni < 4; ++ni)
        acc[mi][ni] = __builtin_amdgcn_mfma_f32_16x16x32_f16(
            af[mi], bf[ni], acc[mi][ni], 0, 0, 0);
    __syncthreads();
  }

  #pragma unroll
  for (int mi = 0; mi < 4; ++mi) {
    int rb = bm + wr * 64 + mi * 16 + (lane >> 4) * 4;
    #pragma unroll
    for (int r = 0; r < 4; ++r) {
      int gm = rb + r;
      if (gm < M) {
        int gn = bn * 128 + wc * 64 + fr;
        float* crow = C + (size_t)gm * ldc + gn;
        #pragma unroll
        for (int ni = 0; ni < 4; ++ni) {
          float v = acc[mi][ni][r];
          if (bias) v += bias[gn + ni * 16];
          crow[ni * 16] = v;
        }
      }
    }
  }
}

// ---------------------------------------------------------------------------
__global__ void lam_kernel(const float* __restrict__ lq1, const float* __restrict__ lk1,
                           const float* __restrict__ lq2, const float* __restrict__ lk2,
                           float* __restrict__ out) {
  int lane = threadIdx.x;
  float v1 = lane < 32 ? lq1[lane] * lk1[lane] : 0.f;
  float v2 = lane < 32 ? lq2[lane] * lk2[lane] : 0.f;
  v1 = wred_sum(v1);
  v2 = wred_sum(v2);
  if (lane == 0) out[0] = expf(v1) - expf(v2) + 0.2f;
}

// ---------------------------------------------------------------------------
// Differential self-attention, MFMA version (verified R3/R4).
// ---------------------------------------------------------------------------
__global__ __launch_bounds__(512, 2) void diff_attn(
    const float* __restrict__ qkv, float* __restrict__ aout)
{
  __shared__ _Float16 Ks[2][272][40];   // [half][k-row][d(32)+pad8]
  __shared__ h2 Vt[64][148];            // Vt[d][kp] = (V[2kp][d], V[2kp+1][d])
  __shared__ h2 Pb[8][16][148];         // per-wave P: [qrow(16)][kp], pad zeroed

  const int h  = blockIdx.x & 3;
  const int bt = blockIdx.x >> 2;
  const int tid = threadIdx.x;
  const int lane = tid & 63;
  const int wave = tid >> 6;
  const int fr = lane & 15;             // fragment row/col index
  const int kb = (lane >> 4) * 4;       // C-layout row part / kp offset
  const float* base = qkv + (size_t)bt * NN * 768;

  union H4 { f16x4 v; h2 h[2]; };
  union H8 { f16x8 v; h2 h[4]; };

  // ---- stage K (both 32-col halves) as f16, rows padded/clamped to 272 ----
  for (int idx = tid; idx < 272 * 16; idx += 512) {
    int row = idx >> 4, q = idx & 15;
    int sr = row < NN ? row : NN - 1;
    float4 kv = *(const float4*)(base + (size_t)sr * 768 + 256 + h * 64 + q * 4);
    H4 t;
    t.h[0] = __builtin_amdgcn_cvt_pkrtz(kv.x, kv.y);
    t.h[1] = __builtin_amdgcn_cvt_pkrtz(kv.z, kv.w);
    *(f16x4*)&Ks[q >> 3][row][(q & 7) * 4] = t.v;
  }
  // ---- stage V transposed as (k,k+1) h2 pairs ----
  for (int idx = tid; idx < 136 * 16; idx += 512) {
    int mp = idx >> 4, dq = (idx & 15) * 4;
    int m0 = 2 * mp, m1 = 2 * mp + 1;
    if (m0 > NN - 1) m0 = NN - 1;
    if (m1 > NN - 1) m1 = NN - 1;
    float4 a = *(const float4*)(base + (size_t)m0 * 768 + 512 + h * 64 + dq);
    float4 b = *(const float4*)(base + (size_t)m1 * 768 + 512 + h * 64 + dq);
    Vt[dq + 0][mp] = __builtin_amdgcn_cvt_pkrtz(a.x, b.x);
    Vt[dq + 1][mp] = __builtin_amdgcn_cvt_pkrtz(a.y, b.y);
    Vt[dq + 2][mp] = __builtin_amdgcn_cvt_pkrtz(a.z, b.z);
    Vt[dq + 3][mp] = __builtin_amdgcn_cvt_pkrtz(a.w, b.w);
  }
  // ---- zero Vt pad columns kp=136..147 (PV reads up to 143) ----
  {
    h2 z; z.x = (__fp16)0.f; z.y = (__fp16)0.f;
    for (int idx = tid; idx < 64 * 12; idx += 512)
      Vt[idx / 12][136 + idx % 12] = z;
  }
  // zero this wave's P pad columns kp=136..147
  {
    h2 z; z.x = (__fp16)0.f; z.y = (__fp16)0.f;
    #pragma unroll
    for (int t = 0; t < 3; ++t) Pb[wave][fr][136 + (kb >> 2) * 3 + t] = z;
  }
  __syncthreads();

  const float scq = 0.17677669529663687f;  // 1/sqrt(32)

  // 34 tasks: task = chunk*2 + half
  for (int task = wave; task < 34; task += 8) {
    const int chunk = task >> 1;
    const int half  = task & 1;

    int qsrc = chunk * 16 + fr; if (qsrc > NN - 1) qsrc = NN - 1;
    const float* qr = base + (size_t)qsrc * 768 + h * 64 + half * 32 + kb * 2;
    f16x8 qf;
    {
      float4 a = *(const float4*)(qr);
      float4 b = *(const float4*)(qr + 4);
      H8 t;
      t.h[0] = __builtin_amdgcn_cvt_pkrtz(a.x, a.y);
      t.h[1] = __builtin_amdgcn_cvt_pkrtz(a.z, a.w);
      t.h[2] = __builtin_amdgcn_cvt_pkrtz(b.x, b.y);
      t.h[3] = __builtin_amdgcn_cvt_pkrtz(b.z, b.w);
      qf = t.v;
    }

    f32x4 s[17];
    #pragma unroll
    for (int mt = 0; mt < 17; ++mt) {
      f16x8 af = *(const f16x8*)&Ks[half][mt * 16 + fr][kb * 2];
      f32x4 z4 = {0.f, 0.f, 0.f, 0.f};
      s[mt] = __builtin_amdgcn_mfma_f32_16x16x32_f16(af, qf, z4, 0, 0, 0);
    }

    float mx = -1e30f;
    #pragma unroll
    for (int mt = 0; mt < 17; ++mt)
      #pragma unroll
      for (int r = 0; r < 4; ++r) {
        float v = s[mt][r] * scq;
        if (mt * 16 + kb + r >= NN) v = -1e30f;
        s[mt][r] = v;
        mx = fmaxf(mx, v);
      }
    mx = fmaxf(mx, __shfl_xor(mx, 16, 64));
    mx = fmaxf(mx, __shfl_xor(mx, 32, 64));
    float sum = 0.f;
    #pragma unroll
    for (int mt = 0; mt < 17; ++mt)
      #pragma unroll
      for (int r = 0; r < 4; ++r) {
        float p = __expf(s[mt][r] - mx);
        s[mt][r] = p;
        sum += p;
      }
    sum += __shfl_xor(sum, 16, 64);
    sum += __shfl_xor(sum, 32, 64);
    float inv = 1.f / sum;

    #pragma unroll
    for (int mt = 0; mt < 17; ++mt) {
      h2 lo = __builtin_amdgcn_cvt_pkrtz(s[mt][0] * inv, s[mt][1] * inv);
      h2 hi = __builtin_amdgcn_cvt_pkrtz(s[mt][2] * inv, s[mt][3] * inv);
      int kp = 8 * mt + (kb >> 1);
      Pb[wave][fr][kp]     = lo;
      Pb[wave][fr][kp + 1] = hi;
    }

    f32x4 o[4];
    #pragma unroll
    for (int nt = 0; nt < 4; ++nt) {
      o[nt].x = 0.f; o[nt].y = 0.f; o[nt].z = 0.f; o[nt].w = 0.f;
    }
    #pragma unroll
    for (int s9 = 0; s9 < 9; ++s9) {
      f16x8 pa = *(const f16x8*)&Pb[wave][fr][16 * s9 + kb];
      #pragma unroll
      for (int nt = 0; nt < 4; ++nt) {
        f16x8 vb = *(const f16x8*)&Vt[nt * 16 + fr][16 * s9 + kb];
        o[nt] = __builtin_amdgcn_mfma_f32_16x16x32_f16(pa, vb, o[nt], 0, 0, 0);
      }
    }

    float* ab = aout + (size_t)half * (50496ull * 256ull);
    #pragma unroll
    for (int r = 0; r < 4; ++r) {
      int qrow = chunk * 16 + kb + r;
      if (qrow < NN) {
        float* op = ab + ((size_t)(bt * NN + qrow) * 4 + h) * 64;
        #pragma unroll
        for (int nt = 0; nt < 4; ++nt) op[nt * 16 + fr] = o[nt][r];
      }
    }
  }
}

// ---------------------------------------------------------------------------
__global__ __launch_bounds__(256) void diff_ln(
    const float* __restrict__ a1, const float* __restrict__ a2,
    const float* __restrict__ lamp,
    const float* __restrict__ g, const float* __restrict__ b,
    float* __restrict__ st)
{
  const int btn = blockIdx.x;
  const int lane = threadIdx.x & 63;
  const int h = threadIdx.x >> 6;
  const float lam = lamp[0];
  size_t off = ((size_t)btn * 4 + h) * 64 + lane;
  float y = a1[off] - lam * a2[off];
  float mean = wred_sum(y) * (1.f / 64.f);
  float t = y - mean;
  float var = wred_sum(t * t) * (1.f / 64.f);
  float r = rsqrtf(var + 1e-5f);
  st[(size_t)btn * 640 + h * 64 + lane] = (t * r * g[lane] + b[lane]) * 0.8f;
}

// ---------------------------------------------------------------------------
// Temporal self-attention v2 (verified R4): LDS flat phases, no shfl chains.
// ---------------------------------------------------------------------------
__global__ __launch_bounds__(256) void temporal_attn(
    const float* __restrict__ qkvt, float* __restrict__ st)
{
  __shared__ float qs[48][68];
  __shared__ float kt[48][68];
  __shared__ float vt[48][68];
  __shared__ float Ss[48][28];
  const int b = blockIdx.x / NN;
  const int n = blockIdx.x % NN;
  const int tid = threadIdx.x;
  const int lane = tid & 63;
  const int wave = tid >> 6;

  for (int idx = tid; idx < 48 * 16; idx += 256) {
    int row = idx >> 4, dq = (idx & 15) * 4;
    int h = row / 24, t = row - h * 24;
    const float* g = qkvt + ((size_t)(b * TT + t) * NN + n) * 640 + h * 64 + dq;
    *(float4*)&qs[row][dq] = *(const float4*)(g);
    *(float4*)&kt[row][dq] = *(const float4*)(g + 128);
    *(float4*)&vt[row][dq] = *(const float4*)(g + 256);
  }
  __syncthreads();

  for (int idx = tid; idx < 48 * 24; idx += 256) {
    int row = idx / 24, s = idx - row * 24;
    int krow = (row >= 24 ? 24 : 0) + s;
    float a0 = 0.f, a1 = 0.f, a2 = 0.f, a3 = 0.f;
    #pragma unroll
    for (int dq = 0; dq < 64; dq += 4) {
      float4 q = *(const float4*)&qs[row][dq];
      float4 k = *(const float4*)&kt[krow][dq];
      a0 = fmaf(q.x, k.x, a0);
      a1 = fmaf(q.y, k.y, a1);
      a2 = fmaf(q.z, k.z, a2);
      a3 = fmaf(q.w, k.w, a3);
    }
    Ss[row][s] = ((a0 + a1) + (a2 + a3)) * 0.125f;
  }
  __syncthreads();

  for (int r = wave; r < 48; r += 4) {
    float v = lane < 24 ? Ss[r][lane] : -1e30f;
    float mx = wred_max(v);
    float p = lane < 24 ? __expf(v - mx) : 0.f;
    float inv = 1.f / wred_sum(p);
    if (lane < 24) Ss[r][lane] = p * inv;
  }
  __syncthreads();

  for (int idx = tid; idx < 48 * 16; idx += 256) {
    int row = idx >> 4, dq = (idx & 15) * 4;
    int h = row / 24, t = row - h * 24;
    int bs = h * 24;
    float ax = 0.f, ay = 0.f, az = 0.f, aw = 0.f;
    #pragma unroll
    for (int s = 0; s < 24; ++s) {
      float p = Ss[row][s];
      float4 v = *(const float4*)&vt[bs + s][dq];
      ax = fmaf(p, v.x, ax);
      ay = fmaf(p, v.y, ay);
      az = fmaf(p, v.z, az);
      aw = fmaf(p, v.w, aw);
    }
    float4 o = {ax, ay, az, aw};
    *(float4*)(st + ((size_t)(b * TT + t) * NN + n) * 640 + 384 + h * 64 + dq) = o;
  }
}

// ---------------------------------------------------------------------------
// Temporal-global attention v2 (verified R4).
// ---------------------------------------------------------------------------
__global__ __launch_bounds__(256) void tglobal_attn(
    const float* __restrict__ qkvt, const float* __restrict__ q_agg,
    const float* __restrict__ tmp_map, float* __restrict__ st)
{
  __shared__ float qg[24][68];
  __shared__ float kg[48][68];
  __shared__ float vg[48][68];
  __shared__ float Sg[24][28];
  __shared__ float tgx[12][128];
  const int b = blockIdx.x / NN;
  const int n = blockIdx.x % NN;
  const int tid = threadIdx.x;
  const int lane = tid & 63;
  const int wave = tid >> 6;

  for (int idx = tid; idx < 48 * 16; idx += 256) {
    int row = idx >> 4, dq = (idx & 15) * 4;
    int h = row / 24, t = row - h * 24;
    const float* g = qkvt + ((size_t)(b * TT + t) * NN + n) * 640 + 384 + h * 64 + dq;
    *(float4*)&kg[row][dq] = *(const float4*)(g);
    *(float4*)&vg[row][dq] = *(const float4*)(g + 128);
  }
  for (int idx = tid; idx < 24 * 16; idx += 256) {
    int row = idx >> 4, dq = (idx & 15) * 4;   // row = h*12+s
    int h = row / 12, s = row - h * 12;
    *(float4*)&qg[row][dq] =
        *(const float4*)(q_agg + ((size_t)n * 12 + s) * 128 + h * 64 + dq);
  }
  __syncthreads();

  for (int idx = tid; idx < 24 * 24; idx += 256) {
    int row = idx / 24, t = idx - row * 24;
    int krow = (row >= 12 ? 24 : 0) + t;
    float a0 = 0.f, a1 = 0.f, a2 = 0.f, a3 = 0.f;
    #pragma unroll
    for (int dq = 0; dq < 64; dq += 4) {
      float4 q = *(const float4*)&qg[row][dq];
      float4 k = *(const float4*)&kg[krow][dq];
      a0 = fmaf(q.x, k.x, a0);
      a1 = fmaf(q.y, k.y, a1);
      a2 = fmaf(q.z, k.z, a2);
      a3 = fmaf(q.w, k.w, a3);
    }
    Sg[row][t] = ((a0 + a1) + (a2 + a3)) * 0.125f;
  }
  __syncthreads();

  for (int r = wave; r < 24; r += 4) {
    float v = lane < 24 ? Sg[r][lane] : -1e30f;
    float mx = wred_max(v);
    float p = lane < 24 ? __expf(v - mx) : 0.f;
    float inv = 1.f / wred_sum(p);
    if (lane < 24) Sg[r][lane] = p * inv;
  }
  __syncthreads();

  for (int idx = tid; idx < 24 * 16; idx += 256) {
    int row = idx >> 4, dq = (idx & 15) * 4;   // row = h*12+s
    int h = row / 12, s = row - h * 12;
    int bt_ = h * 24;
    float ax = 0.f, ay = 0.f, az = 0.f, aw = 0.f;
    #pragma unroll
    for (int t = 0; t < 24; ++t) {
      float p = Sg[row][t];
      float4 v = *(const float4*)&vg[bt_ + t][dq];
      ax = fmaf(p, v.x, ax);
      ay = fmaf(p, v.y, ay);
      az = fmaf(p, v.z, az);
      aw = fmaf(p, v.w, aw);
    }
    float4 o = {ax, ay, az, aw};
    *(float4*)&tgx[s][h * 64 + dq] = o;
  }
  __syncthreads();

  for (int idx = tid; idx < 24 * 32; idx += 256) {
    int t = idx >> 5, cq = (idx & 31) * 4;
    const float* tm = tmp_map + ((size_t)(b * NN + n) * TT + t) * 12;
    float ax = 0.f, ay = 0.f, az = 0.f, aw = 0.f;
    #pragma unroll
    for (int s = 0; s < 12; ++s) {
      float m = tm[s];
      float4 v = *(const float4*)&tgx[s][cq];
      ax = fmaf(m, v.x, ax);
      ay = fmaf(m, v.y, ay);
      az = fmaf(m, v.z, az);
      aw = fmaf(m, v.w, aw);
    }
    float4 o = {ax, ay, az, aw};
    *(float4*)(st + ((size_t)(b * TT + t) * NN + n) * 640 + 512 + cq) = o;
  }
}

// ---------------------------------------------------------------------------
__global__ __launch_bounds__(256) void agg_attn(
    const float* __restrict__ qkva, float* __restrict__ sx, int Ni)
{
  __shared__ float kT[64 * 64];
  __shared__ float vl[64 * 64];
  const int h = blockIdx.x & 1;
  const int bt = blockIdx.x >> 1;
  const int tid = threadIdx.x;
  const int lane = tid & 63;
  const int wave = tid >> 6;
  for (int idx = tid; idx < Ni * 64; idx += 256) {
    int m = idx >> 6, d = idx & 63;
    size_t row = (size_t)(bt * Ni + m) * 384;
    kT[d * Ni + m] = qkva[row + 128 + h * 64 + d];
    vl[m * 64 + d] = qkva[row + 256 + h * 64 + d];
  }
  __syncthreads();
  int mc = lane < Ni ? lane : Ni - 1;
  bool valid = lane < Ni;
  for (int n = wave; n < Ni; n += 4) {
    float qv = qkva[(size_t)(bt * Ni + n) * 384 + h * 64 + lane];
    float sc_ = 0.f;
    #pragma unroll
    for (int d = 0; d < 64; ++d) {
      float qd = __shfl(qv, d, 64);
      sc_ = fmaf(qd, kT[d * Ni + mc], sc_);
    }
    sc_ *= 0.125f;
    float mx = wred_max(valid ? sc_ : -1e30f);
    float p = valid ? __expf(sc_ - mx) : 0.f;
    float inv = 1.f / wred_sum(p);
    float o = 0.f;
    for (int m = 0; m < Ni; ++m) {
      float pm = __shfl(p, m, 64);
      o = fmaf(pm, vl[m * 64 + lane], o);
    }
    sx[(size_t)(bt * Ni + n) * 128 + h * 64 + lane] = o * inv;
  }
}

// ---------------------------------------------------------------------------
__global__ __launch_bounds__(256) void mmap_kernel(
    const float* __restrict__ sx0, const float* __restrict__ sx1,
    const float* __restrict__ M0, const float* __restrict__ M1,
    float* __restrict__ sg)
{
  __shared__ float s0[32 * 128];
  __shared__ float s1[64 * 128];
  const int bt = blockIdx.x;
  const int chunk = blockIdx.y;
  const int tid = threadIdx.x;
  for (int idx = tid; idx < 32 * 128; idx += 256) s0[idx] = sx0[(size_t)bt * 32 * 128 + idx];
  for (int idx = tid; idx < 64 * 128; idx += 256) s1[idx] = sx1[(size_t)bt * 64 * 128 + idx];
  __syncthreads();
  for (int idx = tid; idx < 88 * 128; idx += 256) {
    int n = chunk * 88 + (idx >> 7);
    if (n < NN) {
      int c = idx & 127;
      float acc = 0.f;
      #pragma unroll
      for (int m = 0; m < 32; ++m) acc = fmaf(M0[m * NN + n], s0[m * 128 + c], acc);
      #pragma unroll
      for (int m = 0; m < 64; ++m) acc = fmaf(M1[m * NN + n], s1[m * 128 + c], acc);
      sg[((size_t)bt * NN + n) * 128 + c] = acc;
    }
  }
}

// ---------------------------------------------------------------------------
extern "C" void kernel_launch(void* const* d_in, const int* in_sizes, int n_in,
                              void* d_out, int out_size, void* d_ws, size_t ws_size,
                              hipStream_t stream)
{
  const float* x       = (const float*)d_in[0];
  const float* agg_x0  = (const float*)d_in[1];
  const float* agg_x1  = (const float*)d_in[2];
  const float* tmp_map = (const float*)d_in[3];
  const float* Wq_s = (const float*)d_in[4];
  const float* Wk_s = (const float*)d_in[5];
  const float* Wv_s = (const float*)d_in[6];
  const float* lq1 = (const float*)d_in[7];
  const float* lk1 = (const float*)d_in[8];
  const float* lq2 = (const float*)d_in[9];
  const float* lk2 = (const float*)d_in[10];
  const float* ln_g = (const float*)d_in[11];
  const float* ln_b = (const float*)d_in[12];
  const float* Wq_a0 = (const float*)d_in[13];
  const float* Wk_a0 = (const float*)d_in[14];
  const float* Wv_a0 = (const float*)d_in[15];
  const float* Wq_a1 = (const float*)d_in[16];
  const float* Wk_a1 = (const float*)d_in[17];
  const float* Wv_a1 = (const float*)d_in[18];
  const float* M0   = (const float*)d_in[19];
  const float* M1   = (const float*)d_in[20];
  const float* Wagg = (const float*)d_in[21];
  const float* bagg = (const float*)d_in[22];
  const float* Wq_t = (const float*)d_in[23];
  const float* Wk_t = (const float*)d_in[24];
  const float* Wv_t = (const float*)d_in[25];
  const float* q_agg = (const float*)d_in[26];
  const float* Wk_tg = (const float*)d_in[27];
  const float* Wv_tg = (const float*)d_in[28];
  const float* Wout  = (const float*)d_in[29];
  const float* bout  = (const float*)d_in[30];
  float* ws  = (float*)d_ws;
  float* out = (float*)d_out;

  const size_t o_lam  = 1114112;
  const size_t o_A    = 1114128;
  const size_t o_qkvt = o_A + 38780928;
  const size_t o_B    = o_qkvt + 32317440;

  float* lamp  = ws + o_lam;
  float* qkv_s = ws + o_A;
  float* st    = ws + o_A;
  float* qkvt  = ws + o_qkvt;
  float* a1    = ws + o_B;
  float* qkva0 = ws + o_B;
  float* qkva1 = qkva0 + 2359296;
  float* sx0   = qkva0 + 7077888;
  float* sx1   = qkva0 + 7864320;
  float* sgp   = qkva0 + 9437184;

  hipLaunchKernelGGL(lam_kernel, dim3(1), dim3(64), 0, stream, lq1, lk1, lq2, lk2, lamp);

  const int Mx = 50496;

  // qkv projection: N=768, tiles: Wq_s(2) | Wk_s(2) | Wv_s(2), each 256x512
  WSegs wqkv; wqkv.p[0] = Wq_s; wqkv.p[1] = Wq_s + 65536;
  wqkv.p[2] = Wk_s; wqkv.p[3] = Wk_s + 65536;
  wqkv.p[4] = Wv_s; wqkv.p[5] = Wv_s + 65536;
  hipLaunchKernelGGL(gemm_nt_mfma, dim3(395 * 6), dim3(256), 0, stream,
                     x, wqkv, (const float*)nullptr, qkv_s, Mx, 6, 512, 768);

  hipLaunchKernelGGL(diff_attn, dim3(768), dim3(512), 0, stream, qkv_s, a1);

  // temporal qkv: N=640, tiles: Wq_t|Wk_t|Wv_t|Wk_tg|Wv_tg, each 128x512
  WSegs wt; wt.p[0] = Wq_t; wt.p[1] = Wk_t; wt.p[2] = Wv_t;
  wt.p[3] = Wk_tg; wt.p[4] = Wv_tg; wt.p[5] = Wq_t;
  hipLaunchKernelGGL(gemm_nt_mfma, dim3(395 * 5), dim3(256), 0, stream,
                     x, wt, (const float*)nullptr, qkvt, Mx, 5, 512, 640);

  hipLaunchKernelGGL(diff_ln, dim3(Mx), dim3(256), 0, stream,
                     a1, a1 + 12926976, lamp, ln_g, ln_b, st);
  hipLaunchKernelGGL(temporal_attn, dim3(8 * NN), dim3(256), 0, stream, qkvt, st);
  hipLaunchKernelGGL(tglobal_attn, dim3(8 * NN), dim3(256), 0, stream, qkvt, q_agg, tmp_map, st);

  // agg projections: N=384, tiles each 128x512
  WSegs wa0; wa0.p[0] = Wq_a0; wa0.p[1] = Wk_a0; wa0.p[2] = Wv_a0;
  wa0.p[3] = wa0.p[4] = wa0.p[5] = Wq_a0;
  hipLaunchKernelGGL(gemm_nt_mfma, dim3(48 * 3), dim3(256), 0, stream,
                     agg_x0, wa0, (const float*)nullptr, qkva0, 6144, 3, 512, 384);
  WSegs wa1; wa1.p[0] = Wq_a1; wa1.p[1] = Wk_a1; wa1.p[2] = Wv_a1;
  wa1.p[3] = wa1.p[4] = wa1.p[5] = Wq_a1;
  hipLaunchKernelGGL(gemm_nt_mfma, dim3(96 * 3), dim3(256), 0, stream,
                     agg_x1, wa1, (const float*)nullptr, qkva1, 12288, 3, 512, 384);

  hipLaunchKernelGGL(agg_attn, dim3(384), dim3(256), 0, stream, qkva0, sx0, 32);
  hipLaunchKernelGGL(agg_attn, dim3(384), dim3(256), 0, stream, qkva1, sx1, 64);
  hipLaunchKernelGGL(mmap_kernel, dim3(192, 3), dim3(256), 0, stream, sx0, sx1, M0, M1, sgp);

  // sg @ Wagg.T + bagg: N=128, one tile
  WSegs wag; wag.p[0] = Wagg;
  wag.p[1] = wag.p[2] = wag.p[3] = wag.p[4] = wag.p[5] = Wagg;
  hipLaunchKernelGGL(gemm_nt_mfma, dim3(395 * 1), dim3(256), 0, stream,
                     sgp, wag, bagg, st + 256, Mx, 1, 128, 640);

  // out projection: N=512, tiles = Wout + i*128*640
  WSegs wo; wo.p[0] = Wout; wo.p[1] = Wout + 81920;
  wo.p[2] = Wout + 163840; wo.p[3] = Wout + 245760; wo.p[4] = wo.p[5] = Wout;
  hipLaunchKernelGGL(gemm_nt_mfma, dim3(395 * 4), dim3(256), 0, stream,
                     st, wo, bout, out, Mx, 4, 640, 512);
}

// Round 6
// 954.335 us; speedup vs baseline: 3.2764x; 1.1347x over previous
//
#include <hip/hip_runtime.h>

#define NN 263
#define TT 24

typedef __fp16 h2 __attribute__((ext_vector_type(2)));
typedef _Float16 f16x4 __attribute__((ext_vector_type(4)));
typedef _Float16 f16x8 __attribute__((ext_vector_type(8)));
typedef float f32x4 __attribute__((ext_vector_type(4)));

struct WSegs  { const float* p[6]; };      // fp32 weight tiles (legacy gemm)
struct WSegsH { const _Float16* p[6]; };   // f16 weight tiles
struct CvtSegs { const float* src[11]; _Float16* dst[11]; int cnt8[11]; };

static __device__ __forceinline__ float wred_sum(float v) {
  #pragma unroll
  for (int off = 32; off >= 1; off >>= 1) v += __shfl_xor(v, off, 64);
  return v;
}
static __device__ __forceinline__ float wred_max(float v) {
  #pragma unroll
  for (int off = 32; off >= 1; off >>= 1) v = fmaxf(v, __shfl_xor(v, off, 64));
  return v;
}

// ---------------------------------------------------------------------------
// Batched fp32 -> f16 convert (x + all weights), 8 elems/thread-iter.
// Segment 0 (x) is the big one -> scan exits at s=0 for most threads.
// ---------------------------------------------------------------------------
__global__ __launch_bounds__(256) void cvt_f16(CvtSegs cs, int nseg, int total8)
{
  const int stride = gridDim.x * 256;
  for (int i = blockIdx.x * 256 + threadIdx.x; i < total8; i += stride) {
    int r = i, s = 0;
    while (s < nseg - 1 && r >= cs.cnt8[s]) { r -= cs.cnt8[s]; ++s; }
    const float* sp = cs.src[s] + (size_t)r * 8;
    float4 a = *(const float4*)sp;
    float4 b = *(const float4*)(sp + 4);
    union { h2 h[4]; f16x8 v; } u;
    u.h[0] = __builtin_amdgcn_cvt_pkrtz(a.x, a.y);
    u.h[1] = __builtin_amdgcn_cvt_pkrtz(a.z, a.w);
    u.h[2] = __builtin_amdgcn_cvt_pkrtz(b.x, b.y);
    u.h[3] = __builtin_amdgcn_cvt_pkrtz(b.z, b.w);
    *(f16x8*)(cs.dst[s] + (size_t)r * 8) = u.v;
  }
}

// ---------------------------------------------------------------------------
// f16-in MFMA NT GEMM: C[m, bn*128+n] = sum_k A[m,k]*Wseg[bn][n,k] (+bias)
// A and W pre-converted f16 -> staging is 4x16B loads + 4 ds_write_b128 per
// thread per K-step, ZERO cvt VALU. LDS double-buffered [2][128][40] with
// ONE barrier per K-step (write buf -> prefetch -> barrier -> compute buf;
// step k+2's write to buf[cur] can only pass barrier k+1 after all waves
// finished compute k -> safe). Fragment/MFMA/epilogue layout = R0-verified.
// OUT_HALF=1 writes f16 (for st_h). Requires N=NT*128, K%32==0; M guarded.
// ---------------------------------------------------------------------------
template<int OUT_HALF>
__global__ __launch_bounds__(256) void gemm_h16(
    const _Float16* __restrict__ A, WSegsH wsg, const float* __restrict__ bias,
    void* __restrict__ Cp, int M, int NT, int K, int ldc)
{
  __shared__ _Float16 As[2][128][40];
  __shared__ _Float16 Bs[2][128][40];
  const int tid  = threadIdx.x;
  const int lane = tid & 63;
  const int wave = tid >> 6;
  const int wr = wave >> 1, wc = wave & 1;

  // bijective chunked XCD swizzle (verified R5: kills sibling-tile refetch)
  const int nwg = gridDim.x;
  const int q8 = nwg >> 3, r8 = nwg & 7;
  const int xcd = blockIdx.x & 7, pos = blockIdx.x >> 3;
  const int logical = (xcd < r8 ? xcd * (q8 + 1) : r8 * (q8 + 1) + (xcd - r8) * q8) + pos;
  const int bm = (logical / NT) * 128;
  const int bn = logical - (logical / NT) * NT;
  const _Float16* __restrict__ W = wsg.p[bn];

  // staging: thread covers rows {srow, srow+64}, 16B chunk sch (8 halves)
  const int srow = tid >> 2;
  const int sch  = (tid & 3) * 8;
  const _Float16* aptr[2];
  const _Float16* bptr[2];
  #pragma unroll
  for (int l = 0; l < 2; ++l) {
    int gm = bm + srow + 64 * l; if (gm > M - 1) gm = M - 1;
    aptr[l] = A + (size_t)gm * K + sch;
    bptr[l] = W + (size_t)(srow + 64 * l) * K + sch;
  }

  f32x4 acc[4][4];
  #pragma unroll
  for (int i = 0; i < 4; ++i)
    #pragma unroll
    for (int j = 0; j < 4; ++j) {
      acc[i][j].x = 0.f; acc[i][j].y = 0.f; acc[i][j].z = 0.f; acc[i][j].w = 0.f;
    }

  const int fr = lane & 15;
  const int fk = (lane >> 4) * 8;

  f16x8 av[2], bv[2];
  av[0] = *(const f16x8*)aptr[0]; av[1] = *(const f16x8*)aptr[1];
  bv[0] = *(const f16x8*)bptr[0]; bv[1] = *(const f16x8*)bptr[1];

  int cur = 0;
  for (int k0 = 0; k0 < K; k0 += 32, cur ^= 1) {
    *(f16x8*)&As[cur][srow     ][sch] = av[0];
    *(f16x8*)&As[cur][srow + 64][sch] = av[1];
    *(f16x8*)&Bs[cur][srow     ][sch] = bv[0];
    *(f16x8*)&Bs[cur][srow + 64][sch] = bv[1];
    if (k0 + 32 < K) {
      av[0] = *(const f16x8*)(aptr[0] + k0 + 32);
      av[1] = *(const f16x8*)(aptr[1] + k0 + 32);
      bv[0] = *(const f16x8*)(bptr[0] + k0 + 32);
      bv[1] = *(const f16x8*)(bptr[1] + k0 + 32);
    }
    __syncthreads();

    f16x8 af[4], bf[4];
    #pragma unroll
    for (int mi = 0; mi < 4; ++mi)
      af[mi] = *(const f16x8*)&As[cur][wr * 64 + mi * 16 + fr][fk];
    #pragma unroll
    for (int ni = 0; ni < 4; ++ni)
      bf[ni] = *(const f16x8*)&Bs[cur][wc * 64 + ni * 16 + fr][fk];
    #pragma unroll
    for (int mi = 0; mi < 4; ++mi)
      #pragma unroll
      for (int ni = 0; ni < 4; ++ni)
        acc[mi][ni] = __builtin_amdgcn_mfma_f32_16x16x32_f16(
            af[mi], bf[ni], acc[mi][ni], 0, 0, 0);
    // no trailing barrier: next step writes the OTHER buffer
  }

  #pragma unroll
  for (int mi = 0; mi < 4; ++mi) {
    int rb = bm + wr * 64 + mi * 16 + (lane >> 4) * 4;
    #pragma unroll
    for (int r = 0; r < 4; ++r) {
      int gm = rb + r;
      if (gm < M) {
        int gn = bn * 128 + wc * 64 + fr;
        #pragma unroll
        for (int ni = 0; ni < 4; ++ni) {
          float v = acc[mi][ni][r];
          if (bias) v += bias[gn + ni * 16];
          if (OUT_HALF) {
            ((_Float16*)Cp)[(size_t)gm * ldc + gn + ni * 16] = (_Float16)v;
          } else {
            ((float*)Cp)[(size_t)gm * ldc + gn + ni * 16] = v;
          }
        }
      }
    }
  }
}

// ---------------------------------------------------------------------------
// Legacy fp32-in GEMM (reg-staged cvt) — used only for the small agg projections.
// ---------------------------------------------------------------------------
__global__ __launch_bounds__(256) void gemm_nt_mfma(
    const float* __restrict__ A, WSegs ws, const float* __restrict__ bias,
    float* __restrict__ C, int M, int NT, int K, int ldc)
{
  __shared__ _Float16 As[128][40];
  __shared__ _Float16 Bs[128][40];
  const int tid  = threadIdx.x;
  const int lane = tid & 63;
  const int wave = tid >> 6;
  const int wr = wave >> 1, wc = wave & 1;

  const int nwg = gridDim.x;
  const int q8 = nwg >> 3, r8 = nwg & 7;
  const int xcd = blockIdx.x & 7, pos = blockIdx.x >> 3;
  const int logical = (xcd < r8 ? xcd * (q8 + 1) : r8 * (q8 + 1) + (xcd - r8) * q8) + pos;
  const int bm = (logical / NT) * 128;
  const int bn = logical - (logical / NT) * NT;
  const float* __restrict__ W = ws.p[bn];

  const int srow = tid >> 3;
  const int skq  = (tid & 7) * 4;
  const float* aptr[4];
  const float* bptr[4];
  #pragma unroll
  for (int l = 0; l < 4; ++l) {
    int gm = bm + srow + 32 * l; if (gm > M - 1) gm = M - 1;
    aptr[l] = A + (size_t)gm * K + skq;
    bptr[l] = W + (size_t)(srow + 32 * l) * K + skq;
  }

  f32x4 acc[4][4];
  #pragma unroll
  for (int i = 0; i < 4; ++i)
    #pragma unroll
    for (int j = 0; j < 4; ++j) {
      acc[i][j].x = 0.f; acc[i][j].y = 0.f; acc[i][j].z = 0.f; acc[i][j].w = 0.f;
    }

  const int fr = lane & 15;
  const int fk = (lane >> 4) * 8;

  float4 av[4], bv[4];
  #pragma unroll
  for (int l = 0; l < 4; ++l) {
    av[l] = *(const float4*)(aptr[l]);
    bv[l] = *(const float4*)(bptr[l]);
  }

  for (int k0 = 0; k0 < K; k0 += 32) {
    #pragma unroll
    for (int l = 0; l < 4; ++l) {
      f16x4 a4, b4;
      a4.x = (_Float16)av[l].x; a4.y = (_Float16)av[l].y;
      a4.z = (_Float16)av[l].z; a4.w = (_Float16)av[l].w;
      b4.x = (_Float16)bv[l].x; b4.y = (_Float16)bv[l].y;
      b4.z = (_Float16)bv[l].z; b4.w = (_Float16)bv[l].w;
      *(f16x4*)&As[srow + 32 * l][skq] = a4;
      *(f16x4*)&Bs[srow + 32 * l][skq] = b4;
    }
    __syncthreads();

    if (k0 + 32 < K) {
      #pragma unroll
      for (int l = 0; l < 4; ++l) {
        av[l] = *(const float4*)(aptr[l] + k0 + 32);
        bv[l] = *(const float4*)(bptr[l] + k0 + 32);
      }
    }

    f16x8 af[4], bf[4];
    #pragma unroll
    for (int mi = 0; mi < 4; ++mi)
      af[mi] = *(const f16x8*)&As[wr * 64 + mi * 16 + fr][fk];
    #pragma unroll
    for (int ni = 0; ni < 4; ++ni)
      bf[ni] = *(const f16x8*)&Bs[wc * 64 + ni * 16 + fr][fk];
    #pragma unroll
    for (int mi = 0; mi < 4; ++mi)
      #pragma unroll
      for (int ni = 0; ni < 4; ++ni)
        acc[mi][ni] = __builtin_amdgcn_mfma_f32_16x16x32_f16(
            af[mi], bf[ni], acc[mi][ni], 0, 0, 0);
    __syncthreads();
  }

  #pragma unroll
  for (int mi = 0; mi < 4; ++mi) {
    int rb = bm + wr * 64 + mi * 16 + (lane >> 4) * 4;
    #pragma unroll
    for (int r = 0; r < 4; ++r) {
      int gm = rb + r;
      if (gm < M) {
        int gn = bn * 128 + wc * 64 + fr;
        float* crow = C + (size_t)gm * ldc + gn;
        #pragma unroll
        for (int ni = 0; ni < 4; ++ni) {
          float v = acc[mi][ni][r];
          if (bias) v += bias[gn + ni * 16];
          crow[ni * 16] = v;
        }
      }
    }
  }
}

// ---------------------------------------------------------------------------
__global__ void lam_kernel(const float* __restrict__ lq1, const float* __restrict__ lk1,
                           const float* __restrict__ lq2, const float* __restrict__ lk2,
                           float* __restrict__ out) {
  int lane = threadIdx.x;
  float v1 = lane < 32 ? lq1[lane] * lk1[lane] : 0.f;
  float v2 = lane < 32 ? lq2[lane] * lk2[lane] : 0.f;
  v1 = wred_sum(v1);
  v2 = wred_sum(v2);
  if (lane == 0) out[0] = expf(v1) - expf(v2) + 0.2f;
}

// ---------------------------------------------------------------------------
// Differential self-attention, MFMA version (verified R3/R4/R5).
// ---------------------------------------------------------------------------
__global__ __launch_bounds__(512, 2) void diff_attn(
    const float* __restrict__ qkv, float* __restrict__ aout)
{
  __shared__ _Float16 Ks[2][272][40];   // [half][k-row][d(32)+pad8]
  __shared__ h2 Vt[64][148];            // Vt[d][kp] = (V[2kp][d], V[2kp+1][d])
  __shared__ h2 Pb[8][16][148];         // per-wave P: [qrow(16)][kp], pad zeroed

  const int h  = blockIdx.x & 3;
  const int bt = blockIdx.x >> 2;
  const int tid = threadIdx.x;
  const int lane = tid & 63;
  const int wave = tid >> 6;
  const int fr = lane & 15;             // fragment row/col index
  const int kb = (lane >> 4) * 4;       // C-layout row part / kp offset
  const float* base = qkv + (size_t)bt * NN * 768;

  union H4 { f16x4 v; h2 h[2]; };
  union H8 { f16x8 v; h2 h[4]; };

  // ---- stage K (both 32-col halves) as f16, rows padded/clamped to 272 ----
  for (int idx = tid; idx < 272 * 16; idx += 512) {
    int row = idx >> 4, q = idx & 15;
    int sr = row < NN ? row : NN - 1;
    float4 kv = *(const float4*)(base + (size_t)sr * 768 + 256 + h * 64 + q * 4);
    H4 t;
    t.h[0] = __builtin_amdgcn_cvt_pkrtz(kv.x, kv.y);
    t.h[1] = __builtin_amdgcn_cvt_pkrtz(kv.z, kv.w);
    *(f16x4*)&Ks[q >> 3][row][(q & 7) * 4] = t.v;
  }
  // ---- stage V transposed as (k,k+1) h2 pairs ----
  for (int idx = tid; idx < 136 * 16; idx += 512) {
    int mp = idx >> 4, dq = (idx & 15) * 4;
    int m0 = 2 * mp, m1 = 2 * mp + 1;
    if (m0 > NN - 1) m0 = NN - 1;
    if (m1 > NN - 1) m1 = NN - 1;
    float4 a = *(const float4*)(base + (size_t)m0 * 768 + 512 + h * 64 + dq);
    float4 b = *(const float4*)(base + (size_t)m1 * 768 + 512 + h * 64 + dq);
    Vt[dq + 0][mp] = __builtin_amdgcn_cvt_pkrtz(a.x, b.x);
    Vt[dq + 1][mp] = __builtin_amdgcn_cvt_pkrtz(a.y, b.y);
    Vt[dq + 2][mp] = __builtin_amdgcn_cvt_pkrtz(a.z, b.z);
    Vt[dq + 3][mp] = __builtin_amdgcn_cvt_pkrtz(a.w, b.w);
  }
  // ---- zero Vt pad columns kp=136..147 (PV reads up to 143) ----
  {
    h2 z; z.x = (__fp16)0.f; z.y = (__fp16)0.f;
    for (int idx = tid; idx < 64 * 12; idx += 512)
      Vt[idx / 12][136 + idx % 12] = z;
  }
  // zero this wave's P pad columns kp=136..147
  {
    h2 z; z.x = (__fp16)0.f; z.y = (__fp16)0.f;
    #pragma unroll
    for (int t = 0; t < 3; ++t) Pb[wave][fr][136 + (kb >> 2) * 3 + t] = z;
  }
  __syncthreads();

  const float scq = 0.17677669529663687f;  // 1/sqrt(32)

  for (int task = wave; task < 34; task += 8) {
    const int chunk = task >> 1;
    const int half  = task & 1;

    int qsrc = chunk * 16 + fr; if (qsrc > NN - 1) qsrc = NN - 1;
    const float* qr = base + (size_t)qsrc * 768 + h * 64 + half * 32 + kb * 2;
    f16x8 qf;
    {
      float4 a = *(const float4*)(qr);
      float4 b = *(const float4*)(qr + 4);
      H8 t;
      t.h[0] = __builtin_amdgcn_cvt_pkrtz(a.x, a.y);
      t.h[1] = __builtin_amdgcn_cvt_pkrtz(a.z, a.w);
      t.h[2] = __builtin_amdgcn_cvt_pkrtz(b.x, b.y);
      t.h[3] = __builtin_amdgcn_cvt_pkrtz(b.z, b.w);
      qf = t.v;
    }

    f32x4 s[17];
    #pragma unroll
    for (int mt = 0; mt < 17; ++mt) {
      f16x8 af = *(const f16x8*)&Ks[half][mt * 16 + fr][kb * 2];
      f32x4 z4 = {0.f, 0.f, 0.f, 0.f};
      s[mt] = __builtin_amdgcn_mfma_f32_16x16x32_f16(af, qf, z4, 0, 0, 0);
    }

    float mx = -1e30f;
    #pragma unroll
    for (int mt = 0; mt < 17; ++mt)
      #pragma unroll
      for (int r = 0; r < 4; ++r) {
        float v = s[mt][r] * scq;
        if (mt * 16 + kb + r >= NN) v = -1e30f;
        s[mt][r] = v;
        mx = fmaxf(mx, v);
      }
    mx = fmaxf(mx, __shfl_xor(mx, 16, 64));
    mx = fmaxf(mx, __shfl_xor(mx, 32, 64));
    float sum = 0.f;
    #pragma unroll
    for (int mt = 0; mt < 17; ++mt)
      #pragma unroll
      for (int r = 0; r < 4; ++r) {
        float p = __expf(s[mt][r] - mx);
        s[mt][r] = p;
        sum += p;
      }
    sum += __shfl_xor(sum, 16, 64);
    sum += __shfl_xor(sum, 32, 64);
    float inv = 1.f / sum;

    #pragma unroll
    for (int mt = 0; mt < 17; ++mt) {
      h2 lo = __builtin_amdgcn_cvt_pkrtz(s[mt][0] * inv, s[mt][1] * inv);
      h2 hi = __builtin_amdgcn_cvt_pkrtz(s[mt][2] * inv, s[mt][3] * inv);
      int kp = 8 * mt + (kb >> 1);
      Pb[wave][fr][kp]     = lo;
      Pb[wave][fr][kp + 1] = hi;
    }

    f32x4 o[4];
    #pragma unroll
    for (int nt = 0; nt < 4; ++nt) {
      o[nt].x = 0.f; o[nt].y = 0.f; o[nt].z = 0.f; o[nt].w = 0.f;
    }
    #pragma unroll
    for (int s9 = 0; s9 < 9; ++s9) {
      f16x8 pa = *(const f16x8*)&Pb[wave][fr][16 * s9 + kb];
      #pragma unroll
      for (int nt = 0; nt < 4; ++nt) {
        f16x8 vb = *(const f16x8*)&Vt[nt * 16 + fr][16 * s9 + kb];
        o[nt] = __builtin_amdgcn_mfma_f32_16x16x32_f16(pa, vb, o[nt], 0, 0, 0);
      }
    }

    float* ab = aout + (size_t)half * (50496ull * 256ull);
    #pragma unroll
    for (int r = 0; r < 4; ++r) {
      int qrow = chunk * 16 + kb + r;
      if (qrow < NN) {
        float* op = ab + ((size_t)(bt * NN + qrow) * 4 + h) * 64;
        #pragma unroll
        for (int nt = 0; nt < 4; ++nt) op[nt * 16 + fr] = o[nt][r];
      }
    }
  }
}

// ---------------------------------------------------------------------------
// diff-LN: now writes f16 st_h directly (out-proj reads f16; fp32 st removed)
// ---------------------------------------------------------------------------
__global__ __launch_bounds__(256) void diff_ln(
    const float* __restrict__ a1, const float* __restrict__ a2,
    const float* __restrict__ lamp,
    const float* __restrict__ g, const float* __restrict__ b,
    _Float16* __restrict__ st)
{
  const int btn = blockIdx.x;
  const int lane = threadIdx.x & 63;
  const int h = threadIdx.x >> 6;
  const float lam = lamp[0];
  size_t off = ((size_t)btn * 4 + h) * 64 + lane;
  float y = a1[off] - lam * a2[off];
  float mean = wred_sum(y) * (1.f / 64.f);
  float t = y - mean;
  float var = wred_sum(t * t) * (1.f / 64.f);
  float r = rsqrtf(var + 1e-5f);
  st[(size_t)btn * 640 + h * 64 + lane] = (_Float16)((t * r * g[lane] + b[lane]) * 0.8f);
}

// ---------------------------------------------------------------------------
// Temporal self-attention (verified R4/R5) — output store now f16 into st_h.
// ---------------------------------------------------------------------------
__global__ __launch_bounds__(256) void temporal_attn(
    const float* __restrict__ qkvt, _Float16* __restrict__ st)
{
  __shared__ float qs[48][68];
  __shared__ float kt[48][68];
  __shared__ float vt[48][68];
  __shared__ float Ss[48][28];
  const int b = blockIdx.x / NN;
  const int n = blockIdx.x % NN;
  const int tid = threadIdx.x;
  const int lane = tid & 63;
  const int wave = tid >> 6;

  for (int idx = tid; idx < 48 * 16; idx += 256) {
    int row = idx >> 4, dq = (idx & 15) * 4;
    int h = row / 24, t = row - h * 24;
    const float* g = qkvt + ((size_t)(b * TT + t) * NN + n) * 640 + h * 64 + dq;
    *(float4*)&qs[row][dq] = *(const float4*)(g);
    *(float4*)&kt[row][dq] = *(const float4*)(g + 128);
    *(float4*)&vt[row][dq] = *(const float4*)(g + 256);
  }
  __syncthreads();

  for (int idx = tid; idx < 48 * 24; idx += 256) {
    int row = idx / 24, s = idx - row * 24;
    int krow = (row >= 24 ? 24 : 0) + s;
    float a0 = 0.f, a1 = 0.f, a2 = 0.f, a3 = 0.f;
    #pragma unroll
    for (int dq = 0; dq < 64; dq += 4) {
      float4 q = *(const float4*)&qs[row][dq];
      float4 k = *(const float4*)&kt[krow][dq];
      a0 = fmaf(q.x, k.x, a0);
      a1 = fmaf(q.y, k.y, a1);
      a2 = fmaf(q.z, k.z, a2);
      a3 = fmaf(q.w, k.w, a3);
    }
    Ss[row][s] = ((a0 + a1) + (a2 + a3)) * 0.125f;
  }
  __syncthreads();

  for (int r = wave; r < 48; r += 4) {
    float v = lane < 24 ? Ss[r][lane] : -1e30f;
    float mx = wred_max(v);
    float p = lane < 24 ? __expf(v - mx) : 0.f;
    float inv = 1.f / wred_sum(p);
    if (lane < 24) Ss[r][lane] = p * inv;
  }
  __syncthreads();

  for (int idx = tid; idx < 48 * 16; idx += 256) {
    int row = idx >> 4, dq = (idx & 15) * 4;
    int h = row / 24, t = row - h * 24;
    int bs = h * 24;
    float ax = 0.f, ay = 0.f, az = 0.f, aw = 0.f;
    #pragma unroll
    for (int s = 0; s < 24; ++s) {
      float p = Ss[row][s];
      float4 v = *(const float4*)&vt[bs + s][dq];
      ax = fmaf(p, v.x, ax);
      ay = fmaf(p, v.y, ay);
      az = fmaf(p, v.z, az);
      aw = fmaf(p, v.w, aw);
    }
    union { h2 h[2]; f16x4 v; } o2;
    o2.h[0] = __builtin_amdgcn_cvt_pkrtz(ax, ay);
    o2.h[1] = __builtin_amdgcn_cvt_pkrtz(az, aw);
    *(f16x4*)(st + ((size_t)(b * TT + t) * NN + n) * 640 + 384 + h * 64 + dq) = o2.v;
  }
}

// ---------------------------------------------------------------------------
// Temporal-global attention (verified R4/R5) — output store now f16 into st_h.
// ---------------------------------------------------------------------------
__global__ __launch_bounds__(256) void tglobal_attn(
    const float* __restrict__ qkvt, const float* __restrict__ q_agg,
    const float* __restrict__ tmp_map, _Float16* __restrict__ st)
{
  __shared__ float qg[24][68];
  __shared__ float kg[48][68];
  __shared__ float vg[48][68];
  __shared__ float Sg[24][28];
  __shared__ float tgx[12][128];
  const int b = blockIdx.x / NN;
  const int n = blockIdx.x % NN;
  const int tid = threadIdx.x;
  const int lane = tid & 63;
  const int wave = tid >> 6;

  for (int idx = tid; idx < 48 * 16; idx += 256) {
    int row = idx >> 4, dq = (idx & 15) * 4;
    int h = row / 24, t = row - h * 24;
    const float* g = qkvt + ((size_t)(b * TT + t) * NN + n) * 640 + 384 + h * 64 + dq;
    *(float4*)&kg[row][dq] = *(const float4*)(g);
    *(float4*)&vg[row][dq] = *(const float4*)(g + 128);
  }
  for (int idx = tid; idx < 24 * 16; idx += 256) {
    int row = idx >> 4, dq = (idx & 15) * 4;   // row = h*12+s
    int h = row / 12, s = row - h * 12;
    *(float4*)&qg[row][dq] =
        *(const float4*)(q_agg + ((size_t)n * 12 + s) * 128 + h * 64 + dq);
  }
  __syncthreads();

  for (int idx = tid; idx < 24 * 24; idx += 256) {
    int row = idx / 24, t = idx - row * 24;
    int krow = (row >= 12 ? 24 : 0) + t;
    float a0 = 0.f, a1 = 0.f, a2 = 0.f, a3 = 0.f;
    #pragma unroll
    for (int dq = 0; dq < 64; dq += 4) {
      float4 q = *(const float4*)&qg[row][dq];
      float4 k = *(const float4*)&kg[krow][dq];
      a0 = fmaf(q.x, k.x, a0);
      a1 = fmaf(q.y, k.y, a1);
      a2 = fmaf(q.z, k.z, a2);
      a3 = fmaf(q.w, k.w, a3);
    }
    Sg[row][t] = ((a0 + a1) + (a2 + a3)) * 0.125f;
  }
  __syncthreads();

  for (int r = wave; r < 24; r += 4) {
    float v = lane < 24 ? Sg[r][lane] : -1e30f;
    float mx = wred_max(v);
    float p = lane < 24 ? __expf(v - mx) : 0.f;
    float inv = 1.f / wred_sum(p);
    if (lane < 24) Sg[r][lane] = p * inv;
  }
  __syncthreads();

  for (int idx = tid; idx < 24 * 16; idx += 256) {
    int row = idx >> 4, dq = (idx & 15) * 4;   // row = h*12+s
    int h = row / 12, s = row - h * 12;
    int bt_ = h * 24;
    float ax = 0.f, ay = 0.f, az = 0.f, aw = 0.f;
    #pragma unroll
    for (int t = 0; t < 24; ++t) {
      float p = Sg[row][t];
      float4 v = *(const float4*)&vg[bt_ + t][dq];
      ax = fmaf(p, v.x, ax);
      ay = fmaf(p, v.y, ay);
      az = fmaf(p, v.z, az);
      aw = fmaf(p, v.w, aw);
    }
    float4 o = {ax, ay, az, aw};
    *(float4*)&tgx[s][h * 64 + dq] = o;
  }
  __syncthreads();

  for (int idx = tid; idx < 24 * 32; idx += 256) {
    int t = idx >> 5, cq = (idx & 31) * 4;
    const float* tm = tmp_map + ((size_t)(b * NN + n) * TT + t) * 12;
    float ax = 0.f, ay = 0.f, az = 0.f, aw = 0.f;
    #pragma unroll
    for (int s = 0; s < 12; ++s) {
      float m = tm[s];
      float4 v = *(const float4*)&tgx[s][cq];
      ax = fmaf(m, v.x, ax);
      ay = fmaf(m, v.y, ay);
      az = fmaf(m, v.z, az);
      aw = fmaf(m, v.w, aw);
    }
    union { h2 h[2]; f16x4 v; } o2;
    o2.h[0] = __builtin_amdgcn_cvt_pkrtz(ax, ay);
    o2.h[1] = __builtin_amdgcn_cvt_pkrtz(az, aw);
    *(f16x4*)(st + ((size_t)(b * TT + t) * NN + n) * 640 + 512 + cq) = o2.v;
  }
}

// ---------------------------------------------------------------------------
__global__ __launch_bounds__(256) void agg_attn(
    const float* __restrict__ qkva, float* __restrict__ sx, int Ni)
{
  __shared__ float kT[64 * 64];
  __shared__ float vl[64 * 64];
  const int h = blockIdx.x & 1;
  const int bt = blockIdx.x >> 1;
  const int tid = threadIdx.x;
  const int lane = tid & 63;
  const int wave = tid >> 6;
  for (int idx = tid; idx < Ni * 64; idx += 256) {
    int m = idx >> 6, d = idx & 63;
    size_t row = (size_t)(bt * Ni + m) * 384;
    kT[d * Ni + m] = qkva[row + 128 + h * 64 + d];
    vl[m * 64 + d] = qkva[row + 256 + h * 64 + d];
  }
  __syncthreads();
  int mc = lane < Ni ? lane : Ni - 1;
  bool valid = lane < Ni;
  for (int n = wave; n < Ni; n += 4) {
    float qv = qkva[(size_t)(bt * Ni + n) * 384 + h * 64 + lane];
    float sc_ = 0.f;
    #pragma unroll
    for (int d = 0; d < 64; ++d) {
      float qd = __shfl(qv, d, 64);
      sc_ = fmaf(qd, kT[d * Ni + mc], sc_);
    }
    sc_ *= 0.125f;
    float mx = wred_max(valid ? sc_ : -1e30f);
    float p = valid ? __expf(sc_ - mx) : 0.f;
    float inv = 1.f / wred_sum(p);
    float o = 0.f;
    for (int m = 0; m < Ni; ++m) {
      float pm = __shfl(p, m, 64);
      o = fmaf(pm, vl[m * 64 + lane], o);
    }
    sx[(size_t)(bt * Ni + n) * 128 + h * 64 + lane] = o * inv;
  }
}

// ---------------------------------------------------------------------------
// mmap: output now f16 (sg_h feeds the f16 Wagg GEMM)
// ---------------------------------------------------------------------------
__global__ __launch_bounds__(256) void mmap_kernel(
    const float* __restrict__ sx0, const float* __restrict__ sx1,
    const float* __restrict__ M0, const float* __restrict__ M1,
    _Float16* __restrict__ sg)
{
  __shared__ float s0[32 * 128];
  __shared__ float s1[64 * 128];
  const int bt = blockIdx.x;
  const int chunk = blockIdx.y;
  const int tid = threadIdx.x;
  for (int idx = tid; idx < 32 * 128; idx += 256) s0[idx] = sx0[(size_t)bt * 32 * 128 + idx];
  for (int idx = tid; idx < 64 * 128; idx += 256) s1[idx] = sx1[(size_t)bt * 64 * 128 + idx];
  __syncthreads();
  for (int idx = tid; idx < 88 * 128; idx += 256) {
    int n = chunk * 88 + (idx >> 7);
    if (n < NN) {
      int c = idx & 127;
      float acc = 0.f;
      #pragma unroll
      for (int m = 0; m < 32; ++m) acc = fmaf(M0[m * NN + n], s0[m * 128 + c], acc);
      #pragma unroll
      for (int m = 0; m < 64; ++m) acc = fmaf(M1[m * NN + n], s1[m * 128 + c], acc);
      sg[((size_t)bt * NN + n) * 128 + c] = (_Float16)acc;
    }
  }
}

// ---------------------------------------------------------------------------
extern "C" void kernel_launch(void* const* d_in, const int* in_sizes, int n_in,
                              void* d_out, int out_size, void* d_ws, size_t ws_size,
                              hipStream_t stream)
{
  const float* x       = (const float*)d_in[0];
  const float* agg_x0  = (const float*)d_in[1];
  const float* agg_x1  = (const float*)d_in[2];
  const float* tmp_map = (const float*)d_in[3];
  const float* Wq_s = (const float*)d_in[4];
  const float* Wk_s = (const float*)d_in[5];
  const float* Wv_s = (const float*)d_in[6];
  const float* lq1 = (const float*)d_in[7];
  const float* lk1 = (const float*)d_in[8];
  const float* lq2 = (const float*)d_in[9];
  const float* lk2 = (const float*)d_in[10];
  const float* ln_g = (const float*)d_in[11];
  const float* ln_b = (const float*)d_in[12];
  const float* Wq_a0 = (const float*)d_in[13];
  const float* Wk_a0 = (const float*)d_in[14];
  const float* Wv_a0 = (const float*)d_in[15];
  const float* Wq_a1 = (const float*)d_in[16];
  const float* Wk_a1 = (const float*)d_in[17];
  const float* Wv_a1 = (const float*)d_in[18];
  const float* M0   = (const float*)d_in[19];
  const float* M1   = (const float*)d_in[20];
  const float* Wagg = (const float*)d_in[21];
  const float* bagg = (const float*)d_in[22];
  const float* Wq_t = (const float*)d_in[23];
  const float* Wk_t = (const float*)d_in[24];
  const float* Wv_t = (const float*)d_in[25];
  const float* q_agg = (const float*)d_in[26];
  const float* Wk_tg = (const float*)d_in[27];
  const float* Wv_tg = (const float*)d_in[28];
  const float* Wout  = (const float*)d_in[29];
  const float* bout  = (const float*)d_in[30];
  float* ws  = (float*)d_ws;
  float* out = (float*)d_out;

  const size_t o_lam  = 1114112;
  const size_t o_A    = 1114128;
  const size_t o_qkvt = o_A + 38780928;
  const size_t o_B    = o_qkvt + 32317440;

  float* lamp  = ws + o_lam;
  float* qkv_s = ws + o_A;                       // fp32, dead after diff_attn
  _Float16* st_h = (_Float16*)(ws + o_A);        // reuses o_A after diff_ln
  float* qkvt  = ws + o_qkvt;
  _Float16* x_h = (_Float16*)(ws + o_B);         // dead after qkvt GEMM
  float* a1    = ws + o_B;                       // written by diff_attn (after x_h dead)
  float* qkva0 = ws + o_B;                       // after diff_ln
  float* qkva1 = qkva0 + 2359296;
  float* sx0   = qkva0 + 7077888;
  float* sx1   = qkva0 + 7864320;
  _Float16* sg_h = (_Float16*)(qkva0 + 9437184);
  _Float16* Wh  = (_Float16*)ws;                 // f16 weights in old W_all region

  hipLaunchKernelGGL(lam_kernel, dim3(1), dim3(64), 0, stream, lq1, lk1, lq2, lk2, lamp);

  // ---- one-shot fp32->f16 conversion: x + all h16-GEMM weights ----
  CvtSegs cs;
  cs.src[0] = x;      cs.dst[0] = x_h;          cs.cnt8[0] = 25853952 / 8;
  cs.src[1] = Wq_s;   cs.dst[1] = Wh + 0;       cs.cnt8[1] = 131072 / 8;
  cs.src[2] = Wk_s;   cs.dst[2] = Wh + 131072;  cs.cnt8[2] = 131072 / 8;
  cs.src[3] = Wv_s;   cs.dst[3] = Wh + 262144;  cs.cnt8[3] = 131072 / 8;
  cs.src[4] = Wq_t;   cs.dst[4] = Wh + 393216;  cs.cnt8[4] = 65536 / 8;
  cs.src[5] = Wk_t;   cs.dst[5] = Wh + 458752;  cs.cnt8[5] = 65536 / 8;
  cs.src[6] = Wv_t;   cs.dst[6] = Wh + 524288;  cs.cnt8[6] = 65536 / 8;
  cs.src[7] = Wk_tg;  cs.dst[7] = Wh + 589824;  cs.cnt8[7] = 65536 / 8;
  cs.src[8] = Wv_tg;  cs.dst[8] = Wh + 655360;  cs.cnt8[8] = 65536 / 8;
  cs.src[9] = Wagg;   cs.dst[9] = Wh + 720896;  cs.cnt8[9] = 16384 / 8;
  cs.src[10] = Wout;  cs.dst[10] = Wh + 737280; cs.cnt8[10] = 327680 / 8;
  hipLaunchKernelGGL(cvt_f16, dim3(2048), dim3(256), 0, stream, cs, 11, 3364864);

  const int Mx = 50496;

  // qkv projection: N=768 (6 tiles)
  WSegsH wqkv; wqkv.p[0] = Wh; wqkv.p[1] = Wh + 65536;
  wqkv.p[2] = Wh + 131072; wqkv.p[3] = Wh + 196608;
  wqkv.p[4] = Wh + 262144; wqkv.p[5] = Wh + 327680;
  hipLaunchKernelGGL((gemm_h16<0>), dim3(395 * 6), dim3(256), 0, stream,
                     x_h, wqkv, (const float*)nullptr, (void*)qkv_s, Mx, 6, 512, 768);

  // temporal qkv: N=640 (5 tiles) — before diff_attn so x_h dies before a1
  WSegsH wt; wt.p[0] = Wh + 393216; wt.p[1] = Wh + 458752; wt.p[2] = Wh + 524288;
  wt.p[3] = Wh + 589824; wt.p[4] = Wh + 655360; wt.p[5] = Wh + 393216;
  hipLaunchKernelGGL((gemm_h16<0>), dim3(395 * 5), dim3(256), 0, stream,
                     x_h, wt, (const float*)nullptr, (void*)qkvt, Mx, 5, 512, 640);

  hipLaunchKernelGGL(diff_attn, dim3(768), dim3(512), 0, stream, qkv_s, a1);
  hipLaunchKernelGGL(diff_ln, dim3(Mx), dim3(256), 0, stream,
                     a1, a1 + 12926976, lamp, ln_g, ln_b, st_h);
  hipLaunchKernelGGL(temporal_attn, dim3(8 * NN), dim3(256), 0, stream, qkvt, st_h);
  hipLaunchKernelGGL(tglobal_attn, dim3(8 * NN), dim3(256), 0, stream, qkvt, q_agg, tmp_map, st_h);

  // agg projections (small): legacy fp32 GEMM
  WSegs wa0; wa0.p[0] = Wq_a0; wa0.p[1] = Wk_a0; wa0.p[2] = Wv_a0;
  wa0.p[3] = wa0.p[4] = wa0.p[5] = Wq_a0;
  hipLaunchKernelGGL(gemm_nt_mfma, dim3(48 * 3), dim3(256), 0, stream,
                     agg_x0, wa0, (const float*)nullptr, qkva0, 6144, 3, 512, 384);
  WSegs wa1; wa1.p[0] = Wq_a1; wa1.p[1] = Wk_a1; wa1.p[2] = Wv_a1;
  wa1.p[3] = wa1.p[4] = wa1.p[5] = Wq_a1;
  hipLaunchKernelGGL(gemm_nt_mfma, dim3(96 * 3), dim3(256), 0, stream,
                     agg_x1, wa1, (const float*)nullptr, qkva1, 12288, 3, 512, 384);

  hipLaunchKernelGGL(agg_attn, dim3(384), dim3(256), 0, stream, qkva0, sx0, 32);
  hipLaunchKernelGGL(agg_attn, dim3(384), dim3(256), 0, stream, qkva1, sx1, 64);
  hipLaunchKernelGGL(mmap_kernel, dim3(192, 3), dim3(256), 0, stream, sx0, sx1, M0, M1, sg_h);

  // sg @ Wagg.T + bagg -> st_h cols 256..383 (f16 out)
  WSegsH wag; wag.p[0] = Wh + 720896;
  wag.p[1] = wag.p[2] = wag.p[3] = wag.p[4] = wag.p[5] = wag.p[0];
  hipLaunchKernelGGL((gemm_h16<1>), dim3(395 * 1), dim3(256), 0, stream,
                     sg_h, wag, bagg, (void*)(st_h + 256), Mx, 1, 128, 640);

  // out projection: N=512 (4 tiles of Wout)
  WSegsH wo; wo.p[0] = Wh + 737280; wo.p[1] = Wh + 737280 + 81920;
  wo.p[2] = Wh + 737280 + 163840; wo.p[3] = Wh + 737280 + 245760;
  wo.p[4] = wo.p[5] = wo.p[0];
  hipLaunchKernelGGL((gemm_h16<0>), dim3(395 * 4), dim3(256), 0, stream,
                     st_h, wo, bout, (void*)out, Mx, 4, 640, 512);
}

// Round 7
// 894.104 us; speedup vs baseline: 3.4971x; 1.0674x over previous
//
#include <hip/hip_runtime.h>

#define NN 263
#define TT 24

typedef __fp16 h2 __attribute__((ext_vector_type(2)));
typedef _Float16 f16x4 __attribute__((ext_vector_type(4)));
typedef _Float16 f16x8 __attribute__((ext_vector_type(8)));
typedef float f32x4 __attribute__((ext_vector_type(4)));

struct WSegs  { const float* p[6]; };      // fp32 weight tiles (legacy gemm)
struct WSegsH { const _Float16* p[6]; };   // f16 weight tiles
struct CvtSegs { const float* src[11]; _Float16* dst[11]; int cnt8[11]; };

static __device__ __forceinline__ float wred_sum(float v) {
  #pragma unroll
  for (int off = 32; off >= 1; off >>= 1) v += __shfl_xor(v, off, 64);
  return v;
}
static __device__ __forceinline__ float wred_max(float v) {
  #pragma unroll
  for (int off = 32; off >= 1; off >>= 1) v = fmaxf(v, __shfl_xor(v, off, 64));
  return v;
}

// ---------------------------------------------------------------------------
// Batched fp32 -> f16 convert (x + all weights), 8 elems/thread-iter.
// ---------------------------------------------------------------------------
__global__ __launch_bounds__(256) void cvt_f16(CvtSegs cs, int nseg, int total8)
{
  const int stride = gridDim.x * 256;
  for (int i = blockIdx.x * 256 + threadIdx.x; i < total8; i += stride) {
    int r = i, s = 0;
    while (s < nseg - 1 && r >= cs.cnt8[s]) { r -= cs.cnt8[s]; ++s; }
    const float* sp = cs.src[s] + (size_t)r * 8;
    float4 a = *(const float4*)sp;
    float4 b = *(const float4*)(sp + 4);
    union { h2 h[4]; f16x8 v; } u;
    u.h[0] = __builtin_amdgcn_cvt_pkrtz(a.x, a.y);
    u.h[1] = __builtin_amdgcn_cvt_pkrtz(a.z, a.w);
    u.h[2] = __builtin_amdgcn_cvt_pkrtz(b.x, b.y);
    u.h[3] = __builtin_amdgcn_cvt_pkrtz(b.z, b.w);
    *(f16x8*)(cs.dst[s] + (size_t)r * 8) = u.v;
  }
}

// ---------------------------------------------------------------------------
// f16-in MFMA NT GEMM (verified R6): dbuf LDS, one barrier/K-step.
// ---------------------------------------------------------------------------
template<int OUT_HALF>
__global__ __launch_bounds__(256) void gemm_h16(
    const _Float16* __restrict__ A, WSegsH wsg, const float* __restrict__ bias,
    void* __restrict__ Cp, int M, int NT, int K, int ldc)
{
  __shared__ _Float16 As[2][128][40];
  __shared__ _Float16 Bs[2][128][40];
  const int tid  = threadIdx.x;
  const int lane = tid & 63;
  const int wave = tid >> 6;
  const int wr = wave >> 1, wc = wave & 1;

  const int nwg = gridDim.x;
  const int q8 = nwg >> 3, r8 = nwg & 7;
  const int xcd = blockIdx.x & 7, pos = blockIdx.x >> 3;
  const int logical = (xcd < r8 ? xcd * (q8 + 1) : r8 * (q8 + 1) + (xcd - r8) * q8) + pos;
  const int bm = (logical / NT) * 128;
  const int bn = logical - (logical / NT) * NT;
  const _Float16* __restrict__ W = wsg.p[bn];

  const int srow = tid >> 2;
  const int sch  = (tid & 3) * 8;
  const _Float16* aptr[2];
  const _Float16* bptr[2];
  #pragma unroll
  for (int l = 0; l < 2; ++l) {
    int gm = bm + srow + 64 * l; if (gm > M - 1) gm = M - 1;
    aptr[l] = A + (size_t)gm * K + sch;
    bptr[l] = W + (size_t)(srow + 64 * l) * K + sch;
  }

  f32x4 acc[4][4];
  #pragma unroll
  for (int i = 0; i < 4; ++i)
    #pragma unroll
    for (int j = 0; j < 4; ++j) {
      acc[i][j].x = 0.f; acc[i][j].y = 0.f; acc[i][j].z = 0.f; acc[i][j].w = 0.f;
    }

  const int fr = lane & 15;
  const int fk = (lane >> 4) * 8;

  f16x8 av[2], bv[2];
  av[0] = *(const f16x8*)aptr[0]; av[1] = *(const f16x8*)aptr[1];
  bv[0] = *(const f16x8*)bptr[0]; bv[1] = *(const f16x8*)bptr[1];

  int cur = 0;
  for (int k0 = 0; k0 < K; k0 += 32, cur ^= 1) {
    *(f16x8*)&As[cur][srow     ][sch] = av[0];
    *(f16x8*)&As[cur][srow + 64][sch] = av[1];
    *(f16x8*)&Bs[cur][srow     ][sch] = bv[0];
    *(f16x8*)&Bs[cur][srow + 64][sch] = bv[1];
    if (k0 + 32 < K) {
      av[0] = *(const f16x8*)(aptr[0] + k0 + 32);
      av[1] = *(const f16x8*)(aptr[1] + k0 + 32);
      bv[0] = *(const f16x8*)(bptr[0] + k0 + 32);
      bv[1] = *(const f16x8*)(bptr[1] + k0 + 32);
    }
    __syncthreads();

    f16x8 af[4], bf[4];
    #pragma unroll
    for (int mi = 0; mi < 4; ++mi)
      af[mi] = *(const f16x8*)&As[cur][wr * 64 + mi * 16 + fr][fk];
    #pragma unroll
    for (int ni = 0; ni < 4; ++ni)
      bf[ni] = *(const f16x8*)&Bs[cur][wc * 64 + ni * 16 + fr][fk];
    #pragma unroll
    for (int mi = 0; mi < 4; ++mi)
      #pragma unroll
      for (int ni = 0; ni < 4; ++ni)
        acc[mi][ni] = __builtin_amdgcn_mfma_f32_16x16x32_f16(
            af[mi], bf[ni], acc[mi][ni], 0, 0, 0);
  }

  #pragma unroll
  for (int mi = 0; mi < 4; ++mi) {
    int rb = bm + wr * 64 + mi * 16 + (lane >> 4) * 4;
    #pragma unroll
    for (int r = 0; r < 4; ++r) {
      int gm = rb + r;
      if (gm < M) {
        int gn = bn * 128 + wc * 64 + fr;
        #pragma unroll
        for (int ni = 0; ni < 4; ++ni) {
          float v = acc[mi][ni][r];
          if (bias) v += bias[gn + ni * 16];
          if (OUT_HALF) {
            ((_Float16*)Cp)[(size_t)gm * ldc + gn + ni * 16] = (_Float16)v;
          } else {
            ((float*)Cp)[(size_t)gm * ldc + gn + ni * 16] = v;
          }
        }
      }
    }
  }
}

// ---------------------------------------------------------------------------
// Legacy fp32-in GEMM — small agg projections only.
// ---------------------------------------------------------------------------
__global__ __launch_bounds__(256) void gemm_nt_mfma(
    const float* __restrict__ A, WSegs ws, const float* __restrict__ bias,
    float* __restrict__ C, int M, int NT, int K, int ldc)
{
  __shared__ _Float16 As[128][40];
  __shared__ _Float16 Bs[128][40];
  const int tid  = threadIdx.x;
  const int lane = tid & 63;
  const int wave = tid >> 6;
  const int wr = wave >> 1, wc = wave & 1;

  const int nwg = gridDim.x;
  const int q8 = nwg >> 3, r8 = nwg & 7;
  const int xcd = blockIdx.x & 7, pos = blockIdx.x >> 3;
  const int logical = (xcd < r8 ? xcd * (q8 + 1) : r8 * (q8 + 1) + (xcd - r8) * q8) + pos;
  const int bm = (logical / NT) * 128;
  const int bn = logical - (logical / NT) * NT;
  const float* __restrict__ W = ws.p[bn];

  const int srow = tid >> 3;
  const int skq  = (tid & 7) * 4;
  const float* aptr[4];
  const float* bptr[4];
  #pragma unroll
  for (int l = 0; l < 4; ++l) {
    int gm = bm + srow + 32 * l; if (gm > M - 1) gm = M - 1;
    aptr[l] = A + (size_t)gm * K + skq;
    bptr[l] = W + (size_t)(srow + 32 * l) * K + skq;
  }

  f32x4 acc[4][4];
  #pragma unroll
  for (int i = 0; i < 4; ++i)
    #pragma unroll
    for (int j = 0; j < 4; ++j) {
      acc[i][j].x = 0.f; acc[i][j].y = 0.f; acc[i][j].z = 0.f; acc[i][j].w = 0.f;
    }

  const int fr = lane & 15;
  const int fk = (lane >> 4) * 8;

  float4 av[4], bv[4];
  #pragma unroll
  for (int l = 0; l < 4; ++l) {
    av[l] = *(const float4*)(aptr[l]);
    bv[l] = *(const float4*)(bptr[l]);
  }

  for (int k0 = 0; k0 < K; k0 += 32) {
    #pragma unroll
    for (int l = 0; l < 4; ++l) {
      f16x4 a4, b4;
      a4.x = (_Float16)av[l].x; a4.y = (_Float16)av[l].y;
      a4.z = (_Float16)av[l].z; a4.w = (_Float16)av[l].w;
      b4.x = (_Float16)bv[l].x; b4.y = (_Float16)bv[l].y;
      b4.z = (_Float16)bv[l].z; b4.w = (_Float16)bv[l].w;
      *(f16x4*)&As[srow + 32 * l][skq] = a4;
      *(f16x4*)&Bs[srow + 32 * l][skq] = b4;
    }
    __syncthreads();

    if (k0 + 32 < K) {
      #pragma unroll
      for (int l = 0; l < 4; ++l) {
        av[l] = *(const float4*)(aptr[l] + k0 + 32);
        bv[l] = *(const float4*)(bptr[l] + k0 + 32);
      }
    }

    f16x8 af[4], bf[4];
    #pragma unroll
    for (int mi = 0; mi < 4; ++mi)
      af[mi] = *(const f16x8*)&As[wr * 64 + mi * 16 + fr][fk];
    #pragma unroll
    for (int ni = 0; ni < 4; ++ni)
      bf[ni] = *(const f16x8*)&Bs[wc * 64 + ni * 16 + fr][fk];
    #pragma unroll
    for (int mi = 0; mi < 4; ++mi)
      #pragma unroll
      for (int ni = 0; ni < 4; ++ni)
        acc[mi][ni] = __builtin_amdgcn_mfma_f32_16x16x32_f16(
            af[mi], bf[ni], acc[mi][ni], 0, 0, 0);
    __syncthreads();
  }

  #pragma unroll
  for (int mi = 0; mi < 4; ++mi) {
    int rb = bm + wr * 64 + mi * 16 + (lane >> 4) * 4;
    #pragma unroll
    for (int r = 0; r < 4; ++r) {
      int gm = rb + r;
      if (gm < M) {
        int gn = bn * 128 + wc * 64 + fr;
        float* crow = C + (size_t)gm * ldc + gn;
        #pragma unroll
        for (int ni = 0; ni < 4; ++ni) {
          float v = acc[mi][ni][r];
          if (bias) v += bias[gn + ni * 16];
          crow[ni * 16] = v;
        }
      }
    }
  }
}

// ---------------------------------------------------------------------------
__global__ void lam_kernel(const float* __restrict__ lq1, const float* __restrict__ lk1,
                           const float* __restrict__ lq2, const float* __restrict__ lk2,
                           float* __restrict__ out) {
  int lane = threadIdx.x;
  float v1 = lane < 32 ? lq1[lane] * lk1[lane] : 0.f;
  float v2 = lane < 32 ? lq2[lane] * lk2[lane] : 0.f;
  v1 = wred_sum(v1);
  v2 = wred_sum(v2);
  if (lane == 0) out[0] = expf(v1) - expf(v2) + 0.2f;
}

// ---------------------------------------------------------------------------
// Differential self-attention, MFMA version (verified R3-R6).
// ---------------------------------------------------------------------------
__global__ __launch_bounds__(512, 2) void diff_attn(
    const float* __restrict__ qkv, float* __restrict__ aout)
{
  __shared__ _Float16 Ks[2][272][40];   // [half][k-row][d(32)+pad8]
  __shared__ h2 Vt[64][148];            // Vt[d][kp] = (V[2kp][d], V[2kp+1][d])
  __shared__ h2 Pb[8][16][148];         // per-wave P: [qrow(16)][kp], pad zeroed

  const int h  = blockIdx.x & 3;
  const int bt = blockIdx.x >> 2;
  const int tid = threadIdx.x;
  const int lane = tid & 63;
  const int wave = tid >> 6;
  const int fr = lane & 15;             // fragment row/col index
  const int kb = (lane >> 4) * 4;       // C-layout row part / kp offset
  const float* base = qkv + (size_t)bt * NN * 768;

  union H4 { f16x4 v; h2 h[2]; };
  union H8 { f16x8 v; h2 h[4]; };

  for (int idx = tid; idx < 272 * 16; idx += 512) {
    int row = idx >> 4, q = idx & 15;
    int sr = row < NN ? row : NN - 1;
    float4 kv = *(const float4*)(base + (size_t)sr * 768 + 256 + h * 64 + q * 4);
    H4 t;
    t.h[0] = __builtin_amdgcn_cvt_pkrtz(kv.x, kv.y);
    t.h[1] = __builtin_amdgcn_cvt_pkrtz(kv.z, kv.w);
    *(f16x4*)&Ks[q >> 3][row][(q & 7) * 4] = t.v;
  }
  for (int idx = tid; idx < 136 * 16; idx += 512) {
    int mp = idx >> 4, dq = (idx & 15) * 4;
    int m0 = 2 * mp, m1 = 2 * mp + 1;
    if (m0 > NN - 1) m0 = NN - 1;
    if (m1 > NN - 1) m1 = NN - 1;
    float4 a = *(const float4*)(base + (size_t)m0 * 768 + 512 + h * 64 + dq);
    float4 b = *(const float4*)(base + (size_t)m1 * 768 + 512 + h * 64 + dq);
    Vt[dq + 0][mp] = __builtin_amdgcn_cvt_pkrtz(a.x, b.x);
    Vt[dq + 1][mp] = __builtin_amdgcn_cvt_pkrtz(a.y, b.y);
    Vt[dq + 2][mp] = __builtin_amdgcn_cvt_pkrtz(a.z, b.z);
    Vt[dq + 3][mp] = __builtin_amdgcn_cvt_pkrtz(a.w, b.w);
  }
  {
    h2 z; z.x = (__fp16)0.f; z.y = (__fp16)0.f;
    for (int idx = tid; idx < 64 * 12; idx += 512)
      Vt[idx / 12][136 + idx % 12] = z;
  }
  {
    h2 z; z.x = (__fp16)0.f; z.y = (__fp16)0.f;
    #pragma unroll
    for (int t = 0; t < 3; ++t) Pb[wave][fr][136 + (kb >> 2) * 3 + t] = z;
  }
  __syncthreads();

  const float scq = 0.17677669529663687f;  // 1/sqrt(32)

  for (int task = wave; task < 34; task += 8) {
    const int chunk = task >> 1;
    const int half  = task & 1;

    int qsrc = chunk * 16 + fr; if (qsrc > NN - 1) qsrc = NN - 1;
    const float* qr = base + (size_t)qsrc * 768 + h * 64 + half * 32 + kb * 2;
    f16x8 qf;
    {
      float4 a = *(const float4*)(qr);
      float4 b = *(const float4*)(qr + 4);
      H8 t;
      t.h[0] = __builtin_amdgcn_cvt_pkrtz(a.x, a.y);
      t.h[1] = __builtin_amdgcn_cvt_pkrtz(a.z, a.w);
      t.h[2] = __builtin_amdgcn_cvt_pkrtz(b.x, b.y);
      t.h[3] = __builtin_amdgcn_cvt_pkrtz(b.z, b.w);
      qf = t.v;
    }

    f32x4 s[17];
    #pragma unroll
    for (int mt = 0; mt < 17; ++mt) {
      f16x8 af = *(const f16x8*)&Ks[half][mt * 16 + fr][kb * 2];
      f32x4 z4 = {0.f, 0.f, 0.f, 0.f};
      s[mt] = __builtin_amdgcn_mfma_f32_16x16x32_f16(af, qf, z4, 0, 0, 0);
    }

    float mx = -1e30f;
    #pragma unroll
    for (int mt = 0; mt < 17; ++mt)
      #pragma unroll
      for (int r = 0; r < 4; ++r) {
        float v = s[mt][r] * scq;
        if (mt * 16 + kb + r >= NN) v = -1e30f;
        s[mt][r] = v;
        mx = fmaxf(mx, v);
      }
    mx = fmaxf(mx, __shfl_xor(mx, 16, 64));
    mx = fmaxf(mx, __shfl_xor(mx, 32, 64));
    float sum = 0.f;
    #pragma unroll
    for (int mt = 0; mt < 17; ++mt)
      #pragma unroll
      for (int r = 0; r < 4; ++r) {
        float p = __expf(s[mt][r] - mx);
        s[mt][r] = p;
        sum += p;
      }
    sum += __shfl_xor(sum, 16, 64);
    sum += __shfl_xor(sum, 32, 64);
    float inv = 1.f / sum;

    #pragma unroll
    for (int mt = 0; mt < 17; ++mt) {
      h2 lo = __builtin_amdgcn_cvt_pkrtz(s[mt][0] * inv, s[mt][1] * inv);
      h2 hi = __builtin_amdgcn_cvt_pkrtz(s[mt][2] * inv, s[mt][3] * inv);
      int kp = 8 * mt + (kb >> 1);
      Pb[wave][fr][kp]     = lo;
      Pb[wave][fr][kp + 1] = hi;
    }

    f32x4 o[4];
    #pragma unroll
    for (int nt = 0; nt < 4; ++nt) {
      o[nt].x = 0.f; o[nt].y = 0.f; o[nt].z = 0.f; o[nt].w = 0.f;
    }
    #pragma unroll
    for (int s9 = 0; s9 < 9; ++s9) {
      f16x8 pa = *(const f16x8*)&Pb[wave][fr][16 * s9 + kb];
      #pragma unroll
      for (int nt = 0; nt < 4; ++nt) {
        f16x8 vb = *(const f16x8*)&Vt[nt * 16 + fr][16 * s9 + kb];
        o[nt] = __builtin_amdgcn_mfma_f32_16x16x32_f16(pa, vb, o[nt], 0, 0, 0);
      }
    }

    float* ab = aout + (size_t)half * (50496ull * 256ull);
    #pragma unroll
    for (int r = 0; r < 4; ++r) {
      int qrow = chunk * 16 + kb + r;
      if (qrow < NN) {
        float* op = ab + ((size_t)(bt * NN + qrow) * 4 + h) * 64;
        #pragma unroll
        for (int nt = 0; nt < 4; ++nt) op[nt * 16 + fr] = o[nt][r];
      }
    }
  }
}

// ---------------------------------------------------------------------------
__global__ __launch_bounds__(256) void diff_ln(
    const float* __restrict__ a1, const float* __restrict__ a2,
    const float* __restrict__ lamp,
    const float* __restrict__ g, const float* __restrict__ b,
    _Float16* __restrict__ st)
{
  const int btn = blockIdx.x;
  const int lane = threadIdx.x & 63;
  const int h = threadIdx.x >> 6;
  const float lam = lamp[0];
  size_t off = ((size_t)btn * 4 + h) * 64 + lane;
  float y = a1[off] - lam * a2[off];
  float mean = wred_sum(y) * (1.f / 64.f);
  float t = y - mean;
  float var = wred_sum(t * t) * (1.f / 64.f);
  float r = rsqrtf(var + 1e-5f);
  st[(size_t)btn * 640 + h * 64 + lane] = (_Float16)((t * r * g[lane] + b[lane]) * 0.8f);
}

// ---------------------------------------------------------------------------
// Temporal self-attention (verified R4-R6) — f16 store.
// ---------------------------------------------------------------------------
__global__ __launch_bounds__(256) void temporal_attn(
    const float* __restrict__ qkvt, _Float16* __restrict__ st)
{
  __shared__ float qs[48][68];
  __shared__ float kt[48][68];
  __shared__ float vt[48][68];
  __shared__ float Ss[48][28];
  const int b = blockIdx.x / NN;
  const int n = blockIdx.x % NN;
  const int tid = threadIdx.x;
  const int lane = tid & 63;
  const int wave = tid >> 6;

  for (int idx = tid; idx < 48 * 16; idx += 256) {
    int row = idx >> 4, dq = (idx & 15) * 4;
    int h = row / 24, t = row - h * 24;
    const float* g = qkvt + ((size_t)(b * TT + t) * NN + n) * 640 + h * 64 + dq;
    *(float4*)&qs[row][dq] = *(const float4*)(g);
    *(float4*)&kt[row][dq] = *(const float4*)(g + 128);
    *(float4*)&vt[row][dq] = *(const float4*)(g + 256);
  }
  __syncthreads();

  for (int idx = tid; idx < 48 * 24; idx += 256) {
    int row = idx / 24, s = idx - row * 24;
    int krow = (row >= 24 ? 24 : 0) + s;
    float a0 = 0.f, a1 = 0.f, a2 = 0.f, a3 = 0.f;
    #pragma unroll
    for (int dq = 0; dq < 64; dq += 4) {
      float4 q = *(const float4*)&qs[row][dq];
      float4 k = *(const float4*)&kt[krow][dq];
      a0 = fmaf(q.x, k.x, a0);
      a1 = fmaf(q.y, k.y, a1);
      a2 = fmaf(q.z, k.z, a2);
      a3 = fmaf(q.w, k.w, a3);
    }
    Ss[row][s] = ((a0 + a1) + (a2 + a3)) * 0.125f;
  }
  __syncthreads();

  for (int r = wave; r < 48; r += 4) {
    float v = lane < 24 ? Ss[r][lane] : -1e30f;
    float mx = wred_max(v);
    float p = lane < 24 ? __expf(v - mx) : 0.f;
    float inv = 1.f / wred_sum(p);
    if (lane < 24) Ss[r][lane] = p * inv;
  }
  __syncthreads();

  for (int idx = tid; idx < 48 * 16; idx += 256) {
    int row = idx >> 4, dq = (idx & 15) * 4;
    int h = row / 24, t = row - h * 24;
    int bs = h * 24;
    float ax = 0.f, ay = 0.f, az = 0.f, aw = 0.f;
    #pragma unroll
    for (int s = 0; s < 24; ++s) {
      float p = Ss[row][s];
      float4 v = *(const float4*)&vt[bs + s][dq];
      ax = fmaf(p, v.x, ax);
      ay = fmaf(p, v.y, ay);
      az = fmaf(p, v.z, az);
      aw = fmaf(p, v.w, aw);
    }
    union { h2 h[2]; f16x4 v; } o2;
    o2.h[0] = __builtin_amdgcn_cvt_pkrtz(ax, ay);
    o2.h[1] = __builtin_amdgcn_cvt_pkrtz(az, aw);
    *(f16x4*)(st + ((size_t)(b * TT + t) * NN + n) * 640 + 384 + h * 64 + dq) = o2.v;
  }
}

// ---------------------------------------------------------------------------
// Temporal-global attention (verified R4-R6) — f16 store.
// ---------------------------------------------------------------------------
__global__ __launch_bounds__(256) void tglobal_attn(
    const float* __restrict__ qkvt, const float* __restrict__ q_agg,
    const float* __restrict__ tmp_map, _Float16* __restrict__ st)
{
  __shared__ float qg[24][68];
  __shared__ float kg[48][68];
  __shared__ float vg[48][68];
  __shared__ float Sg[24][28];
  __shared__ float tgx[12][128];
  const int b = blockIdx.x / NN;
  const int n = blockIdx.x % NN;
  const int tid = threadIdx.x;
  const int lane = tid & 63;
  const int wave = tid >> 6;

  for (int idx = tid; idx < 48 * 16; idx += 256) {
    int row = idx >> 4, dq = (idx & 15) * 4;
    int h = row / 24, t = row - h * 24;
    const float* g = qkvt + ((size_t)(b * TT + t) * NN + n) * 640 + 384 + h * 64 + dq;
    *(float4*)&kg[row][dq] = *(const float4*)(g);
    *(float4*)&vg[row][dq] = *(const float4*)(g + 128);
  }
  for (int idx = tid; idx < 24 * 16; idx += 256) {
    int row = idx >> 4, dq = (idx & 15) * 4;   // row = h*12+s
    int h = row / 12, s = row - h * 12;
    *(float4*)&qg[row][dq] =
        *(const float4*)(q_agg + ((size_t)n * 12 + s) * 128 + h * 64 + dq);
  }
  __syncthreads();

  for (int idx = tid; idx < 24 * 24; idx += 256) {
    int row = idx / 24, t = idx - row * 24;
    int krow = (row >= 12 ? 24 : 0) + t;
    float a0 = 0.f, a1 = 0.f, a2 = 0.f, a3 = 0.f;
    #pragma unroll
    for (int dq = 0; dq < 64; dq += 4) {
      float4 q = *(const float4*)&qg[row][dq];
      float4 k = *(const float4*)&kg[krow][dq];
      a0 = fmaf(q.x, k.x, a0);
      a1 = fmaf(q.y, k.y, a1);
      a2 = fmaf(q.z, k.z, a2);
      a3 = fmaf(q.w, k.w, a3);
    }
    Sg[row][t] = ((a0 + a1) + (a2 + a3)) * 0.125f;
  }
  __syncthreads();

  for (int r = wave; r < 24; r += 4) {
    float v = lane < 24 ? Sg[r][lane] : -1e30f;
    float mx = wred_max(v);
    float p = lane < 24 ? __expf(v - mx) : 0.f;
    float inv = 1.f / wred_sum(p);
    if (lane < 24) Sg[r][lane] = p * inv;
  }
  __syncthreads();

  for (int idx = tid; idx < 24 * 16; idx += 256) {
    int row = idx >> 4, dq = (idx & 15) * 4;   // row = h*12+s
    int h = row / 12, s = row - h * 12;
    int bt_ = h * 24;
    float ax = 0.f, ay = 0.f, az = 0.f, aw = 0.f;
    #pragma unroll
    for (int t = 0; t < 24; ++t) {
      float p = Sg[row][t];
      float4 v = *(const float4*)&vg[bt_ + t][dq];
      ax = fmaf(p, v.x, ax);
      ay = fmaf(p, v.y, ay);
      az = fmaf(p, v.z, az);
      aw = fmaf(p, v.w, aw);
    }
    float4 o = {ax, ay, az, aw};
    *(float4*)&tgx[s][h * 64 + dq] = o;
  }
  __syncthreads();

  for (int idx = tid; idx < 24 * 32; idx += 256) {
    int t = idx >> 5, cq = (idx & 31) * 4;
    const float* tm = tmp_map + ((size_t)(b * NN + n) * TT + t) * 12;
    float ax = 0.f, ay = 0.f, az = 0.f, aw = 0.f;
    #pragma unroll
    for (int s = 0; s < 12; ++s) {
      float m = tm[s];
      float4 v = *(const float4*)&tgx[s][cq];
      ax = fmaf(m, v.x, ax);
      ay = fmaf(m, v.y, ay);
      az = fmaf(m, v.z, az);
      aw = fmaf(m, v.w, aw);
    }
    union { h2 h[2]; f16x4 v; } o2;
    o2.h[0] = __builtin_amdgcn_cvt_pkrtz(ax, ay);
    o2.h[1] = __builtin_amdgcn_cvt_pkrtz(az, aw);
    *(f16x4*)(st + ((size_t)(b * TT + t) * NN + n) * 640 + 512 + cq) = o2.v;
  }
}

// ---------------------------------------------------------------------------
__global__ __launch_bounds__(256) void agg_attn(
    const float* __restrict__ qkva, float* __restrict__ sx, int Ni)
{
  __shared__ float kT[64 * 64];
  __shared__ float vl[64 * 64];
  const int h = blockIdx.x & 1;
  const int bt = blockIdx.x >> 1;
  const int tid = threadIdx.x;
  const int lane = tid & 63;
  const int wave = tid >> 6;
  for (int idx = tid; idx < Ni * 64; idx += 256) {
    int m = idx >> 6, d = idx & 63;
    size_t row = (size_t)(bt * Ni + m) * 384;
    kT[d * Ni + m] = qkva[row + 128 + h * 64 + d];
    vl[m * 64 + d] = qkva[row + 256 + h * 64 + d];
  }
  __syncthreads();
  int mc = lane < Ni ? lane : Ni - 1;
  bool valid = lane < Ni;
  for (int n = wave; n < Ni; n += 4) {
    float qv = qkva[(size_t)(bt * Ni + n) * 384 + h * 64 + lane];
    float sc_ = 0.f;
    #pragma unroll
    for (int d = 0; d < 64; ++d) {
      float qd = __shfl(qv, d, 64);
      sc_ = fmaf(qd, kT[d * Ni + mc], sc_);
    }
    sc_ *= 0.125f;
    float mx = wred_max(valid ? sc_ : -1e30f);
    float p = valid ? __expf(sc_ - mx) : 0.f;
    float inv = 1.f / wred_sum(p);
    float o = 0.f;
    for (int m = 0; m < Ni; ++m) {
      float pm = __shfl(p, m, 64);
      o = fmaf(pm, vl[m * 64 + lane], o);
    }
    sx[(size_t)(bt * Ni + n) * 128 + h * 64 + lane] = o * inv;
  }
}

// ---------------------------------------------------------------------------
// mmap v3: LDS-staged M + s, 8n x 4c register tile, 32 independent fma chains.
// (v2 was latency-bound: 96 scalar GLOBAL M-loads feeding a 96-deep dependent
// fmaf chain per output at 18% occupancy -> 115us for 1.2 GFLOP.)
// LDS: sS 48KB + Mc 33KB = 81.2KB (1 block/CU; fine, 576 blocks ~2.25 rounds).
// ---------------------------------------------------------------------------
__global__ __launch_bounds__(256) void mmap_kernel(
    const float* __restrict__ sx0, const float* __restrict__ sx1,
    const float* __restrict__ M0, const float* __restrict__ M1,
    _Float16* __restrict__ sg)
{
  __shared__ float sS[96][128];   // rows 0..31 = s0, 32..95 = s1
  __shared__ float Mc[96][88];    // M columns for this n-chunk
  const int bt = blockIdx.x;
  const int chunk = blockIdx.y;
  const int tid = threadIdx.x;
  const int nbase = chunk * 88;

  // stage s (coalesced float4)
  for (int idx = tid; idx < 96 * 32; idx += 256) {
    int m = idx >> 5, c4 = (idx & 31) * 4;
    float4 v = (m < 32)
        ? *(const float4*)(sx0 + ((size_t)(bt * 32 + m) * 128 + c4))
        : *(const float4*)(sx1 + ((size_t)(bt * 64 + (m - 32)) * 128 + c4));
    *(float4*)&sS[m][c4] = v;
  }
  // stage M chunk (coalesced scalars; rows of M are contiguous in n)
  for (int idx = tid; idx < 96 * 88; idx += 256) {
    int m = idx / 88, nl = idx - m * 88;
    int n = nbase + nl; if (n > NN - 1) n = NN - 1;
    Mc[m][nl] = (m < 32) ? M0[m * NN + n] : M1[(m - 32) * NN + n];
  }
  __syncthreads();

  // compute: task = (ngroup of 8, c4 of 4) -> 11*32 = 352 tasks
  for (int idx = tid; idx < 352; idx += 256) {
    const int n0 = (idx >> 5) * 8;
    const int c4 = (idx & 31) * 4;
    f32x4 acc[8];
    #pragma unroll
    for (int j = 0; j < 8; ++j) {
      acc[j].x = 0.f; acc[j].y = 0.f; acc[j].z = 0.f; acc[j].w = 0.f;
    }
    #pragma unroll 4
    for (int m = 0; m < 96; ++m) {
      float4 sv = *(const float4*)&sS[m][c4];
      float mj[8];
      *(float4*)&mj[0] = *(const float4*)&Mc[m][n0];
      *(float4*)&mj[4] = *(const float4*)&Mc[m][n0 + 4];
      #pragma unroll
      for (int j = 0; j < 8; ++j) {
        acc[j].x = fmaf(mj[j], sv.x, acc[j].x);
        acc[j].y = fmaf(mj[j], sv.y, acc[j].y);
        acc[j].z = fmaf(mj[j], sv.z, acc[j].z);
        acc[j].w = fmaf(mj[j], sv.w, acc[j].w);
      }
    }
    #pragma unroll
    for (int j = 0; j < 8; ++j) {
      int n = nbase + n0 + j;
      if (n < NN) {
        union { h2 h[2]; f16x4 v; } o;
        o.h[0] = __builtin_amdgcn_cvt_pkrtz(acc[j].x, acc[j].y);
        o.h[1] = __builtin_amdgcn_cvt_pkrtz(acc[j].z, acc[j].w);
        *(f16x4*)(sg + ((size_t)bt * NN + n) * 128 + c4) = o.v;
      }
    }
  }
}

// ---------------------------------------------------------------------------
extern "C" void kernel_launch(void* const* d_in, const int* in_sizes, int n_in,
                              void* d_out, int out_size, void* d_ws, size_t ws_size,
                              hipStream_t stream)
{
  const float* x       = (const float*)d_in[0];
  const float* agg_x0  = (const float*)d_in[1];
  const float* agg_x1  = (const float*)d_in[2];
  const float* tmp_map = (const float*)d_in[3];
  const float* Wq_s = (const float*)d_in[4];
  const float* Wk_s = (const float*)d_in[5];
  const float* Wv_s = (const float*)d_in[6];
  const float* lq1 = (const float*)d_in[7];
  const float* lk1 = (const float*)d_in[8];
  const float* lq2 = (const float*)d_in[9];
  const float* lk2 = (const float*)d_in[10];
  const float* ln_g = (const float*)d_in[11];
  const float* ln_b = (const float*)d_in[12];
  const float* Wq_a0 = (const float*)d_in[13];
  const float* Wk_a0 = (const float*)d_in[14];
  const float* Wv_a0 = (const float*)d_in[15];
  const float* Wq_a1 = (const float*)d_in[16];
  const float* Wk_a1 = (const float*)d_in[17];
  const float* Wv_a1 = (const float*)d_in[18];
  const float* M0   = (const float*)d_in[19];
  const float* M1   = (const float*)d_in[20];
  const float* Wagg = (const float*)d_in[21];
  const float* bagg = (const float*)d_in[22];
  const float* Wq_t = (const float*)d_in[23];
  const float* Wk_t = (const float*)d_in[24];
  const float* Wv_t = (const float*)d_in[25];
  const float* q_agg = (const float*)d_in[26];
  const float* Wk_tg = (const float*)d_in[27];
  const float* Wv_tg = (const float*)d_in[28];
  const float* Wout  = (const float*)d_in[29];
  const float* bout  = (const float*)d_in[30];
  float* ws  = (float*)d_ws;
  float* out = (float*)d_out;

  const size_t o_lam  = 1114112;
  const size_t o_A    = 1114128;
  const size_t o_qkvt = o_A + 38780928;
  const size_t o_B    = o_qkvt + 32317440;

  float* lamp  = ws + o_lam;
  float* qkv_s = ws + o_A;                       // fp32, dead after diff_attn
  _Float16* st_h = (_Float16*)(ws + o_A);        // reuses o_A after diff_ln
  float* qkvt  = ws + o_qkvt;
  _Float16* x_h = (_Float16*)(ws + o_B);         // dead after qkvt GEMM
  float* a1    = ws + o_B;                       // written by diff_attn (after x_h dead)
  float* qkva0 = ws + o_B;                       // after diff_ln
  float* qkva1 = qkva0 + 2359296;
  float* sx0   = qkva0 + 7077888;
  float* sx1   = qkva0 + 7864320;
  _Float16* sg_h = (_Float16*)(qkva0 + 9437184);
  _Float16* Wh  = (_Float16*)ws;                 // f16 weights in old W_all region

  hipLaunchKernelGGL(lam_kernel, dim3(1), dim3(64), 0, stream, lq1, lk1, lq2, lk2, lamp);

  // ---- one-shot fp32->f16 conversion: x + all h16-GEMM weights ----
  CvtSegs cs;
  cs.src[0] = x;      cs.dst[0] = x_h;          cs.cnt8[0] = 25853952 / 8;
  cs.src[1] = Wq_s;   cs.dst[1] = Wh + 0;       cs.cnt8[1] = 131072 / 8;
  cs.src[2] = Wk_s;   cs.dst[2] = Wh + 131072;  cs.cnt8[2] = 131072 / 8;
  cs.src[3] = Wv_s;   cs.dst[3] = Wh + 262144;  cs.cnt8[3] = 131072 / 8;
  cs.src[4] = Wq_t;   cs.dst[4] = Wh + 393216;  cs.cnt8[4] = 65536 / 8;
  cs.src[5] = Wk_t;   cs.dst[5] = Wh + 458752;  cs.cnt8[5] = 65536 / 8;
  cs.src[6] = Wv_t;   cs.dst[6] = Wh + 524288;  cs.cnt8[6] = 65536 / 8;
  cs.src[7] = Wk_tg;  cs.dst[7] = Wh + 589824;  cs.cnt8[7] = 65536 / 8;
  cs.src[8] = Wv_tg;  cs.dst[8] = Wh + 655360;  cs.cnt8[8] = 65536 / 8;
  cs.src[9] = Wagg;   cs.dst[9] = Wh + 720896;  cs.cnt8[9] = 16384 / 8;
  cs.src[10] = Wout;  cs.dst[10] = Wh + 737280; cs.cnt8[10] = 327680 / 8;
  hipLaunchKernelGGL(cvt_f16, dim3(2048), dim3(256), 0, stream, cs, 11, 3364864);

  const int Mx = 50496;

  // qkv projection: N=768 (6 tiles)
  WSegsH wqkv; wqkv.p[0] = Wh; wqkv.p[1] = Wh + 65536;
  wqkv.p[2] = Wh + 131072; wqkv.p[3] = Wh + 196608;
  wqkv.p[4] = Wh + 262144; wqkv.p[5] = Wh + 327680;
  hipLaunchKernelGGL((gemm_h16<0>), dim3(395 * 6), dim3(256), 0, stream,
                     x_h, wqkv, (const float*)nullptr, (void*)qkv_s, Mx, 6, 512, 768);

  // temporal qkv: N=640 (5 tiles) — before diff_attn so x_h dies before a1
  WSegsH wt; wt.p[0] = Wh + 393216; wt.p[1] = Wh + 458752; wt.p[2] = Wh + 524288;
  wt.p[3] = Wh + 589824; wt.p[4] = Wh + 655360; wt.p[5] = Wh + 393216;
  hipLaunchKernelGGL((gemm_h16<0>), dim3(395 * 5), dim3(256), 0, stream,
                     x_h, wt, (const float*)nullptr, (void*)qkvt, Mx, 5, 512, 640);

  hipLaunchKernelGGL(diff_attn, dim3(768), dim3(512), 0, stream, qkv_s, a1);
  hipLaunchKernelGGL(diff_ln, dim3(Mx), dim3(256), 0, stream,
                     a1, a1 + 12926976, lamp, ln_g, ln_b, st_h);
  hipLaunchKernelGGL(temporal_attn, dim3(8 * NN), dim3(256), 0, stream, qkvt, st_h);
  hipLaunchKernelGGL(tglobal_attn, dim3(8 * NN), dim3(256), 0, stream, qkvt, q_agg, tmp_map, st_h);

  // agg projections (small): legacy fp32 GEMM
  WSegs wa0; wa0.p[0] = Wq_a0; wa0.p[1] = Wk_a0; wa0.p[2] = Wv_a0;
  wa0.p[3] = wa0.p[4] = wa0.p[5] = Wq_a0;
  hipLaunchKernelGGL(gemm_nt_mfma, dim3(48 * 3), dim3(256), 0, stream,
                     agg_x0, wa0, (const float*)nullptr, qkva0, 6144, 3, 512, 384);
  WSegs wa1; wa1.p[0] = Wq_a1; wa1.p[1] = Wk_a1; wa1.p[2] = Wv_a1;
  wa1.p[3] = wa1.p[4] = wa1.p[5] = Wq_a1;
  hipLaunchKernelGGL(gemm_nt_mfma, dim3(96 * 3), dim3(256), 0, stream,
                     agg_x1, wa1, (const float*)nullptr, qkva1, 12288, 3, 512, 384);

  hipLaunchKernelGGL(agg_attn, dim3(384), dim3(256), 0, stream, qkva0, sx0, 32);
  hipLaunchKernelGGL(agg_attn, dim3(384), dim3(256), 0, stream, qkva1, sx1, 64);
  hipLaunchKernelGGL(mmap_kernel, dim3(192, 3), dim3(256), 0, stream, sx0, sx1, M0, M1, sg_h);

  // sg @ Wagg.T + bagg -> st_h cols 256..383 (f16 out)
  WSegsH wag; wag.p[0] = Wh + 720896;
  wag.p[1] = wag.p[2] = wag.p[3] = wag.p[4] = wag.p[5] = wag.p[0];
  hipLaunchKernelGGL((gemm_h16<1>), dim3(395 * 1), dim3(256), 0, stream,
                     sg_h, wag, bagg, (void*)(st_h + 256), Mx, 1, 128, 640);

  // out projection: N=512 (4 tiles of Wout)
  WSegsH wo; wo.p[0] = Wh + 737280; wo.p[1] = Wh + 737280 + 81920;
  wo.p[2] = Wh + 737280 + 163840; wo.p[3] = Wh + 737280 + 245760;
  wo.p[4] = wo.p[5] = wo.p[0];
  hipLaunchKernelGGL((gemm_h16<0>), dim3(395 * 4), dim3(256), 0, stream,
                     st_h, wo, bout, (void*)out, Mx, 4, 640, 512);
}

// Round 9
// 839.333 us; speedup vs baseline: 3.7253x; 1.0653x over previous
//
#include <hip/hip_runtime.h>

#define NN 263
#define TT 24

typedef __fp16 h2 __attribute__((ext_vector_type(2)));
typedef _Float16 f16x4 __attribute__((ext_vector_type(4)));
typedef _Float16 f16x8 __attribute__((ext_vector_type(8)));
typedef float f32x4 __attribute__((ext_vector_type(4)));

struct WSegs  { const float* p[6]; };      // fp32 weight tiles (legacy gemm)
struct WSegsH { const _Float16* p[6]; };   // f16 weight tiles
struct CvtSegs { const float* src[11]; _Float16* dst[11]; int cnt8[11]; };

static __device__ __forceinline__ float wred_sum(float v) {
  #pragma unroll
  for (int off = 32; off >= 1; off >>= 1) v += __shfl_xor(v, off, 64);
  return v;
}
static __device__ __forceinline__ float wred_max(float v) {
  #pragma unroll
  for (int off = 32; off >= 1; off >>= 1) v = fmaxf(v, __shfl_xor(v, off, 64));
  return v;
}

// ---------------------------------------------------------------------------
// Batched fp32 -> f16 convert (x + all weights), 8 elems/thread-iter.
// ---------------------------------------------------------------------------
__global__ __launch_bounds__(256) void cvt_f16(CvtSegs cs, int nseg, int total8)
{
  const int stride = gridDim.x * 256;
  for (int i = blockIdx.x * 256 + threadIdx.x; i < total8; i += stride) {
    int r = i, s = 0;
    while (s < nseg - 1 && r >= cs.cnt8[s]) { r -= cs.cnt8[s]; ++s; }
    const float* sp = cs.src[s] + (size_t)r * 8;
    float4 a = *(const float4*)sp;
    float4 b = *(const float4*)(sp + 4);
    union { h2 h[4]; f16x8 v; } u;
    u.h[0] = __builtin_amdgcn_cvt_pkrtz(a.x, a.y);
    u.h[1] = __builtin_amdgcn_cvt_pkrtz(a.z, a.w);
    u.h[2] = __builtin_amdgcn_cvt_pkrtz(b.x, b.y);
    u.h[3] = __builtin_amdgcn_cvt_pkrtz(b.z, b.w);
    *(f16x8*)(cs.dst[s] + (size_t)r * 8) = u.v;
  }
}

// ---------------------------------------------------------------------------
// f16-in MFMA NT GEMM (verified R6/R7): dbuf LDS, one barrier/K-step.
// OUT_HALF=1 writes f16.
// ---------------------------------------------------------------------------
template<int OUT_HALF>
__global__ __launch_bounds__(256) void gemm_h16(
    const _Float16* __restrict__ A, WSegsH wsg, const float* __restrict__ bias,
    void* __restrict__ Cp, int M, int NT, int K, int ldc)
{
  __shared__ _Float16 As[2][128][40];
  __shared__ _Float16 Bs[2][128][40];
  const int tid  = threadIdx.x;
  const int lane = tid & 63;
  const int wave = tid >> 6;
  const int wr = wave >> 1, wc = wave & 1;

  const int nwg = gridDim.x;
  const int q8 = nwg >> 3, r8 = nwg & 7;
  const int xcd = blockIdx.x & 7, pos = blockIdx.x >> 3;
  const int logical = (xcd < r8 ? xcd * (q8 + 1) : r8 * (q8 + 1) + (xcd - r8) * q8) + pos;
  const int bm = (logical / NT) * 128;
  const int bn = logical - (logical / NT) * NT;
  const _Float16* __restrict__ W = wsg.p[bn];

  const int srow = tid >> 2;
  const int sch  = (tid & 3) * 8;
  const _Float16* aptr[2];
  const _Float16* bptr[2];
  #pragma unroll
  for (int l = 0; l < 2; ++l) {
    int gm = bm + srow + 64 * l; if (gm > M - 1) gm = M - 1;
    aptr[l] = A + (size_t)gm * K + sch;
    bptr[l] = W + (size_t)(srow + 64 * l) * K + sch;
  }

  f32x4 acc[4][4];
  #pragma unroll
  for (int i = 0; i < 4; ++i)
    #pragma unroll
    for (int j = 0; j < 4; ++j) {
      acc[i][j].x = 0.f; acc[i][j].y = 0.f; acc[i][j].z = 0.f; acc[i][j].w = 0.f;
    }

  const int fr = lane & 15;
  const int fk = (lane >> 4) * 8;

  f16x8 av[2], bv[2];
  av[0] = *(const f16x8*)aptr[0]; av[1] = *(const f16x8*)aptr[1];
  bv[0] = *(const f16x8*)bptr[0]; bv[1] = *(const f16x8*)bptr[1];

  int cur = 0;
  for (int k0 = 0; k0 < K; k0 += 32, cur ^= 1) {
    *(f16x8*)&As[cur][srow     ][sch] = av[0];
    *(f16x8*)&As[cur][srow + 64][sch] = av[1];
    *(f16x8*)&Bs[cur][srow     ][sch] = bv[0];
    *(f16x8*)&Bs[cur][srow + 64][sch] = bv[1];
    if (k0 + 32 < K) {
      av[0] = *(const f16x8*)(aptr[0] + k0 + 32);
      av[1] = *(const f16x8*)(aptr[1] + k0 + 32);
      bv[0] = *(const f16x8*)(bptr[0] + k0 + 32);
      bv[1] = *(const f16x8*)(bptr[1] + k0 + 32);
    }
    __syncthreads();

    f16x8 af[4], bf[4];
    #pragma unroll
    for (int mi = 0; mi < 4; ++mi)
      af[mi] = *(const f16x8*)&As[cur][wr * 64 + mi * 16 + fr][fk];
    #pragma unroll
    for (int ni = 0; ni < 4; ++ni)
      bf[ni] = *(const f16x8*)&Bs[cur][wc * 64 + ni * 16 + fr][fk];
    #pragma unroll
    for (int mi = 0; mi < 4; ++mi)
      #pragma unroll
      for (int ni = 0; ni < 4; ++ni)
        acc[mi][ni] = __builtin_amdgcn_mfma_f32_16x16x32_f16(
            af[mi], bf[ni], acc[mi][ni], 0, 0, 0);
  }

  #pragma unroll
  for (int mi = 0; mi < 4; ++mi) {
    int rb = bm + wr * 64 + mi * 16 + (lane >> 4) * 4;
    #pragma unroll
    for (int r = 0; r < 4; ++r) {
      int gm = rb + r;
      if (gm < M) {
        int gn = bn * 128 + wc * 64 + fr;
        #pragma unroll
        for (int ni = 0; ni < 4; ++ni) {
          float v = acc[mi][ni][r];
          if (bias) v += bias[gn + ni * 16];
          if (OUT_HALF) {
            ((_Float16*)Cp)[(size_t)gm * ldc + gn + ni * 16] = (_Float16)v;
          } else {
            ((float*)Cp)[(size_t)gm * ldc + gn + ni * 16] = v;
          }
        }
      }
    }
  }
}

// ---------------------------------------------------------------------------
// Legacy fp32-in GEMM — small agg projections only.
// ---------------------------------------------------------------------------
__global__ __launch_bounds__(256) void gemm_nt_mfma(
    const float* __restrict__ A, WSegs ws, const float* __restrict__ bias,
    float* __restrict__ C, int M, int NT, int K, int ldc)
{
  __shared__ _Float16 As[128][40];
  __shared__ _Float16 Bs[128][40];
  const int tid  = threadIdx.x;
  const int lane = tid & 63;
  const int wave = tid >> 6;
  const int wr = wave >> 1, wc = wave & 1;

  const int nwg = gridDim.x;
  const int q8 = nwg >> 3, r8 = nwg & 7;
  const int xcd = blockIdx.x & 7, pos = blockIdx.x >> 3;
  const int logical = (xcd < r8 ? xcd * (q8 + 1) : r8 * (q8 + 1) + (xcd - r8) * q8) + pos;
  const int bm = (logical / NT) * 128;
  const int bn = logical - (logical / NT) * NT;
  const float* __restrict__ W = ws.p[bn];

  const int srow = tid >> 3;
  const int skq  = (tid & 7) * 4;
  const float* aptr[4];
  const float* bptr[4];
  #pragma unroll
  for (int l = 0; l < 4; ++l) {
    int gm = bm + srow + 32 * l; if (gm > M - 1) gm = M - 1;
    aptr[l] = A + (size_t)gm * K + skq;
    bptr[l] = W + (size_t)(srow + 32 * l) * K + skq;
  }

  f32x4 acc[4][4];
  #pragma unroll
  for (int i = 0; i < 4; ++i)
    #pragma unroll
    for (int j = 0; j < 4; ++j) {
      acc[i][j].x = 0.f; acc[i][j].y = 0.f; acc[i][j].z = 0.f; acc[i][j].w = 0.f;
    }

  const int fr = lane & 15;
  const int fk = (lane >> 4) * 8;

  float4 av[4], bv[4];
  #pragma unroll
  for (int l = 0; l < 4; ++l) {
    av[l] = *(const float4*)(aptr[l]);
    bv[l] = *(const float4*)(bptr[l]);
  }

  for (int k0 = 0; k0 < K; k0 += 32) {
    #pragma unroll
    for (int l = 0; l < 4; ++l) {
      f16x4 a4, b4;
      a4.x = (_Float16)av[l].x; a4.y = (_Float16)av[l].y;
      a4.z = (_Float16)av[l].z; a4.w = (_Float16)av[l].w;
      b4.x = (_Float16)bv[l].x; b4.y = (_Float16)bv[l].y;
      b4.z = (_Float16)bv[l].z; b4.w = (_Float16)bv[l].w;
      *(f16x4*)&As[srow + 32 * l][skq] = a4;
      *(f16x4*)&Bs[srow + 32 * l][skq] = b4;
    }
    __syncthreads();

    if (k0 + 32 < K) {
      #pragma unroll
      for (int l = 0; l < 4; ++l) {
        av[l] = *(const float4*)(aptr[l] + k0 + 32);
        bv[l] = *(const float4*)(bptr[l] + k0 + 32);
      }
    }

    f16x8 af[4], bf[4];
    #pragma unroll
    for (int mi = 0; mi < 4; ++mi)
      af[mi] = *(const f16x8*)&As[wr * 64 + mi * 16 + fr][fk];
    #pragma unroll
    for (int ni = 0; ni < 4; ++ni)
      bf[ni] = *(const f16x8*)&Bs[wc * 64 + ni * 16 + fr][fk];
    #pragma unroll
    for (int mi = 0; mi < 4; ++mi)
      #pragma unroll
      for (int ni = 0; ni < 4; ++ni)
        acc[mi][ni] = __builtin_amdgcn_mfma_f32_16x16x32_f16(
            af[mi], bf[ni], acc[mi][ni], 0, 0, 0);
    __syncthreads();
  }

  #pragma unroll
  for (int mi = 0; mi < 4; ++mi) {
    int rb = bm + wr * 64 + mi * 16 + (lane >> 4) * 4;
    #pragma unroll
    for (int r = 0; r < 4; ++r) {
      int gm = rb + r;
      if (gm < M) {
        int gn = bn * 128 + wc * 64 + fr;
        float* crow = C + (size_t)gm * ldc + gn;
        #pragma unroll
        for (int ni = 0; ni < 4; ++ni) {
          float v = acc[mi][ni][r];
          if (bias) v += bias[gn + ni * 16];
          crow[ni * 16] = v;
        }
      }
    }
  }
}

// ---------------------------------------------------------------------------
__global__ void lam_kernel(const float* __restrict__ lq1, const float* __restrict__ lk1,
                           const float* __restrict__ lq2, const float* __restrict__ lk2,
                           float* __restrict__ out) {
  int lane = threadIdx.x;
  float v1 = lane < 32 ? lq1[lane] * lk1[lane] : 0.f;
  float v2 = lane < 32 ? lq2[lane] * lk2[lane] : 0.f;
  v1 = wred_sum(v1);
  v2 = wred_sum(v2);
  if (lane == 0) out[0] = expf(v1) - expf(v2) + 0.2f;
}

// ---------------------------------------------------------------------------
// Differential self-attention, MFMA (R7: f16 input -> staging is pure copies,
// zero cvt VALU; V staged per-(d,kp-quad) with one aligned b128 write each —
// kills the 8-way column-strided write conflict; softmax max/sum as 4
// independent chains; Pb written b64; f16 output a1/a2).
// ---------------------------------------------------------------------------
__global__ __launch_bounds__(512, 2) void diff_attn(
    const _Float16* __restrict__ qkv, _Float16* __restrict__ aout)
{
  __shared__ _Float16 Ks[2][272][40];   // [half][k-row][d(32)+pad8]
  __shared__ h2 Vt[64][148];            // Vt[d][kp] = (V[2kp][d], V[2kp+1][d])
  __shared__ h2 Pb[8][16][148];         // per-wave P: [qrow(16)][kp], pad zeroed

  const int h  = blockIdx.x & 3;
  const int bt = blockIdx.x >> 2;
  const int tid = threadIdx.x;
  const int lane = tid & 63;
  const int wave = tid >> 6;
  const int fr = lane & 15;
  const int kb = (lane >> 4) * 4;
  const _Float16* base = qkv + (size_t)bt * NN * 768;

  // ---- K staging: direct f16 16B copies ----
  for (int idx = tid; idx < 272 * 8; idx += 512) {
    int row = idx >> 3, c = idx & 7;
    int sr = row < NN ? row : NN - 1;
    f16x8 kv = *(const f16x8*)(base + (size_t)sr * 768 + 256 + h * 64 + c * 8);
    *(f16x8*)&Ks[c >> 2][row][(c & 3) * 8] = kv;
  }
  // ---- V staging: thread owns (d, 4 consecutive kp) -> one b128 write.
  // Covers kp 0..147 (pad zeros folded in). Global loads coalesced per row. ----
  {
    const ushort* vb = (const ushort*)(base + 512 + h * 64);
    for (int idx = tid; idx < 64 * 37; idx += 512) {
      int d = idx & 63, kp0 = (idx >> 6) * 4;
      union { ushort u[8]; f16x8 v; } w;
      #pragma unroll
      for (int i = 0; i < 4; ++i) {
        int kp = kp0 + i;
        ushort lo = 0, hi = 0;
        if (kp < 136) {
          int m0 = 2 * kp, m1 = 2 * kp + 1;
          if (m0 > NN - 1) m0 = NN - 1;
          if (m1 > NN - 1) m1 = NN - 1;
          lo = vb[(size_t)m0 * 768 + d];
          hi = vb[(size_t)m1 * 768 + d];
        }
        w.u[2 * i] = lo; w.u[2 * i + 1] = hi;
      }
      *(f16x8*)&Vt[d][kp0] = w.v;
    }
  }
  // zero this wave's P pad columns kp=136..147
  {
    h2 z; z.x = (__fp16)0.f; z.y = (__fp16)0.f;
    #pragma unroll
    for (int t = 0; t < 3; ++t) Pb[wave][fr][136 + (kb >> 2) * 3 + t] = z;
  }
  __syncthreads();

  const float scq = 0.17677669529663687f;  // 1/sqrt(32)

  for (int task = wave; task < 34; task += 8) {
    const int chunk = task >> 1;
    const int half  = task & 1;

    int qsrc = chunk * 16 + fr; if (qsrc > NN - 1) qsrc = NN - 1;
    f16x8 qf = *(const f16x8*)(base + (size_t)qsrc * 768 + h * 64 + half * 32 + kb * 2);

    f32x4 s[17];
    #pragma unroll
    for (int mt = 0; mt < 17; ++mt) {
      f16x8 af = *(const f16x8*)&Ks[half][mt * 16 + fr][kb * 2];
      f32x4 z4 = {0.f, 0.f, 0.f, 0.f};
      s[mt] = __builtin_amdgcn_mfma_f32_16x16x32_f16(af, qf, z4, 0, 0, 0);
    }

    // softmax: 4 independent max/sum chains (depth 17), then 2 shfl each
    float mx4[4] = {-1e30f, -1e30f, -1e30f, -1e30f};
    #pragma unroll
    for (int mt = 0; mt < 17; ++mt)
      #pragma unroll
      for (int r = 0; r < 4; ++r) {
        float v = s[mt][r] * scq;
        if (mt * 16 + kb + r >= NN) v = -1e30f;
        s[mt][r] = v;
        mx4[r] = fmaxf(mx4[r], v);
      }
    float mx = fmaxf(fmaxf(mx4[0], mx4[1]), fmaxf(mx4[2], mx4[3]));
    mx = fmaxf(mx, __shfl_xor(mx, 16, 64));
    mx = fmaxf(mx, __shfl_xor(mx, 32, 64));
    float sm4[4] = {0.f, 0.f, 0.f, 0.f};
    #pragma unroll
    for (int mt = 0; mt < 17; ++mt)
      #pragma unroll
      for (int r = 0; r < 4; ++r) {
        float p = __expf(s[mt][r] - mx);
        s[mt][r] = p;
        sm4[r] += p;
      }
    float sum = (sm4[0] + sm4[1]) + (sm4[2] + sm4[3]);
    sum += __shfl_xor(sum, 16, 64);
    sum += __shfl_xor(sum, 32, 64);
    float inv = 1.f / sum;

    // write P as one b64 per mt: kp = 8*mt + (kb>>1) (even -> 8B aligned)
    #pragma unroll
    for (int mt = 0; mt < 17; ++mt) {
      union { h2 h[2]; f16x4 v; } pw;
      pw.h[0] = __builtin_amdgcn_cvt_pkrtz(s[mt][0] * inv, s[mt][1] * inv);
      pw.h[1] = __builtin_amdgcn_cvt_pkrtz(s[mt][2] * inv, s[mt][3] * inv);
      *(f16x4*)&Pb[wave][fr][8 * mt + (kb >> 1)] = pw.v;
    }

    // PV: 9 K-steps of 32 (k padded to 288 with zero P / zero V)
    f32x4 o[4];
    #pragma unroll
    for (int nt = 0; nt < 4; ++nt) {
      o[nt].x = 0.f; o[nt].y = 0.f; o[nt].z = 0.f; o[nt].w = 0.f;
    }
    #pragma unroll
    for (int s9 = 0; s9 < 9; ++s9) {
      f16x8 pa = *(const f16x8*)&Pb[wave][fr][16 * s9 + kb];
      #pragma unroll
      for (int nt = 0; nt < 4; ++nt) {
        f16x8 vb2 = *(const f16x8*)&Vt[nt * 16 + fr][16 * s9 + kb];
        o[nt] = __builtin_amdgcn_mfma_f32_16x16x32_f16(pa, vb2, o[nt], 0, 0, 0);
      }
    }

    _Float16* ab = aout + (size_t)half * (50496ull * 256ull);
    #pragma unroll
    for (int r = 0; r < 4; ++r) {
      int qrow = chunk * 16 + kb + r;
      if (qrow < NN) {
        _Float16* op = ab + ((size_t)(bt * NN + qrow) * 4 + h) * 64;
        #pragma unroll
        for (int nt = 0; nt < 4; ++nt) op[nt * 16 + fr] = (_Float16)o[nt][r];
      }
    }
  }
}

// ---------------------------------------------------------------------------
// diff-LN: f16 in (a1/a2), f16 out (st_h).
// ---------------------------------------------------------------------------
__global__ __launch_bounds__(256) void diff_ln(
    const _Float16* __restrict__ a1, const _Float16* __restrict__ a2,
    const float* __restrict__ lamp,
    const float* __restrict__ g, const float* __restrict__ b,
    _Float16* __restrict__ st)
{
  const int btn = blockIdx.x;
  const int lane = threadIdx.x & 63;
  const int h = threadIdx.x >> 6;
  const float lam = lamp[0];
  size_t off = ((size_t)btn * 4 + h) * 64 + lane;
  float y = (float)a1[off] - lam * (float)a2[off];
  float mean = wred_sum(y) * (1.f / 64.f);
  float t = y - mean;
  float var = wred_sum(t * t) * (1.f / 64.f);
  float r = rsqrtf(var + 1e-5f);
  st[(size_t)btn * 640 + h * 64 + lane] = (_Float16)((t * r * g[lane] + b[lane]) * 0.8f);
}

// ---------------------------------------------------------------------------
// Temporal self-attention (R7: f16 qkvt input; compute fp32 in LDS as before).
// ---------------------------------------------------------------------------
__global__ __launch_bounds__(256) void temporal_attn(
    const _Float16* __restrict__ qkvt, _Float16* __restrict__ st)
{
  __shared__ float qs[48][68];
  __shared__ float kt[48][68];
  __shared__ float vt[48][68];
  __shared__ float Ss[48][28];
  const int b = blockIdx.x / NN;
  const int n = blockIdx.x % NN;
  const int tid = threadIdx.x;
  const int lane = tid & 63;
  const int wave = tid >> 6;

  for (int idx = tid; idx < 48 * 16; idx += 256) {
    int row = idx >> 4, dq = (idx & 15) * 4;
    int h = row / 24, t = row - h * 24;
    const _Float16* g = qkvt + ((size_t)(b * TT + t) * NN + n) * 640 + h * 64 + dq;
    f16x4 a = *(const f16x4*)(g);
    f16x4 k = *(const f16x4*)(g + 128);
    f16x4 v = *(const f16x4*)(g + 256);
    float4 fa = {(float)a.x, (float)a.y, (float)a.z, (float)a.w};
    float4 fk = {(float)k.x, (float)k.y, (float)k.z, (float)k.w};
    float4 fv = {(float)v.x, (float)v.y, (float)v.z, (float)v.w};
    *(float4*)&qs[row][dq] = fa;
    *(float4*)&kt[row][dq] = fk;
    *(float4*)&vt[row][dq] = fv;
  }
  __syncthreads();

  for (int idx = tid; idx < 48 * 24; idx += 256) {
    int row = idx / 24, s = idx - row * 24;
    int krow = (row >= 24 ? 24 : 0) + s;
    float a0 = 0.f, a1 = 0.f, a2 = 0.f, a3 = 0.f;
    #pragma unroll
    for (int dq = 0; dq < 64; dq += 4) {
      float4 q = *(const float4*)&qs[row][dq];
      float4 k = *(const float4*)&kt[krow][dq];
      a0 = fmaf(q.x, k.x, a0);
      a1 = fmaf(q.y, k.y, a1);
      a2 = fmaf(q.z, k.z, a2);
      a3 = fmaf(q.w, k.w, a3);
    }
    Ss[row][s] = ((a0 + a1) + (a2 + a3)) * 0.125f;
  }
  __syncthreads();

  for (int r = wave; r < 48; r += 4) {
    float v = lane < 24 ? Ss[r][lane] : -1e30f;
    float mx = wred_max(v);
    float p = lane < 24 ? __expf(v - mx) : 0.f;
    float inv = 1.f / wred_sum(p);
    if (lane < 24) Ss[r][lane] = p * inv;
  }
  __syncthreads();

  for (int idx = tid; idx < 48 * 16; idx += 256) {
    int row = idx >> 4, dq = (idx & 15) * 4;
    int h = row / 24, t = row - h * 24;
    int bs = h * 24;
    float ax = 0.f, ay = 0.f, az = 0.f, aw = 0.f;
    #pragma unroll
    for (int s = 0; s < 24; ++s) {
      float p = Ss[row][s];
      float4 v = *(const float4*)&vt[bs + s][dq];
      ax = fmaf(p, v.x, ax);
      ay = fmaf(p, v.y, ay);
      az = fmaf(p, v.z, az);
      aw = fmaf(p, v.w, aw);
    }
    union { h2 h[2]; f16x4 v; } o2;
    o2.h[0] = __builtin_amdgcn_cvt_pkrtz(ax, ay);
    o2.h[1] = __builtin_amdgcn_cvt_pkrtz(az, aw);
    *(f16x4*)(st + ((size_t)(b * TT + t) * NN + n) * 640 + 384 + h * 64 + dq) = o2.v;
  }
}

// ---------------------------------------------------------------------------
// Temporal-global attention (R7: f16 qkvt input).
// ---------------------------------------------------------------------------
__global__ __launch_bounds__(256) void tglobal_attn(
    const _Float16* __restrict__ qkvt, const float* __restrict__ q_agg,
    const float* __restrict__ tmp_map, _Float16* __restrict__ st)
{
  __shared__ float qg[24][68];
  __shared__ float kg[48][68];
  __shared__ float vg[48][68];
  __shared__ float Sg[24][28];
  __shared__ float tgx[12][128];
  const int b = blockIdx.x / NN;
  const int n = blockIdx.x % NN;
  const int tid = threadIdx.x;
  const int lane = tid & 63;
  const int wave = tid >> 6;

  for (int idx = tid; idx < 48 * 16; idx += 256) {
    int row = idx >> 4, dq = (idx & 15) * 4;
    int h = row / 24, t = row - h * 24;
    const _Float16* g = qkvt + ((size_t)(b * TT + t) * NN + n) * 640 + 384 + h * 64 + dq;
    f16x4 k = *(const f16x4*)(g);
    f16x4 v = *(const f16x4*)(g + 128);
    float4 fk = {(float)k.x, (float)k.y, (float)k.z, (float)k.w};
    float4 fv = {(float)v.x, (float)v.y, (float)v.z, (float)v.w};
    *(float4*)&kg[row][dq] = fk;
    *(float4*)&vg[row][dq] = fv;
  }
  for (int idx = tid; idx < 24 * 16; idx += 256) {
    int row = idx >> 4, dq = (idx & 15) * 4;   // row = h*12+s
    int h = row / 12, s = row - h * 12;
    *(float4*)&qg[row][dq] =
        *(const float4*)(q_agg + ((size_t)n * 12 + s) * 128 + h * 64 + dq);
  }
  __syncthreads();

  for (int idx = tid; idx < 24 * 24; idx += 256) {
    int row = idx / 24, t = idx - row * 24;
    int krow = (row >= 12 ? 24 : 0) + t;
    float a0 = 0.f, a1 = 0.f, a2 = 0.f, a3 = 0.f;
    #pragma unroll
    for (int dq = 0; dq < 64; dq += 4) {
      float4 q = *(const float4*)&qg[row][dq];
      float4 k = *(const float4*)&kg[krow][dq];
      a0 = fmaf(q.x, k.x, a0);
      a1 = fmaf(q.y, k.y, a1);
      a2 = fmaf(q.z, k.z, a2);
      a3 = fmaf(q.w, k.w, a3);
    }
    Sg[row][t] = ((a0 + a1) + (a2 + a3)) * 0.125f;
  }
  __syncthreads();

  for (int r = wave; r < 24; r += 4) {
    float v = lane < 24 ? Sg[r][lane] : -1e30f;
    float mx = wred_max(v);
    float p = lane < 24 ? __expf(v - mx) : 0.f;
    float inv = 1.f / wred_sum(p);
    if (lane < 24) Sg[r][lane] = p * inv;
  }
  __syncthreads();

  for (int idx = tid; idx < 24 * 16; idx += 256) {
    int row = idx >> 4, dq = (idx & 15) * 4;   // row = h*12+s
    int h = row / 12, s = row - h * 12;
    int bt_ = h * 24;
    float ax = 0.f, ay = 0.f, az = 0.f, aw = 0.f;
    #pragma unroll
    for (int t = 0; t < 24; ++t) {
      float p = Sg[row][t];
      float4 v = *(const float4*)&vg[bt_ + t][dq];
      ax = fmaf(p, v.x, ax);
      ay = fmaf(p, v.y, ay);
      az = fmaf(p, v.z, az);
      aw = fmaf(p, v.w, aw);
    }
    float4 o = {ax, ay, az, aw};
    *(float4*)&tgx[s][h * 64 + dq] = o;
  }
  __syncthreads();

  for (int idx = tid; idx < 24 * 32; idx += 256) {
    int t = idx >> 5, cq = (idx & 31) * 4;
    const float* tm = tmp_map + ((size_t)(b * NN + n) * TT + t) * 12;
    float ax = 0.f, ay = 0.f, az = 0.f, aw = 0.f;
    #pragma unroll
    for (int s = 0; s < 12; ++s) {
      float m = tm[s];
      float4 v = *(const float4*)&tgx[s][cq];
      ax = fmaf(m, v.x, ax);
      ay = fmaf(m, v.y, ay);
      az = fmaf(m, v.z, az);
      aw = fmaf(m, v.w, aw);
    }
    union { h2 h[2]; f16x4 v; } o2;
    o2.h[0] = __builtin_amdgcn_cvt_pkrtz(ax, ay);
    o2.h[1] = __builtin_amdgcn_cvt_pkrtz(az, aw);
    *(f16x4*)(st + ((size_t)(b * TT + t) * NN + n) * 640 + 512 + cq) = o2.v;
  }
}

// ---------------------------------------------------------------------------
// Agg attention v2 (R7): LDS flat phases (temporal_attn pattern) — replaces
// the old 64-deep serial-shfl chains. Ni is a power of 2 (32 or 64).
// ---------------------------------------------------------------------------
__global__ __launch_bounds__(256) void agg_attn(
    const float* __restrict__ qkva, float* __restrict__ sx, int Ni, int lg)
{
  __shared__ float qa[64][68];
  __shared__ float ka[64][68];
  __shared__ float va[64][68];
  __shared__ float Ss[64][68];
  const int h = blockIdx.x & 1;
  const int bt = blockIdx.x >> 1;
  const int tid = threadIdx.x;
  const int lane = tid & 63;
  const int wave = tid >> 6;

  for (int idx = tid; idx < Ni * 16; idx += 256) {
    int m = idx >> 4, dq = (idx & 15) * 4;
    const float* r = qkva + (size_t)(bt * Ni + m) * 384 + h * 64 + dq;
    *(float4*)&qa[m][dq] = *(const float4*)(r);
    *(float4*)&ka[m][dq] = *(const float4*)(r + 128);
    *(float4*)&va[m][dq] = *(const float4*)(r + 256);
  }
  __syncthreads();

  for (int idx = tid; idx < Ni * Ni; idx += 256) {
    int n = idx >> lg, m = idx & (Ni - 1);
    float a0 = 0.f, a1 = 0.f, a2 = 0.f, a3 = 0.f;
    #pragma unroll
    for (int dq = 0; dq < 64; dq += 4) {
      float4 q = *(const float4*)&qa[n][dq];
      float4 k = *(const float4*)&ka[m][dq];
      a0 = fmaf(q.x, k.x, a0);
      a1 = fmaf(q.y, k.y, a1);
      a2 = fmaf(q.z, k.z, a2);
      a3 = fmaf(q.w, k.w, a3);
    }
    Ss[n][m] = ((a0 + a1) + (a2 + a3)) * 0.125f;
  }
  __syncthreads();

  for (int r = wave; r < Ni; r += 4) {
    float v = lane < Ni ? Ss[r][lane] : -1e30f;
    float mx = wred_max(v);
    float p = lane < Ni ? __expf(v - mx) : 0.f;
    float inv = 1.f / wred_sum(p);
    if (lane < Ni) Ss[r][lane] = p * inv;
  }
  __syncthreads();

  for (int idx = tid; idx < Ni * 16; idx += 256) {
    int n = idx >> 4, dq = (idx & 15) * 4;
    float ax = 0.f, ay = 0.f, az = 0.f, aw = 0.f;
    for (int m = 0; m < Ni; ++m) {
      float p = Ss[n][m];
      float4 v = *(const float4*)&va[m][dq];
      ax = fmaf(p, v.x, ax);
      ay = fmaf(p, v.y, ay);
      az = fmaf(p, v.z, az);
      aw = fmaf(p, v.w, aw);
    }
    float4 o = {ax, ay, az, aw};
    *(float4*)(sx + (size_t)(bt * Ni + n) * 128 + h * 64 + dq) = o;
  }
}

// ---------------------------------------------------------------------------
// mmap v3 (verified R7): LDS-staged M + s, 8n x 4c register tile.
// ---------------------------------------------------------------------------
__global__ __launch_bounds__(256) void mmap_kernel(
    const float* __restrict__ sx0, const float* __restrict__ sx1,
    const float* __restrict__ M0, const float* __restrict__ M1,
    _Float16* __restrict__ sg)
{
  __shared__ float sS[96][128];
  __shared__ float Mc[96][88];
  const int bt = blockIdx.x;
  const int chunk = blockIdx.y;
  const int tid = threadIdx.x;
  const int nbase = chunk * 88;

  for (int idx = tid; idx < 96 * 32; idx += 256) {
    int m = idx >> 5, c4 = (idx & 31) * 4;
    float4 v = (m < 32)
        ? *(const float4*)(sx0 + ((size_t)(bt * 32 + m) * 128 + c4))
        : *(const float4*)(sx1 + ((size_t)(bt * 64 + (m - 32)) * 128 + c4));
    *(float4*)&sS[m][c4] = v;
  }
  for (int idx = tid; idx < 96 * 88; idx += 256) {
    int m = idx / 88, nl = idx - m * 88;
    int n = nbase + nl; if (n > NN - 1) n = NN - 1;
    Mc[m][nl] = (m < 32) ? M0[m * NN + n] : M1[(m - 32) * NN + n];
  }
  __syncthreads();

  for (int idx = tid; idx < 352; idx += 256) {
    const int n0 = (idx >> 5) * 8;
    const int c4 = (idx & 31) * 4;
    f32x4 acc[8];
    #pragma unroll
    for (int j = 0; j < 8; ++j) {
      acc[j].x = 0.f; acc[j].y = 0.f; acc[j].z = 0.f; acc[j].w = 0.f;
    }
    #pragma unroll 4
    for (int m = 0; m < 96; ++m) {
      float4 sv = *(const float4*)&sS[m][c4];
      float mj[8];
      *(float4*)&mj[0] = *(const float4*)&Mc[m][n0];
      *(float4*)&mj[4] = *(const float4*)&Mc[m][n0 + 4];
      #pragma unroll
      for (int j = 0; j < 8; ++j) {
        acc[j].x = fmaf(mj[j], sv.x, acc[j].x);
        acc[j].y = fmaf(mj[j], sv.y, acc[j].y);
        acc[j].z = fmaf(mj[j], sv.z, acc[j].z);
        acc[j].w = fmaf(mj[j], sv.w, acc[j].w);
      }
    }
    #pragma unroll
    for (int j = 0; j < 8; ++j) {
      int n = nbase + n0 + j;
      if (n < NN) {
        union { h2 h[2]; f16x4 v; } o;
        o.h[0] = __builtin_amdgcn_cvt_pkrtz(acc[j].x, acc[j].y);
        o.h[1] = __builtin_amdgcn_cvt_pkrtz(acc[j].z, acc[j].w);
        *(f16x4*)(sg + ((size_t)bt * NN + n) * 128 + c4) = o.v;
      }
    }
  }
}

// ---------------------------------------------------------------------------
extern "C" void kernel_launch(void* const* d_in, const int* in_sizes, int n_in,
                              void* d_out, int out_size, void* d_ws, size_t ws_size,
                              hipStream_t stream)
{
  const float* x       = (const float*)d_in[0];
  const float* agg_x0  = (const float*)d_in[1];
  const float* agg_x1  = (const float*)d_in[2];
  const float* tmp_map = (const float*)d_in[3];
  const float* Wq_s = (const float*)d_in[4];
  const float* Wk_s = (const float*)d_in[5];
  const float* Wv_s = (const float*)d_in[6];
  const float* lq1 = (const float*)d_in[7];
  const float* lk1 = (const float*)d_in[8];
  const float* lq2 = (const float*)d_in[9];
  const float* lk2 = (const float*)d_in[10];
  const float* ln_g = (const float*)d_in[11];
  const float* ln_b = (const float*)d_in[12];
  const float* Wq_a0 = (const float*)d_in[13];
  const float* Wk_a0 = (const float*)d_in[14];
  const float* Wv_a0 = (const float*)d_in[15];
  const float* Wq_a1 = (const float*)d_in[16];
  const float* Wk_a1 = (const float*)d_in[17];
  const float* Wv_a1 = (const float*)d_in[18];
  const float* M0   = (const float*)d_in[19];
  const float* M1   = (const float*)d_in[20];
  const float* Wagg = (const float*)d_in[21];
  const float* bagg = (const float*)d_in[22];
  const float* Wq_t = (const float*)d_in[23];
  const float* Wk_t = (const float*)d_in[24];
  const float* Wv_t = (const float*)d_in[25];
  const float* q_agg = (const float*)d_in[26];
  const float* Wk_tg = (const float*)d_in[27];
  const float* Wv_tg = (const float*)d_in[28];
  const float* Wout  = (const float*)d_in[29];
  const float* bout  = (const float*)d_in[30];
  float* ws  = (float*)d_ws;
  float* out = (float*)d_out;

  const size_t o_lam  = 1114112;
  const size_t o_A    = 1114128;
  const size_t o_qkvt = o_A + 38780928;
  const size_t o_B    = o_qkvt + 32317440;

  float* lamp  = ws + o_lam;
  _Float16* qkv_h  = (_Float16*)(ws + o_A);      // f16, dead after diff_attn
  _Float16* st_h   = (_Float16*)(ws + o_A);      // reuses o_A after diff_ln
  _Float16* qkvt_h = (_Float16*)(ws + o_qkvt);
  _Float16* x_h = (_Float16*)(ws + o_B);         // dead after qkvt GEMM
  _Float16* a1_h = (_Float16*)(ws + o_B);        // written by diff_attn (after x_h dead)
  float* qkva0 = ws + o_B;                       // after diff_ln
  float* qkva1 = qkva0 + 2359296;
  float* sx0   = qkva0 + 7077888;
  float* sx1   = qkva0 + 7864320;
  _Float16* sg_h = (_Float16*)(qkva0 + 9437184);
  _Float16* Wh  = (_Float16*)ws;                 // f16 weights in old W_all region

  hipLaunchKernelGGL(lam_kernel, dim3(1), dim3(64), 0, stream, lq1, lk1, lq2, lk2, lamp);

  // ---- one-shot fp32->f16 conversion: x + all h16-GEMM weights ----
  CvtSegs cs;
  cs.src[0] = x;      cs.dst[0] = x_h;          cs.cnt8[0] = 25853952 / 8;
  cs.src[1] = Wq_s;   cs.dst[1] = Wh + 0;       cs.cnt8[1] = 131072 / 8;
  cs.src[2] = Wk_s;   cs.dst[2] = Wh + 131072;  cs.cnt8[2] = 131072 / 8;
  cs.src[3] = Wv_s;   cs.dst[3] = Wh + 262144;  cs.cnt8[3] = 131072 / 8;
  cs.src[4] = Wq_t;   cs.dst[4] = Wh + 393216;  cs.cnt8[4] = 65536 / 8;
  cs.src[5] = Wk_t;   cs.dst[5] = Wh + 458752;  cs.cnt8[5] = 65536 / 8;
  cs.src[6] = Wv_t;   cs.dst[6] = Wh + 524288;  cs.cnt8[6] = 65536 / 8;
  cs.src[7] = Wk_tg;  cs.dst[7] = Wh + 589824;  cs.cnt8[7] = 65536 / 8;
  cs.src[8] = Wv_tg;  cs.dst[8] = Wh + 655360;  cs.cnt8[8] = 65536 / 8;
  cs.src[9] = Wagg;   cs.dst[9] = Wh + 720896;  cs.cnt8[9] = 16384 / 8;
  cs.src[10] = Wout;  cs.dst[10] = Wh + 737280; cs.cnt8[10] = 327680 / 8;
  hipLaunchKernelGGL(cvt_f16, dim3(2048), dim3(256), 0, stream, cs, 11, 3364864);

  const int Mx = 50496;

  // qkv projection: N=768 (6 tiles), f16 out
  WSegsH wqkv; wqkv.p[0] = Wh; wqkv.p[1] = Wh + 65536;
  wqkv.p[2] = Wh + 131072; wqkv.p[3] = Wh + 196608;
  wqkv.p[4] = Wh + 262144; wqkv.p[5] = Wh + 327680;
  hipLaunchKernelGGL((gemm_h16<1>), dim3(395 * 6), dim3(256), 0, stream,
                     x_h, wqkv, (const float*)nullptr, (void*)qkv_h, Mx, 6, 512, 768);

  // temporal qkv: N=640 (5 tiles), f16 out — before diff_attn so x_h dies first
  WSegsH wt; wt.p[0] = Wh + 393216; wt.p[1] = Wh + 458752; wt.p[2] = Wh + 524288;
  wt.p[3] = Wh + 589824; wt.p[4] = Wh + 655360; wt.p[5] = Wh + 393216;
  hipLaunchKernelGGL((gemm_h16<1>), dim3(395 * 5), dim3(256), 0, stream,
                     x_h, wt, (const float*)nullptr, (void*)qkvt_h, Mx, 5, 512, 640);

  hipLaunchKernelGGL(diff_attn, dim3(768), dim3(512), 0, stream, qkv_h, a1_h);
  hipLaunchKernelGGL(diff_ln, dim3(Mx), dim3(256), 0, stream,
                     a1_h, a1_h + 12926976, lamp, ln_g, ln_b, st_h);
  hipLaunchKernelGGL(temporal_attn, dim3(8 * NN), dim3(256), 0, stream, qkvt_h, st_h);
  hipLaunchKernelGGL(tglobal_attn, dim3(8 * NN), dim3(256), 0, stream, qkvt_h, q_agg, tmp_map, st_h);

  // agg projections (small): legacy fp32 GEMM
  WSegs wa0; wa0.p[0] = Wq_a0; wa0.p[1] = Wk_a0; wa0.p[2] = Wv_a0;
  wa0.p[3] = wa0.p[4] = wa0.p[5] = Wq_a0;
  hipLaunchKernelGGL(gemm_nt_mfma, dim3(48 * 3), dim3(256), 0, stream,
                     agg_x0, wa0, (const float*)nullptr, qkva0, 6144, 3, 512, 384);
  WSegs wa1; wa1.p[0] = Wq_a1; wa1.p[1] = Wk_a1; wa1.p[2] = Wv_a1;
  wa1.p[3] = wa1.p[4] = wa1.p[5] = Wq_a1;
  hipLaunchKernelGGL(gemm_nt_mfma, dim3(96 * 3), dim3(256), 0, stream,
                     agg_x1, wa1, (const float*)nullptr, qkva1, 12288, 3, 512, 384);

  hipLaunchKernelGGL(agg_attn, dim3(384), dim3(256), 0, stream, qkva0, sx0, 32, 5);
  hipLaunchKernelGGL(agg_attn, dim3(384), dim3(256), 0, stream, qkva1, sx1, 64, 6);
  hipLaunchKernelGGL(mmap_kernel, dim3(192, 3), dim3(256), 0, stream, sx0, sx1, M0, M1, sg_h);

  // sg @ Wagg.T + bagg -> st_h cols 256..383 (f16 out)
  WSegsH wag; wag.p[0] = Wh + 720896;
  wag.p[1] = wag.p[2] = wag.p[3] = wag.p[4] = wag.p[5] = wag.p[0];
  hipLaunchKernelGGL((gemm_h16<1>), dim3(395 * 1), dim3(256), 0, stream,
                     sg_h, wag, bagg, (void*)(st_h + 256), Mx, 1, 128, 640);

  // out projection: N=512 (4 tiles of Wout)
  WSegsH wo; wo.p[0] = Wh + 737280; wo.p[1] = Wh + 737280 + 81920;
  wo.p[2] = Wh + 737280 + 163840; wo.p[3] = Wh + 737280 + 245760;
  wo.p[4] = wo.p[5] = wo.p[0];
  hipLaunchKernelGGL((gemm_h16<0>), dim3(395 * 4), dim3(256), 0, stream,
                     st_h, wo, bout, (void*)out, Mx, 4, 640, 512);
}